// Round 5
// baseline (826.830 us; speedup 1.0000x reference)
//
#include <hip/hip_runtime.h>
#include <hip/hip_bf16.h>
#include <stdint.h>

typedef __attribute__((ext_vector_type(8))) short short8;
typedef __attribute__((ext_vector_type(4))) float floatx4;
typedef __attribute__((ext_vector_type(4))) unsigned int u32x4;
typedef unsigned short u16;
typedef unsigned int u32;
typedef unsigned long long u64;

static __device__ __forceinline__ u16 f2bf(float f) {
  union { float f; u32 u; } v; v.f = f;
  return (u16)((v.u + 0x7fffu + ((v.u >> 16) & 1u)) >> 16);
}
static __device__ __forceinline__ float bf2f(u16 h) {
  union { u32 u; float f; } v; v.u = ((u32)h) << 16; return v.f;
}
static __device__ __forceinline__ u64 pack4(float a, float b, float c, float d) {
  return (u64)f2bf(a) | ((u64)f2bf(b) << 16) | ((u64)f2bf(c) << 32) | ((u64)f2bf(d) << 48);
}

// ---------------- conversions ----------------
__global__ __launch_bounds__(256) void k_cvt(const float* __restrict__ src, u16* __restrict__ dst, int nquad) {
  int i = blockIdx.x * 256 + threadIdx.x;
  int stride = gridDim.x * 256;
  for (; i < nquad; i += stride) {
    float4 v = ((const float4*)src)[i];
    ((u64*)dst)[i] = pack4(v.x, v.y, v.z, v.w);
  }
}

// conv weights (K,1,ws,1024) -> Wc[4608][1024] bf16, rows = [ws2: j*512+k | ws3 | ws4]
__global__ __launch_bounds__(256) void k_cvt_wc(const float* __restrict__ w2, const float* __restrict__ w3,
                                                const float* __restrict__ w4, u16* __restrict__ wc) {
  int i = blockIdx.x * 256 + threadIdx.x;
  int stride = gridDim.x * 256;
  const int nquad = 4608 * 1024 / 4;
  for (; i < nquad; i += stride) {
    int e = i << 2;
    int row = e >> 10, col = e & 1023;
    const float* src;
    if (row < 1024)      { int j = row >> 9, k = row & 511;               src = w2 + (k * 2 + j) * 1024; }
    else if (row < 2560) { int m = row - 1024; int j = m >> 9, k = m & 511; src = w3 + (k * 3 + j) * 1024; }
    else                 { int m = row - 2560; int j = m >> 9, k = m & 511; src = w4 + (k * 4 + j) * 1024; }
    float4 v = *(const float4*)(src + col);
    ((u64*)wc)[i] = pack4(v.x, v.y, v.z, v.w);
  }
}

__global__ __launch_bounds__(256) void k_prep(const float* __restrict__ bih_f, const float* __restrict__ bih_b,
    const float* __restrict__ fcb, const float* __restrict__ gam, const float* __restrict__ bet,
    const float* __restrict__ mu, const float* __restrict__ var,
    float* __restrict__ bihcat, float* __restrict__ bns, float* __restrict__ bnt) {
  int i = blockIdx.x * 256 + threadIdx.x;
  if (i < 3072) bihcat[i] = (i < 1536) ? bih_f[i] : bih_b[i - 1536];
  if (i < 2048) {
    float s = gam[i] * rsqrtf(var[i] + 1e-5f);
    bns[i] = s;
    bnt[i] = s * (fcb[i] - mu[i]) + bet[i];
  }
}

// ---------------- generic bf16 MFMA GEMM: C[M,N] = A[M,K] * B[N,K]^T
static __device__ __forceinline__ void gload_lds16(const u16* g, u16* l) {
  __builtin_amdgcn_global_load_lds((const __attribute__((address_space(1))) u32*)(const void*)g,
                                   (__attribute__((address_space(3))) u32*)(void*)l, 16, 0, 0);
}

__global__ __launch_bounds__(256) void gemm_bt(
    const u16* __restrict__ A, const u16* __restrict__ Bm,
    float* __restrict__ C, u16* __restrict__ C16, int M, int N, int K, int kn,
    const float* __restrict__ scale, const float* __restrict__ shift)
{
  __shared__ u16 As[128 * 32];
  __shared__ u16 Bs[128 * 32];
  int tid = threadIdx.x, lane = tid & 63, wid = tid >> 6;
  int m0 = blockIdx.y * 128, n0 = blockIdx.x * 128;
  int kt0 = blockIdx.z * kn;
  int wr = wid >> 1, wc = wid & 1;
  int r16 = lane & 15, kq = lane >> 4;
  const floatx4 z4 = {0.f, 0.f, 0.f, 0.f};
  floatx4 acc[4][4];
#pragma unroll
  for (int i = 0; i < 4; ++i)
#pragma unroll
    for (int j = 0; j < 4; ++j) acc[i][j] = z4;
  for (int kt = kt0; kt < kt0 + kn; ++kt) {
    __syncthreads();
#pragma unroll
    for (int inst = 0; inst < 2; ++inst) {
      int g = inst * 256 + tid;
      int row = g >> 2, cb = g & 3;
      const u16* ga = A + (long)(m0 + row) * K + kt * 32 + cb * 8;
      const u16* gb = Bm + (long)(n0 + row) * K + kt * 32 + cb * 8;
      gload_lds16(ga, &As[(inst * 256 + wid * 64) * 8]);
      gload_lds16(gb, &Bs[(inst * 256 + wid * 64) * 8]);
    }
    __syncthreads();
    short8 af[4], bf[4];
#pragma unroll
    for (int mt = 0; mt < 4; ++mt) af[mt] = *(const short8*)&As[(wr * 64 + mt * 16 + r16) * 32 + kq * 8];
#pragma unroll
    for (int nt = 0; nt < 4; ++nt) bf[nt] = *(const short8*)&Bs[(wc * 64 + nt * 16 + r16) * 32 + kq * 8];
#pragma unroll
    for (int mt = 0; mt < 4; ++mt)
#pragma unroll
      for (int nt = 0; nt < 4; ++nt)
        acc[mt][nt] = __builtin_amdgcn_mfma_f32_16x16x32_bf16(af[mt], bf[nt], acc[mt][nt], 0, 0, 0);
  }
  float* Cp = C + (long)blockIdx.z * M * N;
#pragma unroll
  for (int nt = 0; nt < 4; ++nt) {
    int col = n0 + wc * 64 + nt * 16 + r16;
    float sc = scale ? scale[col] : 1.f;
    float sh = shift ? shift[col] : 0.f;
#pragma unroll
    for (int mt = 0; mt < 4; ++mt)
#pragma unroll
      for (int q = 0; q < 4; ++q) {
        int row = m0 + wr * 64 + mt * 16 + kq * 4 + q;
        float v = acc[mt][nt][q] * sc + sh;
        if (C16) C16[(long)row * N + col] = f2bf(v);
        else     Cp[(long)row * N + col] = v;
      }
  }
}

// ---------------- GRU recurrence ----------------
// R4 = R3 structure + R2 protocol.
// 128 blocks = bt(8: 16 batches) x is(16: 32 i-rows); each block runs BOTH
// directions, alternating phases f,b per step. While dir-f's stored h transits
// L3 and the group's stragglers publish, the block computes dir-b: the
// handshake latency hides under the independent second chain's compute.
// Waves: 8 = ih(2) x ks(4: 128-wide k quarter). Whh fragments for both dirs
// resident in VGPRs.
// Exchange protocol (PROVEN, from R2 — R3's tagged single-store scheme was
// UNSOUND: no dword-granular visibility order within one store => stale-data
// race): h stored sc0 sc1 -> vmcnt(0) ack drain -> per-wave flag store.
// Flag observed => h globally visible. Single poller wave + s_sleep backoff,
// raw s_barrier release. hbuf parity double-buffered per step.
// LDS: hstage single copy (reuse ordered by the lgkmcnt(0)+s_barrier pairs);
// part[] parity-indexed by direction (insurance).
__global__ __launch_bounds__(512) void gru_rec(
    const float* __restrict__ xg,     // [8192][3072]
    const u16* __restrict__ whhb,     // [2][1536][512] bf16
    const float* __restrict__ bhh_f, const float* __restrict__ bhh_b,
    u16* __restrict__ hbuf,           // [2 parity][2 dir][128][512] bf16 (zeroed each launch)
    float* __restrict__ hs,           // [128][64][1024] fp32
    int* __restrict__ flg)            // 512 flags x 16 ints (64B lines), zeroed each launch
{
  __shared__ u16 hstage[8192];          // 16KB: h[16 batch][512 i] bf16, XOR-swizzled
  __shared__ float part[2][3][2][3][256]; // 36KB: [d][ks-1][ih][g][lane*4]
  int tid = threadIdx.x, lane = tid & 63, wid = tid >> 6;
  int bid = blockIdx.x;
  int bt = bid >> 4, is = bid & 15;
  int ih = wid & 1, ks = wid >> 1;
  int r16 = lane & 15, kq = lane >> 4;
  int iglob = is * 32 + ih * 16 + r16;       // weight row within gate block
  int i0 = is * 32 + ih * 16 + kq * 4;       // base of this lane's 4 outputs
  int batch = bt * 16 + r16;
  const floatx4 z4 = {0.f, 0.f, 0.f, 0.f};

  // Whh fragments, both dirs: [d][g][kk], k-slice = ks*128 + kk*32 + kq*8
  short8 wfrag[2][3][4];
#pragma unroll
  for (int d = 0; d < 2; ++d)
#pragma unroll
    for (int g = 0; g < 3; ++g) {
      const u16* wrow = whhb + (long)(d * 1536 + g * 512 + iglob) * 512;
#pragma unroll
      for (int kk = 0; kk < 4; ++kk)
        wfrag[d][g][kk] = *(const short8*)&wrow[ks * 128 + kk * 32 + kq * 8];
    }
  float4 bh4[2][3];
#pragma unroll
  for (int d = 0; d < 2; ++d) {
    const float* bhh = d ? bhh_b : bhh_f;
#pragma unroll
    for (int g = 0; g < 3; ++g) bh4[d][g] = *(const float4*)&bhh[g * 512 + i0];
  }
  float4 hprev[2];
  hprev[0] = {0.f, 0.f, 0.f, 0.f};
  hprev[1] = {0.f, 0.f, 0.f, 0.f};

  float4 px[2][3];
  if (ks == 0) {
#pragma unroll
    for (int d = 0; d < 2; ++d) {
      int ts0 = d ? 63 : 0;
      long xb = (long)(batch * 64 + ts0) * 3072 + d * 1536 + i0;
#pragma unroll
      for (int g = 0; g < 3; ++g) px[d][g] = *(const float4*)&xg[xb + g * 512];
    }
  }

  // stage addressing: two 16B chunks per thread, rows 2*wid and 2*wid+1
  // (granule lane&7 -> conflict-free ds_write). swizzle byte ^= (row&7)<<4.
  int so0 = wid * 2048 + lane * 16;
  int so1 = so0 + 1024;
  char* sl0 = (char*)hstage + (so0 ^ (((so0 >> 10) & 7) << 4));
  char* sl1 = (char*)hstage + (so1 ^ (((so1 >> 10) & 7) << 4));
  // fragment read base: bytes r16*1024 + ks*256 + kk*64 + kq*16, swz (r16&7)<<4
  int rb = r16 * 1024 + ks * 256 + kq * 16;
  int rsw = (r16 & 7) << 4;

  for (int t = 0; t < 64; ++t) {
    int par = t & 1;
#pragma unroll
    for (int d = 0; d < 2; ++d) {
      // 1. wait for all group blocks (same bt, dir d) to have finished step t-1.
      if (t > 0) {
        if (wid == 0) {
          const int* fp = &flg[((d * 8 + bt) * 32 + (lane & 31)) * 16];
          while (true) {
            int v;
            asm volatile("global_load_dword %0, %1, off sc0 sc1\n\ts_waitcnt vmcnt(0)"
                         : "=v"(v) : "v"(fp) : "memory");
            if (__all(v >= t)) break;
            __builtin_amdgcn_s_sleep(1);
          }
        }
        asm volatile("s_barrier" ::: "memory");
      }
      // 2. coalesced cooperative stage: h[16][512] bf16 (16KB) -> LDS (swizzled)
      const char* hsrc = (const char*)(hbuf + (long)((par * 2 + d) * 128 + bt * 16) * 512);
      u32x4 qa, qb;
      asm volatile(
        "global_load_dwordx4 %0, %2, off sc0 sc1\n\t"
        "global_load_dwordx4 %1, %3, off sc0 sc1"
        : "=&v"(qa), "=&v"(qb)
        : "v"(hsrc + so0), "v"(hsrc + so1)
        : "memory");
      asm volatile("s_waitcnt vmcnt(0)" ::: "memory");
      *(u32x4*)sl0 = qa;
      *(u32x4*)sl1 = qb;
      // 3. next-step xg prefetch for this dir (consumed one full step later)
      float4 pxn[3];
      if (ks == 0 && t < 63) {
        int ts1 = d ? (62 - t) : (t + 1);
        long xb = (long)(batch * 64 + ts1) * 3072 + d * 1536 + i0;
#pragma unroll
        for (int g = 0; g < 3; ++g) pxn[g] = *(const float4*)&xg[xb + g * 512];
      }
      asm volatile("s_waitcnt lgkmcnt(0)\n\ts_barrier" ::: "memory");
      // 4. fragments from LDS + MFMA
      floatx4 acc[3];
#pragma unroll
      for (int g = 0; g < 3; ++g) acc[g] = z4;
#pragma unroll
      for (int kk = 0; kk < 4; ++kk) {
        short8 hv = *(const short8*)((const char*)hstage + ((rb + kk * 64) ^ rsw));
#pragma unroll
        for (int g = 0; g < 3; ++g)
          acc[g] = __builtin_amdgcn_mfma_f32_16x16x32_bf16(wfrag[d][g][kk], hv, acc[g], 0, 0, 0);
      }
      if (ks != 0) {
#pragma unroll
        for (int g = 0; g < 3; ++g) *(floatx4*)&part[d][ks - 1][ih][g][lane * 4] = acc[g];
      }
      asm volatile("s_waitcnt lgkmcnt(0)\n\ts_barrier" ::: "memory");
      if (ks == 0) {
#pragma unroll
        for (int j = 0; j < 3; ++j)
#pragma unroll
          for (int g = 0; g < 3; ++g) acc[g] += *(const floatx4*)&part[d][j][ih][g][lane * 4];
        float4 hn4;
#pragma unroll
        for (int q = 0; q < 4; ++q) {
          float rr = acc[0][q] + ((const float*)&bh4[d][0])[q] + ((const float*)&px[d][0])[q];
          float zz = acc[1][q] + ((const float*)&bh4[d][1])[q] + ((const float*)&px[d][1])[q];
          float r = 1.f / (1.f + __expf(-rr));
          float z = 1.f / (1.f + __expf(-zz));
          float n = tanhf(((const float*)&px[d][2])[q] + r * (acc[2][q] + ((const float*)&bh4[d][2])[q]));
          ((float*)&hn4)[q] = (1.f - z) * n + z * ((const float*)&hprev[d])[q];
        }
        hprev[d] = hn4;
        u16* hdst = hbuf + (long)(((par ^ 1) * 2 + d) * 128 + bt * 16) * 512;
        u64 hval = pack4(hn4.x, hn4.y, hn4.z, hn4.w);
        asm volatile("global_store_dwordx2 %0, %1, off sc0 sc1"
                     :: "v"((u64*)&hdst[r16 * 512 + i0]), "v"(hval) : "memory");
        if (t < 63) {
          // drain own stores (h store visible), then publish per-wave flag
          asm volatile("s_waitcnt vmcnt(0)" ::: "memory");
          if (lane == 0) {
            int tv = t + 1;
            asm volatile("global_store_dword %0, %1, off sc0 sc1"
                         :: "v"(&flg[((d * 8 + bt) * 32 + is * 2 + ih) * 16]), "v"(tv) : "memory");
          }
        }
        // hs store off the critical path
        int tsrc = d ? (63 - t) : t;
        *(float4*)&hs[(long)(batch * 64 + tsrc) * 1024 + d * 512 + i0] = hn4;
        px[d][0] = pxn[0]; px[d][1] = pxn[1]; px[d][2] = pxn[2];
      }
    }
  }
}

// ---------------- mask + mean-pool + feature assembly ----------------
__global__ __launch_bounds__(256) void k_mask_pool(
    const float* __restrict__ hs, const int* __restrict__ lengths,
    const float* __restrict__ vo, const float* __restrict__ mo,
    u16* __restrict__ maskedb, u16* __restrict__ feat)
{
  int b = blockIdx.x, tid = threadIdx.x;
  int len = lengths[b];
  float inv = 1.0f / (float)len;
  int c0 = tid * 4;
  float s0 = 0.f, s1 = 0.f, s2 = 0.f, s3 = 0.f;
  for (int t = 0; t < 64; ++t) {
    float4 v = *(const float4*)&hs[(long)(b * 64 + t) * 1024 + c0];
    u64 pk = 0ull;
    if (t < len) {
      s0 += v.x; s1 += v.y; s2 += v.z; s3 += v.w;
      pk = pack4(v.x, v.y, v.z, v.w);
    }
    *(u64*)&maskedb[(long)(b * 64 + t) * 1024 + c0] = pk;
  }
  u16* fb = feat + (long)b * 5632;
  *(u64*)&fb[c0] = pack4(s0 * inv, s1 * inv, s2 * inv, s3 * inv);
  {
    int c = tid * 8;
    float4 a = *(const float4*)&vo[(long)b * 2048 + c];
    float4 d = *(const float4*)&vo[(long)b * 2048 + c + 4];
    *(u64*)&fb[2560 + c] = pack4(a.x, a.y, a.z, a.w);
    *(u64*)&fb[2560 + c + 4] = pack4(d.x, d.y, d.z, d.w);
  }
  {
    float4 a = *(const float4*)&mo[(long)b * 1024 + c0];
    *(u64*)&fb[4608 + c0] = pack4(a.x, a.y, a.z, a.w);
  }
}

// ---------------- conv shift-add + relu + max over positions (z is bf16) ----------------
__global__ __launch_bounds__(512) void k_conv_finish(
    const u16* __restrict__ z, const float* __restrict__ cb2,
    const float* __restrict__ cb3, const float* __restrict__ cb4,
    u16* __restrict__ feat)
{
  int b = blockIdx.x, wsi = blockIdx.y, k = threadIdx.x;
  int ws = wsi + 2;
  int base = (wsi == 0) ? 0 : (wsi == 1 ? 1024 : 2560);
  const float* cb = (wsi == 0) ? cb2 : (wsi == 1 ? cb3 : cb4);
  float bias = cb[k];
  float m = 0.f;  // relu floor
  for (int p = 0; p < 64 + ws - 1; ++p) {
    float acc = bias;
    for (int j = 0; j < ws; ++j) {
      int t = p - (ws - 1) + j;
      if (t >= 0 && t < 64)
        acc += bf2f(z[(long)(b * 64 + t) * 4608 + base + j * 512 + k]);
    }
    m = fmaxf(m, acc);
  }
  feat[(long)b * 5632 + 1024 + wsi * 512 + k] = f2bf(m);
}

// ---------------- split-K reduce + BN + row L2 normalize ----------------
__global__ __launch_bounds__(256) void k_l2norm(const float* __restrict__ p,
    const float* __restrict__ bns, const float* __restrict__ bnt, float* __restrict__ out)
{
  __shared__ float red[4];
  int b = blockIdx.x, tid = threadIdx.x;
  float v[8]; float s = 0.f;
#pragma unroll
  for (int j = 0; j < 8; ++j) {
    int i = j * 256 + tid;
    long o = (long)b * 2048 + i;
    float a = p[o] + p[o + 262144] + p[o + 524288] + p[o + 786432];
    a = a * bns[i] + bnt[i];
    v[j] = a; s += a * a;
  }
#pragma unroll
  for (int o = 32; o > 0; o >>= 1) s += __shfl_down(s, o);
  if ((tid & 63) == 0) red[tid >> 6] = s;
  __syncthreads();
  float rn = rsqrtf(red[0] + red[1] + red[2] + red[3]);
#pragma unroll
  for (int j = 0; j < 8; ++j)
    out[(long)b * 2048 + j * 256 + tid] = v[j] * rn;
}

// ---------------- launch ----------------
extern "C" void kernel_launch(void* const* d_in, const int* in_sizes, int n_in,
                              void* d_out, int out_size, void* d_ws, size_t ws_size,
                              hipStream_t stream)
{
  (void)in_sizes; (void)n_in; (void)out_size; (void)ws_size;
  const float* videos       = (const float*)d_in[0];
  const float* motions      = (const float*)d_in[1];
  const float* videos_origin= (const float*)d_in[2];
  const int*   lengths      = (const int*)d_in[3];
  const float* Wih_f = (const float*)d_in[4];
  const float* Whh_f = (const float*)d_in[5];
  const float* bih_f = (const float*)d_in[6];
  const float* bhh_f = (const float*)d_in[7];
  const float* Wih_b = (const float*)d_in[8];
  const float* Whh_b = (const float*)d_in[9];
  const float* bih_b = (const float*)d_in[10];
  const float* bhh_b = (const float*)d_in[11];
  const float* fc_w  = (const float*)d_in[12];
  const float* fc_b  = (const float*)d_in[13];
  const float* bn_gamma = (const float*)d_in[14];
  const float* bn_beta  = (const float*)d_in[15];
  const float* bn_mean  = (const float*)d_in[16];
  const float* bn_var   = (const float*)d_in[17];
  const float* conv_w2 = (const float*)d_in[18];
  const float* conv_b2 = (const float*)d_in[19];
  const float* conv_w3 = (const float*)d_in[20];
  const float* conv_b3 = (const float*)d_in[21];
  const float* conv_w4 = (const float*)d_in[22];
  const float* conv_b4 = (const float*)d_in[23];
  float* out = (float*)d_out;
  char* w = (char*)d_ws;

  // workspace layout (bytes). z (bf16) overlays XG; FC split-K partials overlay MASKB.
  const size_t XG    = 0;              // 8192x3072 f32 = 100,663,296
  const size_t HS    = 100663296;      // 128x64x1024 f32 = 33,554,432
  const size_t VID   = 134217728;      // 8192x2048 bf16 = 33,554,432
  const size_t MASKB = 167772160;      // 8192x1024 bf16 = 16,777,216 (FC partials 4MB overlay)
  const size_t WIH   = 184549376;      // 3072x2048 bf16 = 12,582,912
  const size_t WHH   = 197132288;      // 2x1536x512 bf16 = 3,145,728
  const size_t WC    = 200278016;      // 4608x1024 bf16 = 9,437,184
  const size_t FCW   = 209715200;      // 2048x5632 bf16 = 23,068,672
  const size_t FEAT  = 232783872;      // 128x5632 bf16 = 1,441,792
  const size_t BIH   = 235274240;      // 3072 f32
  const size_t BNS   = 235286528;      // 2048 f32
  const size_t BNT   = 235294720;      // 2048 f32
  const size_t HB    = 235302912;      // 2x2x128x512 bf16 = 524,288
  const size_t FLG   = HB + 524288;    // 512 flags x 64B = 32,768

  float* xg   = (float*)(w + XG);
  u16*   zb16 = (u16*)(w + XG);        // overlay
  float* hs   = (float*)(w + HS);
  u16* vid    = (u16*)(w + VID);
  u16* maskb  = (u16*)(w + MASKB);
  float* fcp  = (float*)(w + MASKB);   // FC split-K partials overlay (after conv GEMM)
  u16* wih    = (u16*)(w + WIH);
  u16* whh    = (u16*)(w + WHH);
  u16* wc_    = (u16*)(w + WC);
  u16* fcw    = (u16*)(w + FCW);
  u16* feat   = (u16*)(w + FEAT);
  float* bih  = (float*)(w + BIH);
  float* bns  = (float*)(w + BNS);
  float* bnt  = (float*)(w + BNT);
  u16* hb     = (u16*)(w + HB);
  int* flg    = (int*)(w + FLG);

  // zero h double-buffer (parity0 read at t=0) + flags, every launch
  hipMemsetAsync(w + HB, 0, 524288 + 32768, stream);

  k_cvt<<<4096, 256, 0, stream>>>(videos, vid, 16777216 / 4);
  k_cvt<<<1024, 256, 0, stream>>>(Wih_f, wih, 3145728 / 4);
  k_cvt<<<1024, 256, 0, stream>>>(Wih_b, wih + 3145728, 3145728 / 4);
  k_cvt<<<512, 256, 0, stream>>>(Whh_f, whh, 786432 / 4);
  k_cvt<<<512, 256, 0, stream>>>(Whh_b, whh + 786432, 786432 / 4);
  k_cvt<<<2048, 256, 0, stream>>>(fc_w, fcw, 11534336 / 4);
  k_cvt_wc<<<2048, 256, 0, stream>>>(conv_w2, conv_w3, conv_w4, wc_);
  k_prep<<<12, 256, 0, stream>>>(bih_f, bih_b, fc_b, bn_gamma, bn_beta, bn_mean, bn_var, bih, bns, bnt);

  // xg = videos @ [Wih_f;Wih_b]^T + bih  (f32 out)
  gemm_bt<<<dim3(24, 64), 256, 0, stream>>>(vid, wih, xg, nullptr, 8192, 3072, 2048, 64, nullptr, bih);

  {
    const float* xg_c = xg; const u16* whh_c = whh;
    u16* hb_c = hb; float* hs_c = hs; int* flg_c = flg;
    const float* bf_c = bhh_f; const float* bb_c = bhh_b;
    void* args[] = { (void*)&xg_c, (void*)&whh_c, (void*)&bf_c, (void*)&bb_c,
                     (void*)&hb_c, (void*)&hs_c, (void*)&flg_c };
    hipLaunchCooperativeKernel(reinterpret_cast<void*>(gru_rec), dim3(128), dim3(512), args, 0, stream);
  }

  k_mask_pool<<<128, 256, 0, stream>>>(hs, lengths, videos_origin, motions, maskb, feat);
  // z = masked @ Wc^T  (9 shifted conv col-blocks), bf16 out
  gemm_bt<<<dim3(36, 64), 256, 0, stream>>>(maskb, wc_, nullptr, zb16, 8192, 4608, 1024, 32, nullptr, nullptr);
  k_conv_finish<<<dim3(128, 3), 512, 0, stream>>>(zb16, conv_b2, conv_b3, conv_b4, feat);
  // FC split-K x4 (raw partials; BN folded into l2norm)
  gemm_bt<<<dim3(16, 1, 4), 256, 0, stream>>>(feat, fcw, fcp, nullptr, 128, 2048, 5632, 44, nullptr, nullptr);
  k_l2norm<<<128, 256, 0, stream>>>(fcp, bns, bnt, out);
}

// Round 7
// 678.690 us; speedup vs baseline: 1.2183x; 1.2183x over previous
//
#include <hip/hip_runtime.h>
#include <hip/hip_bf16.h>
#include <stdint.h>

typedef __attribute__((ext_vector_type(8))) short short8;
typedef __attribute__((ext_vector_type(4))) float floatx4;
typedef __attribute__((ext_vector_type(4))) unsigned int u32x4;
typedef unsigned short u16;
typedef unsigned int u32;
typedef unsigned long long u64;

static __device__ __forceinline__ u16 f2bf(float f) {
  union { float f; u32 u; } v; v.f = f;
  return (u16)((v.u + 0x7fffu + ((v.u >> 16) & 1u)) >> 16);
}
static __device__ __forceinline__ float bf2f(u16 h) {
  union { u32 u; float f; } v; v.u = ((u32)h) << 16; return v.f;
}
static __device__ __forceinline__ u64 pack4(float a, float b, float c, float d) {
  return (u64)f2bf(a) | ((u64)f2bf(b) << 16) | ((u64)f2bf(c) << 32) | ((u64)f2bf(d) << 48);
}

// ---------------- conversions ----------------
__global__ __launch_bounds__(256) void k_cvt(const float* __restrict__ src, u16* __restrict__ dst, int nquad) {
  int i = blockIdx.x * 256 + threadIdx.x;
  int stride = gridDim.x * 256;
  for (; i < nquad; i += stride) {
    float4 v = ((const float4*)src)[i];
    ((u64*)dst)[i] = pack4(v.x, v.y, v.z, v.w);
  }
}

// conv weights (K,1,ws,1024) -> Wc[4608][1024] bf16, rows = [ws2: j*512+k | ws3 | ws4]
__global__ __launch_bounds__(256) void k_cvt_wc(const float* __restrict__ w2, const float* __restrict__ w3,
                                                const float* __restrict__ w4, u16* __restrict__ wc) {
  int i = blockIdx.x * 256 + threadIdx.x;
  int stride = gridDim.x * 256;
  const int nquad = 4608 * 1024 / 4;
  for (; i < nquad; i += stride) {
    int e = i << 2;
    int row = e >> 10, col = e & 1023;
    const float* src;
    if (row < 1024)      { int j = row >> 9, k = row & 511;               src = w2 + (k * 2 + j) * 1024; }
    else if (row < 2560) { int m = row - 1024; int j = m >> 9, k = m & 511; src = w3 + (k * 3 + j) * 1024; }
    else                 { int m = row - 2560; int j = m >> 9, k = m & 511; src = w4 + (k * 4 + j) * 1024; }
    float4 v = *(const float4*)(src + col);
    ((u64*)wc)[i] = pack4(v.x, v.y, v.z, v.w);
  }
}

__global__ __launch_bounds__(256) void k_prep(const float* __restrict__ bih_f, const float* __restrict__ bih_b,
    const float* __restrict__ fcb, const float* __restrict__ gam, const float* __restrict__ bet,
    const float* __restrict__ mu, const float* __restrict__ var,
    float* __restrict__ bihcat, float* __restrict__ bns, float* __restrict__ bnt) {
  int i = blockIdx.x * 256 + threadIdx.x;
  if (i < 3072) bihcat[i] = (i < 1536) ? bih_f[i] : bih_b[i - 1536];
  if (i < 2048) {
    float s = gam[i] * rsqrtf(var[i] + 1e-5f);
    bns[i] = s;
    bnt[i] = s * (fcb[i] - mu[i]) + bet[i];
  }
}

// ---------------- generic bf16 MFMA GEMM: C[M,N] = A[M,K] * B[N,K]^T
static __device__ __forceinline__ void gload_lds16(const u16* g, u16* l) {
  __builtin_amdgcn_global_load_lds((const __attribute__((address_space(1))) u32*)(const void*)g,
                                   (__attribute__((address_space(3))) u32*)(void*)l, 16, 0, 0);
}

__global__ __launch_bounds__(256) void gemm_bt(
    const u16* __restrict__ A, const u16* __restrict__ Bm,
    float* __restrict__ C, u16* __restrict__ C16, int M, int N, int K, int kn,
    const float* __restrict__ scale, const float* __restrict__ shift)
{
  __shared__ u16 As[128 * 32];
  __shared__ u16 Bs[128 * 32];
  int tid = threadIdx.x, lane = tid & 63, wid = tid >> 6;
  int m0 = blockIdx.y * 128, n0 = blockIdx.x * 128;
  int kt0 = blockIdx.z * kn;
  int wr = wid >> 1, wc = wid & 1;
  int r16 = lane & 15, kq = lane >> 4;
  const floatx4 z4 = {0.f, 0.f, 0.f, 0.f};
  floatx4 acc[4][4];
#pragma unroll
  for (int i = 0; i < 4; ++i)
#pragma unroll
    for (int j = 0; j < 4; ++j) acc[i][j] = z4;
  for (int kt = kt0; kt < kt0 + kn; ++kt) {
    __syncthreads();
#pragma unroll
    for (int inst = 0; inst < 2; ++inst) {
      int g = inst * 256 + tid;
      int row = g >> 2, cb = g & 3;
      const u16* ga = A + (long)(m0 + row) * K + kt * 32 + cb * 8;
      const u16* gb = Bm + (long)(n0 + row) * K + kt * 32 + cb * 8;
      gload_lds16(ga, &As[(inst * 256 + wid * 64) * 8]);
      gload_lds16(gb, &Bs[(inst * 256 + wid * 64) * 8]);
    }
    __syncthreads();
    short8 af[4], bf[4];
#pragma unroll
    for (int mt = 0; mt < 4; ++mt) af[mt] = *(const short8*)&As[(wr * 64 + mt * 16 + r16) * 32 + kq * 8];
#pragma unroll
    for (int nt = 0; nt < 4; ++nt) bf[nt] = *(const short8*)&Bs[(wc * 64 + nt * 16 + r16) * 32 + kq * 8];
#pragma unroll
    for (int mt = 0; mt < 4; ++mt)
#pragma unroll
      for (int nt = 0; nt < 4; ++nt)
        acc[mt][nt] = __builtin_amdgcn_mfma_f32_16x16x32_bf16(af[mt], bf[nt], acc[mt][nt], 0, 0, 0);
  }
  float* Cp = C + (long)blockIdx.z * M * N;
#pragma unroll
  for (int nt = 0; nt < 4; ++nt) {
    int col = n0 + wc * 64 + nt * 16 + r16;
    float sc = scale ? scale[col] : 1.f;
    float sh = shift ? shift[col] : 0.f;
#pragma unroll
    for (int mt = 0; mt < 4; ++mt)
#pragma unroll
      for (int q = 0; q < 4; ++q) {
        int row = m0 + wr * 64 + mt * 16 + kq * 4 + q;
        float v = acc[mt][nt][q] * sc + sh;
        if (C16) C16[(long)row * N + col] = f2bf(v);
        else     Cp[(long)row * N + col] = v;
      }
  }
}

// ---------------- GRU recurrence ----------------
// R6: true byte-for-byte revert to the R2 version (217us, 3 rounds correct).
// R5's "revert" had ONE transcription bug: fragment read stride kk*32 instead
// of kk*64 (each wave covers 8 k-chunks x 64B) -> wrong k-slices vs wfrag ->
// absmax 5e-3 fail. Fixed here; nothing else changed.
// 128 blocks x 512 threads = dir(2) x b-tile(8 of 16 batches) x i-slice(8 of 64 i).
// Coalesced cooperative stage of the block's 16KB h-slice into LDS (XOR-swizzled,
// conflict-free split chunks); sc0 sc1 (no nt) for all handshake traffic;
// publish protocol: h store -> vmcnt(0) ack drain -> per-wave flag store; flag
// observed => h globally visible. Single poller wave + s_sleep backoff; raw
// s_barrier release.
__global__ __launch_bounds__(512) void gru_rec(
    const float* __restrict__ xg,     // [8192][3072]
    const u16* __restrict__ whhb,     // [2][1536][512] bf16
    const float* __restrict__ bhh_f, const float* __restrict__ bhh_b,
    u16* __restrict__ hbuf,           // [2 parity][2 dir][128][512] bf16 (zeroed each launch)
    float* __restrict__ hs,           // [128][64][1024] fp32
    int* __restrict__ flg)            // 512 flags x 16 ints (64B lines), zeroed each launch
{
  __shared__ float part[2][4][3][256];
  __shared__ u16 hstage[8192];        // 16KB: h[16 batches][512 i] bf16, XOR-swizzled
  int tid = threadIdx.x, lane = tid & 63, wid = tid >> 6;
  int bid = blockIdx.x;
  int dir = bid >> 6, rem = bid & 63, bt = rem >> 3, is = rem & 7;
  int ih = wid & 3, ks = wid >> 2;
  int gbase = (dir * 8 + bt) * 32;
  int r16 = lane & 15, kq = lane >> 4;
  int iglob = is * 64 + ih * 16 + r16;       // i index of this lane's weight rows
  int i0 = is * 64 + ih * 16 + kq * 4;       // i base of this lane's 4 outputs
  int batch = bt * 16 + r16;                 // this lane's output batch (global)
  int pollidx = (gbase + (lane & 31)) * 16;
  int pubidx = (gbase + is * 4 + ih) * 16;
  const float* bhh = dir ? bhh_b : bhh_f;
  const floatx4 z4 = {0.f, 0.f, 0.f, 0.f};

  short8 wfrag[3][8];
#pragma unroll
  for (int g = 0; g < 3; ++g) {
    const u16* wrow = whhb + (long)(dir * 1536 + g * 512 + iglob) * 512;
#pragma unroll
    for (int kk = 0; kk < 8; ++kk)
      wfrag[g][kk] = *(const short8*)&wrow[(ks * 8 + kk) * 32 + kq * 8];
  }
  float4 bh4[3];
#pragma unroll
  for (int g = 0; g < 3; ++g) bh4[g] = *(const float4*)&bhh[g * 512 + i0];
  float4 hprev = {0.f, 0.f, 0.f, 0.f};

  float4 px[3];
  if (ks == 0) {
    int ts0 = dir ? 63 : 0;
    long xb = (long)(batch * 64 + ts0) * 3072 + dir * 1536 + i0;
#pragma unroll
    for (int g = 0; g < 3; ++g) px[g] = *(const float4*)&xg[xb + g * 512];
  }

  // stage addressing: two 16B chunks per thread, rows 2*wid and 2*wid+1
  // (granule lane&7 -> conflict-free ds_write). swizzle byte ^= (row&7)<<4.
  int so0 = wid * 2048 + lane * 16;
  int so1 = so0 + 1024;
  char* sl0 = (char*)hstage + (so0 ^ (((so0 >> 10) & 7) << 4));
  char* sl1 = (char*)hstage + (so1 ^ (((so1 >> 10) & 7) << 4));
  // fragment read base: bytes r16*1024 + ks*512 + kq*16, swz (r16&7)<<4
  int rb = r16 * 1024 + ks * 512 + kq * 16;
  int rsw = (r16 & 7) << 4;

  for (int t = 0; t < 64; ++t) {
    // 1. wait for all group blocks to have finished step t-1.
    if (t > 0) {
      if (wid == 0) {
        while (true) {
          int v;
          asm volatile("global_load_dword %0, %1, off sc0 sc1\n\ts_waitcnt vmcnt(0)"
                       : "=v"(v) : "v"(&flg[pollidx]) : "memory");
          if (__all(v >= t)) break;
          __builtin_amdgcn_s_sleep(1);
        }
      }
      asm volatile("s_barrier" ::: "memory");
    }
    int par = t & 1;
    // 2. coalesced cooperative stage: h[16][512] bf16 (16KB) -> LDS (swizzled).
    const char* hsrc = (const char*)(hbuf + (long)((par * 2 + dir) * 128 + bt * 16) * 512);
    u32x4 qa, qb;
    asm volatile(
      "global_load_dwordx4 %0, %2, off sc0 sc1\n\t"
      "global_load_dwordx4 %1, %3, off sc0 sc1"
      : "=&v"(qa), "=&v"(qb)
      : "v"(hsrc + so0), "v"(hsrc + so1)
      : "memory");
    asm volatile("s_waitcnt vmcnt(0)" ::: "memory");
    *(u32x4*)sl0 = qa;
    *(u32x4*)sl1 = qb;
    // 3. next-step xg prefetch (plain cached loads), off the stage critical path
    float4 pxn[3];
    if (ks == 0 && t < 63) {
      int ts1 = dir ? (62 - t) : (t + 1);
      long xb = (long)(batch * 64 + ts1) * 3072 + dir * 1536 + i0;
#pragma unroll
      for (int g = 0; g < 3; ++g) pxn[g] = *(const float4*)&xg[xb + g * 512];
    }
    asm volatile("s_waitcnt lgkmcnt(0)\n\ts_barrier" ::: "memory");
    // 4. fragments from LDS + MFMA  (stride kk*64: 8 k-chunks x 64B per wave)
    floatx4 acc[3];
#pragma unroll
    for (int g = 0; g < 3; ++g) acc[g] = z4;
#pragma unroll
    for (int kk = 0; kk < 8; ++kk) {
      short8 hv = *(const short8*)((const char*)hstage + ((rb + kk * 64) ^ rsw));
#pragma unroll
      for (int g = 0; g < 3; ++g)
        acc[g] = __builtin_amdgcn_mfma_f32_16x16x32_bf16(wfrag[g][kk], hv, acc[g], 0, 0, 0);
    }
    if (ks == 1) {
#pragma unroll
      for (int g = 0; g < 3; ++g) *(floatx4*)&part[par][ih][g][lane * 4] = acc[g];
    }
    // LDS-only barrier: order ks1 ds_writes before ks0 ds_reads; no vmcnt drain.
    asm volatile("s_waitcnt lgkmcnt(0)\n\ts_barrier" ::: "memory");
    if (ks == 0) {
      int tsrc = dir ? (63 - t) : t;
#pragma unroll
      for (int g = 0; g < 3; ++g) acc[g] += *(const floatx4*)&part[par][ih][g][lane * 4];
      float4 hn4;
#pragma unroll
      for (int q = 0; q < 4; ++q) {
        float rr = acc[0][q] + ((const float*)&bh4[0])[q] + ((const float*)&px[0])[q];
        float zz = acc[1][q] + ((const float*)&bh4[1])[q] + ((const float*)&px[1])[q];
        float r = 1.f / (1.f + __expf(-rr));
        float z = 1.f / (1.f + __expf(-zz));
        float n = tanhf(((const float*)&px[2])[q] + r * (acc[2][q] + ((const float*)&bh4[2])[q]));
        ((float*)&hn4)[q] = (1.f - z) * n + z * ((const float*)&hprev)[q];
      }
      hprev = hn4;
      u16* hdst = hbuf + (long)(((par ^ 1) * 2 + dir) * 128 + bt * 16) * 512;
      u64 hval = pack4(hn4.x, hn4.y, hn4.z, hn4.w);
      asm volatile("global_store_dwordx2 %0, %1, off sc0 sc1"
                   :: "v"((u64*)&hdst[r16 * 512 + i0]), "v"(hval) : "memory");
      if (t < 63) {
        // drain own stores (h store visible), then publish per-wave flag
        asm volatile("s_waitcnt vmcnt(0)" ::: "memory");
        if (lane == 0) {
          int tv = t + 1;
          asm volatile("global_store_dword %0, %1, off sc0 sc1"
                       :: "v"(&flg[pubidx]), "v"(tv) : "memory");
        }
      }
      // hs store off the critical path (drains at next step's vmcnt(0))
      *(float4*)&hs[(long)(batch * 64 + tsrc) * 1024 + dir * 512 + i0] = hn4;
      px[0] = pxn[0]; px[1] = pxn[1]; px[2] = pxn[2];
    }
  }
}

// ---------------- mask + mean-pool + feature assembly ----------------
__global__ __launch_bounds__(256) void k_mask_pool(
    const float* __restrict__ hs, const int* __restrict__ lengths,
    const float* __restrict__ vo, const float* __restrict__ mo,
    u16* __restrict__ maskedb, u16* __restrict__ feat)
{
  int b = blockIdx.x, tid = threadIdx.x;
  int len = lengths[b];
  float inv = 1.0f / (float)len;
  int c0 = tid * 4;
  float s0 = 0.f, s1 = 0.f, s2 = 0.f, s3 = 0.f;
  for (int t = 0; t < 64; ++t) {
    float4 v = *(const float4*)&hs[(long)(b * 64 + t) * 1024 + c0];
    u64 pk = 0ull;
    if (t < len) {
      s0 += v.x; s1 += v.y; s2 += v.z; s3 += v.w;
      pk = pack4(v.x, v.y, v.z, v.w);
    }
    *(u64*)&maskedb[(long)(b * 64 + t) * 1024 + c0] = pk;
  }
  u16* fb = feat + (long)b * 5632;
  *(u64*)&fb[c0] = pack4(s0 * inv, s1 * inv, s2 * inv, s3 * inv);
  {
    int c = tid * 8;
    float4 a = *(const float4*)&vo[(long)b * 2048 + c];
    float4 d = *(const float4*)&vo[(long)b * 2048 + c + 4];
    *(u64*)&fb[2560 + c] = pack4(a.x, a.y, a.z, a.w);
    *(u64*)&fb[2560 + c + 4] = pack4(d.x, d.y, d.z, d.w);
  }
  {
    float4 a = *(const float4*)&mo[(long)b * 1024 + c0];
    *(u64*)&fb[4608 + c0] = pack4(a.x, a.y, a.z, a.w);
  }
}

// ---------------- conv shift-add + relu + max over positions (z is bf16) ----------------
// R5: 256 threads/block, each thread owns an adjacent k-pair and loads u32
// (4B/lane, G13) instead of scalar u16 (2B/lane) -> half the load instructions.
__global__ __launch_bounds__(256) void k_conv_finish(
    const u16* __restrict__ z, const float* __restrict__ cb2,
    const float* __restrict__ cb3, const float* __restrict__ cb4,
    u16* __restrict__ feat)
{
  int b = blockIdx.x, wsi = blockIdx.y, k2 = threadIdx.x * 2;
  int ws = wsi + 2;
  int base = (wsi == 0) ? 0 : (wsi == 1 ? 1024 : 2560);
  const float* cb = (wsi == 0) ? cb2 : (wsi == 1 ? cb3 : cb4);
  float bias0 = cb[k2], bias1 = cb[k2 + 1];
  float m0 = 0.f, m1 = 0.f;  // relu floor
  for (int p = 0; p < 64 + ws - 1; ++p) {
    float a0 = bias0, a1 = bias1;
    for (int j = 0; j < ws; ++j) {
      int t = p - (ws - 1) + j;
      if (t >= 0 && t < 64) {
        u32 v = *(const u32*)&z[(long)(b * 64 + t) * 4608 + base + j * 512 + k2];
        a0 += bf2f((u16)v);
        a1 += bf2f((u16)(v >> 16));
      }
    }
    m0 = fmaxf(m0, a0);
    m1 = fmaxf(m1, a1);
  }
  *(u32*)&feat[(long)b * 5632 + 1024 + wsi * 512 + k2] = (u32)f2bf(m0) | ((u32)f2bf(m1) << 16);
}

// ---------------- split-K reduce + BN + row L2 normalize (8 partials) ----------------
__global__ __launch_bounds__(256) void k_l2norm(const float* __restrict__ p,
    const float* __restrict__ bns, const float* __restrict__ bnt, float* __restrict__ out)
{
  __shared__ float red[4];
  int b = blockIdx.x, tid = threadIdx.x;
  float v[8]; float s = 0.f;
#pragma unroll
  for (int j = 0; j < 8; ++j) {
    int i = j * 256 + tid;
    long o = (long)b * 2048 + i;
    float a = 0.f;
#pragma unroll
    for (int zz = 0; zz < 8; ++zz) a += p[o + (long)zz * 262144];
    a = a * bns[i] + bnt[i];
    v[j] = a; s += a * a;
  }
#pragma unroll
  for (int o = 32; o > 0; o >>= 1) s += __shfl_down(s, o);
  if ((tid & 63) == 0) red[tid >> 6] = s;
  __syncthreads();
  float rn = rsqrtf(red[0] + red[1] + red[2] + red[3]);
#pragma unroll
  for (int j = 0; j < 8; ++j)
    out[(long)b * 2048 + j * 256 + tid] = v[j] * rn;
}

// ---------------- launch ----------------
extern "C" void kernel_launch(void* const* d_in, const int* in_sizes, int n_in,
                              void* d_out, int out_size, void* d_ws, size_t ws_size,
                              hipStream_t stream)
{
  (void)in_sizes; (void)n_in; (void)out_size; (void)ws_size;
  const float* videos       = (const float*)d_in[0];
  const float* motions      = (const float*)d_in[1];
  const float* videos_origin= (const float*)d_in[2];
  const int*   lengths      = (const int*)d_in[3];
  const float* Wih_f = (const float*)d_in[4];
  const float* Whh_f = (const float*)d_in[5];
  const float* bih_f = (const float*)d_in[6];
  const float* bhh_f = (const float*)d_in[7];
  const float* Wih_b = (const float*)d_in[8];
  const float* Whh_b = (const float*)d_in[9];
  const float* bih_b = (const float*)d_in[10];
  const float* bhh_b = (const float*)d_in[11];
  const float* fc_w  = (const float*)d_in[12];
  const float* fc_b  = (const float*)d_in[13];
  const float* bn_gamma = (const float*)d_in[14];
  const float* bn_beta  = (const float*)d_in[15];
  const float* bn_mean  = (const float*)d_in[16];
  const float* bn_var   = (const float*)d_in[17];
  const float* conv_w2 = (const float*)d_in[18];
  const float* conv_b2 = (const float*)d_in[19];
  const float* conv_w3 = (const float*)d_in[20];
  const float* conv_b3 = (const float*)d_in[21];
  const float* conv_w4 = (const float*)d_in[22];
  const float* conv_b4 = (const float*)d_in[23];
  float* out = (float*)d_out;
  char* w = (char*)d_ws;

  // workspace layout (bytes). z (bf16) overlays XG; FC split-K partials overlay MASKB.
  const size_t XG    = 0;              // 8192x3072 f32 = 100,663,296
  const size_t HS    = 100663296;      // 128x64x1024 f32 = 33,554,432
  const size_t VID   = 134217728;      // 8192x2048 bf16 = 33,554,432
  const size_t MASKB = 167772160;      // 8192x1024 bf16 = 16,777,216 (FC partials 8MB overlay)
  const size_t WIH   = 184549376;      // 3072x2048 bf16 = 12,582,912
  const size_t WHH   = 197132288;      // 2x1536x512 bf16 = 3,145,728
  const size_t WC    = 200278016;      // 4608x1024 bf16 = 9,437,184
  const size_t FCW   = 209715200;      // 2048x5632 bf16 = 23,068,672
  const size_t FEAT  = 232783872;      // 128x5632 bf16 = 1,441,792
  const size_t BIH   = 235274240;      // 3072 f32
  const size_t BNS   = 235286528;      // 2048 f32
  const size_t BNT   = 235294720;      // 2048 f32
  const size_t HB    = 235302912;      // 2x2x128x512 bf16 = 524,288
  const size_t FLG   = HB + 524288;    // 512 flags x 64B = 32,768

  float* xg   = (float*)(w + XG);
  u16*   zb16 = (u16*)(w + XG);        // overlay
  float* hs   = (float*)(w + HS);
  u16* vid    = (u16*)(w + VID);
  u16* maskb  = (u16*)(w + MASKB);
  float* fcp  = (float*)(w + MASKB);   // FC split-K partials overlay (after conv GEMM)
  u16* wih    = (u16*)(w + WIH);
  u16* whh    = (u16*)(w + WHH);
  u16* wc_    = (u16*)(w + WC);
  u16* fcw    = (u16*)(w + FCW);
  u16* feat   = (u16*)(w + FEAT);
  float* bih  = (float*)(w + BIH);
  float* bns  = (float*)(w + BNS);
  float* bnt  = (float*)(w + BNT);
  u16* hb     = (u16*)(w + HB);
  int* flg    = (int*)(w + FLG);

  // zero h double-buffer (parity0 read at t=0) + flags, every launch
  hipMemsetAsync(w + HB, 0, 524288 + 32768, stream);

  k_cvt<<<4096, 256, 0, stream>>>(videos, vid, 16777216 / 4);
  k_cvt<<<1024, 256, 0, stream>>>(Wih_f, wih, 3145728 / 4);
  k_cvt<<<1024, 256, 0, stream>>>(Wih_b, wih + 3145728, 3145728 / 4);
  k_cvt<<<512, 256, 0, stream>>>(Whh_f, whh, 786432 / 4);
  k_cvt<<<512, 256, 0, stream>>>(Whh_b, whh + 786432, 786432 / 4);
  k_cvt<<<2048, 256, 0, stream>>>(fc_w, fcw, 11534336 / 4);
  k_cvt_wc<<<2048, 256, 0, stream>>>(conv_w2, conv_w3, conv_w4, wc_);
  k_prep<<<12, 256, 0, stream>>>(bih_f, bih_b, fc_b, bn_gamma, bn_beta, bn_mean, bn_var, bih, bns, bnt);

  // xg = videos @ [Wih_f;Wih_b]^T + bih  (f32 out)
  gemm_bt<<<dim3(24, 64), 256, 0, stream>>>(vid, wih, xg, nullptr, 8192, 3072, 2048, 64, nullptr, bih);

  {
    const float* xg_c = xg; const u16* whh_c = whh;
    u16* hb_c = hb; float* hs_c = hs; int* flg_c = flg;
    const float* bf_c = bhh_f; const float* bb_c = bhh_b;
    void* args[] = { (void*)&xg_c, (void*)&whh_c, (void*)&bf_c, (void*)&bb_c,
                     (void*)&hb_c, (void*)&hs_c, (void*)&flg_c };
    hipLaunchCooperativeKernel(reinterpret_cast<void*>(gru_rec), dim3(128), dim3(512), args, 0, stream);
  }

  k_mask_pool<<<128, 256, 0, stream>>>(hs, lengths, videos_origin, motions, maskb, feat);
  // z = masked @ Wc^T  (9 shifted conv col-blocks), bf16 out
  gemm_bt<<<dim3(36, 64), 256, 0, stream>>>(maskb, wc_, nullptr, zb16, 8192, 4608, 1024, 32, nullptr, nullptr);
  k_conv_finish<<<dim3(128, 3), 256, 0, stream>>>(zb16, conv_b2, conv_b3, conv_b4, feat);
  // FC split-K x8 (raw partials; BN folded into l2norm)
  gemm_bt<<<dim3(16, 1, 8), 256, 0, stream>>>(feat, fcw, fcp, nullptr, 128, 2048, 5632, 22, nullptr, nullptr);
  k_l2norm<<<128, 256, 0, stream>>>(fcp, bns, bnt, out);
}

// Round 8
// 641.625 us; speedup vs baseline: 1.2886x; 1.0578x over previous
//
#include <hip/hip_runtime.h>
#include <hip/hip_bf16.h>
#include <stdint.h>

typedef __attribute__((ext_vector_type(8))) short short8;
typedef __attribute__((ext_vector_type(4))) float floatx4;
typedef __attribute__((ext_vector_type(4))) unsigned int u32x4;
typedef unsigned short u16;
typedef unsigned int u32;
typedef unsigned long long u64;

static __device__ __forceinline__ u16 f2bf(float f) {
  union { float f; u32 u; } v; v.f = f;
  return (u16)((v.u + 0x7fffu + ((v.u >> 16) & 1u)) >> 16);
}
static __device__ __forceinline__ float bf2f(u16 h) {
  union { u32 u; float f; } v; v.u = ((u32)h) << 16; return v.f;
}
static __device__ __forceinline__ u64 pack4(float a, float b, float c, float d) {
  return (u64)f2bf(a) | ((u64)f2bf(b) << 16) | ((u64)f2bf(c) << 32) | ((u64)f2bf(d) << 48);
}

// ---------------- fused conversions + prep + vo/mo feat assembly ----------------
// One grid-stride kernel over a unified quad (4-element) index space replaces
// 8 separate launches (6x k_cvt, k_cvt_wc, k_prep) + the vo/mo half of the old
// k_mask_pool. Same bytes moved; 7 fewer launch gaps.
__global__ __launch_bounds__(256) void k_fused_cvt(
    const float* __restrict__ videos, const float* __restrict__ Wih_f,
    const float* __restrict__ Wih_b, const float* __restrict__ Whh_f,
    const float* __restrict__ Whh_b, const float* __restrict__ fc_w,
    const float* __restrict__ w2, const float* __restrict__ w3,
    const float* __restrict__ w4, const float* __restrict__ vo,
    const float* __restrict__ mo, const float* __restrict__ bih_f,
    const float* __restrict__ bih_b, const float* __restrict__ fcb,
    const float* __restrict__ gam, const float* __restrict__ bet,
    const float* __restrict__ mu, const float* __restrict__ var,
    u16* __restrict__ vid, u16* __restrict__ wih, u16* __restrict__ whh,
    u16* __restrict__ fcw, u16* __restrict__ wc, u16* __restrict__ feat,
    float* __restrict__ bihcat, float* __restrict__ bns, float* __restrict__ bnt)
{
  const int O1 = 4194304;            // vid      (16777216 elems)
  const int O2 = O1 + 786432;        // wih_f    (3145728)
  const int O3 = O2 + 786432;        // wih_b
  const int O4 = O3 + 196608;        // whh_f    (786432)
  const int O5 = O4 + 196608;        // whh_b
  const int O6 = O5 + 2883584;       // fcw      (11534336)
  const int O7 = O6 + 1179648;       // wc       (4718592, remapped)
  const int O8 = O7 + 65536;         // vo->feat (128x2048)
  const int O9 = O8 + 32768;         // mo->feat (128x1024)
  const int NQ = O9 + 1280;          // 768 bihcat quads + 512 bn quads
  for (int q = blockIdx.x * 256 + threadIdx.x; q < NQ; q += gridDim.x * 256) {
    if (q < O1) {
      float4 v = ((const float4*)videos)[q];
      ((u64*)vid)[q] = pack4(v.x, v.y, v.z, v.w);
    } else if (q < O2) {
      int r = q - O1; float4 v = ((const float4*)Wih_f)[r];
      ((u64*)wih)[r] = pack4(v.x, v.y, v.z, v.w);
    } else if (q < O3) {
      int r = q - O2; float4 v = ((const float4*)Wih_b)[r];
      ((u64*)wih)[r + 786432] = pack4(v.x, v.y, v.z, v.w);
    } else if (q < O4) {
      int r = q - O3; float4 v = ((const float4*)Whh_f)[r];
      ((u64*)whh)[r] = pack4(v.x, v.y, v.z, v.w);
    } else if (q < O5) {
      int r = q - O4; float4 v = ((const float4*)Whh_b)[r];
      ((u64*)whh)[r + 196608] = pack4(v.x, v.y, v.z, v.w);
    } else if (q < O6) {
      int r = q - O5; float4 v = ((const float4*)fc_w)[r];
      ((u64*)fcw)[r] = pack4(v.x, v.y, v.z, v.w);
    } else if (q < O7) {
      // conv weights (K,1,ws,1024) -> Wc[4608][1024], rows = [ws2: j*512+k | ws3 | ws4]
      int r = q - O6;
      int e = r << 2;
      int row = e >> 10, col = e & 1023;
      const float* src;
      if (row < 1024)      { int j = row >> 9, k = row & 511;                 src = w2 + (k * 2 + j) * 1024; }
      else if (row < 2560) { int m = row - 1024; int j = m >> 9, k = m & 511; src = w3 + (k * 3 + j) * 1024; }
      else                 { int m = row - 2560; int j = m >> 9, k = m & 511; src = w4 + (k * 4 + j) * 1024; }
      float4 v = *(const float4*)(src + col);
      ((u64*)wc)[r] = pack4(v.x, v.y, v.z, v.w);
    } else if (q < O8) {
      int r = q - O7; int b = r >> 9, c = (r & 511) * 4;
      float4 v = *(const float4*)&vo[(long)b * 2048 + c];
      *(u64*)&feat[(long)b * 5632 + 2560 + c] = pack4(v.x, v.y, v.z, v.w);
    } else if (q < O9) {
      int r = q - O8; int b = r >> 8, c = (r & 255) * 4;
      float4 v = *(const float4*)&mo[(long)b * 1024 + c];
      *(u64*)&feat[(long)b * 5632 + 4608 + c] = pack4(v.x, v.y, v.z, v.w);
    } else {
      int r = q - O9;
      if (r < 768) {
        int i = r * 4;  // 1536 % 4 == 0: quad never straddles f/b boundary
        const float* s = (i < 1536) ? (bih_f + i) : (bih_b + (i - 1536));
        *(float4*)&bihcat[i] = *(const float4*)s;
      } else {
        int i = (r - 768) * 4;
#pragma unroll
        for (int j = 0; j < 4; ++j) {
          int idx = i + j;
          float sc = gam[idx] * rsqrtf(var[idx] + 1e-5f);
          bns[idx] = sc;
          bnt[idx] = sc * (fcb[idx] - mu[idx]) + bet[idx];
        }
      }
    }
  }
}

// ---------------- generic bf16 MFMA GEMM: C[M,N] = A[M,K] * B[N,K]^T
// R7: XCD-aware bijective blockIdx swizzle (all launch grids have nwg%8==0):
// each XCD gets a contiguous chunk of linear tile indices, sweeping N fastest,
// so consecutive tiles on one XCD share the A row-panel in that XCD's L2.
static __device__ __forceinline__ void gload_lds16(const u16* g, u16* l) {
  __builtin_amdgcn_global_load_lds((const __attribute__((address_space(1))) u32*)(const void*)g,
                                   (__attribute__((address_space(3))) u32*)(void*)l, 16, 0, 0);
}

__global__ __launch_bounds__(256) void gemm_bt(
    const u16* __restrict__ A, const u16* __restrict__ Bm,
    float* __restrict__ C, u16* __restrict__ C16, int M, int N, int K, int kn,
    const float* __restrict__ scale, const float* __restrict__ shift)
{
  __shared__ u16 As[128 * 32];
  __shared__ u16 Bs[128 * 32];
  int tid = threadIdx.x, lane = tid & 63, wid = tid >> 6;
  // XCD swizzle (requires nwg % 8 == 0; true for all launches here)
  int nwg = gridDim.x * gridDim.y;
  int lin = blockIdx.y * gridDim.x + blockIdx.x;
  int q8 = nwg >> 3;
  int swz = (lin & 7) * q8 + (lin >> 3);
  int m0 = (swz / gridDim.x) * 128, n0 = (swz % gridDim.x) * 128;
  int kt0 = blockIdx.z * kn;
  int wr = wid >> 1, wc = wid & 1;
  int r16 = lane & 15, kq = lane >> 4;
  const floatx4 z4 = {0.f, 0.f, 0.f, 0.f};
  floatx4 acc[4][4];
#pragma unroll
  for (int i = 0; i < 4; ++i)
#pragma unroll
    for (int j = 0; j < 4; ++j) acc[i][j] = z4;
  for (int kt = kt0; kt < kt0 + kn; ++kt) {
    __syncthreads();
#pragma unroll
    for (int inst = 0; inst < 2; ++inst) {
      int g = inst * 256 + tid;
      int row = g >> 2, cb = g & 3;
      const u16* ga = A + (long)(m0 + row) * K + kt * 32 + cb * 8;
      const u16* gb = Bm + (long)(n0 + row) * K + kt * 32 + cb * 8;
      gload_lds16(ga, &As[(inst * 256 + wid * 64) * 8]);
      gload_lds16(gb, &Bs[(inst * 256 + wid * 64) * 8]);
    }
    __syncthreads();
    short8 af[4], bf[4];
#pragma unroll
    for (int mt = 0; mt < 4; ++mt) af[mt] = *(const short8*)&As[(wr * 64 + mt * 16 + r16) * 32 + kq * 8];
#pragma unroll
    for (int nt = 0; nt < 4; ++nt) bf[nt] = *(const short8*)&Bs[(wc * 64 + nt * 16 + r16) * 32 + kq * 8];
#pragma unroll
    for (int mt = 0; mt < 4; ++mt)
#pragma unroll
      for (int nt = 0; nt < 4; ++nt)
        acc[mt][nt] = __builtin_amdgcn_mfma_f32_16x16x32_bf16(af[mt], bf[nt], acc[mt][nt], 0, 0, 0);
  }
  float* Cp = C + (long)blockIdx.z * M * N;
#pragma unroll
  for (int nt = 0; nt < 4; ++nt) {
    int col = n0 + wc * 64 + nt * 16 + r16;
    float sc = scale ? scale[col] : 1.f;
    float sh = shift ? shift[col] : 0.f;
#pragma unroll
    for (int mt = 0; mt < 4; ++mt)
#pragma unroll
      for (int q = 0; q < 4; ++q) {
        int row = m0 + wr * 64 + mt * 16 + kq * 4 + q;
        float v = acc[mt][nt][q] * sc + sh;
        if (C16) C16[(long)row * N + col] = f2bf(v);
        else     Cp[(long)row * N + col] = v;
      }
  }
}

// ---------------- GRU recurrence ----------------
// R6 core (R2 protocol, 217us, proven correct) + R7 epilogue fusion:
// instead of storing hs (f32, 33.5MB) and re-reading it in a separate
// mask+pool kernel, the ks0 lanes (which hold every h_t in registers) apply
// the t<len mask inline, store maskb (bf16) directly, and accumulate the
// mean-pool sum in registers; feat's gru section is written after the loop.
// Same f32 values enter the mean as before (hs was an exact f32 copy of hn4).
// Sync protocol untouched: h store sc0sc1 -> vmcnt(0) ack drain -> per-wave
// flag store; single poller wave + s_sleep; raw s_barrier release.
__global__ __launch_bounds__(512) void gru_rec(
    const float* __restrict__ xg,     // [8192][3072]
    const u16* __restrict__ whhb,     // [2][1536][512] bf16
    const float* __restrict__ bhh_f, const float* __restrict__ bhh_b,
    u16* __restrict__ hbuf,           // [2 parity][2 dir][128][512] bf16 (zeroed each launch)
    u16* __restrict__ maskb,          // [8192][1024] bf16 masked output
    u16* __restrict__ feat,           // [128][5632] bf16 (gru mean section)
    const int* __restrict__ lengths,  // [128]
    int* __restrict__ flg)            // 512 flags x 16 ints (64B lines), zeroed each launch
{
  __shared__ float part[2][4][3][256];
  __shared__ u16 hstage[8192];        // 16KB: h[16 batches][512 i] bf16, XOR-swizzled
  int tid = threadIdx.x, lane = tid & 63, wid = tid >> 6;
  int bid = blockIdx.x;
  int dir = bid >> 6, rem = bid & 63, bt = rem >> 3, is = rem & 7;
  int ih = wid & 3, ks = wid >> 2;
  int gbase = (dir * 8 + bt) * 32;
  int r16 = lane & 15, kq = lane >> 4;
  int iglob = is * 64 + ih * 16 + r16;       // i index of this lane's weight rows
  int i0 = is * 64 + ih * 16 + kq * 4;       // i base of this lane's 4 outputs
  int batch = bt * 16 + r16;                 // this lane's output batch (global)
  int pollidx = (gbase + (lane & 31)) * 16;
  int pubidx = (gbase + is * 4 + ih) * 16;
  const float* bhh = dir ? bhh_b : bhh_f;
  const floatx4 z4 = {0.f, 0.f, 0.f, 0.f};
  int len = lengths[batch];

  short8 wfrag[3][8];
#pragma unroll
  for (int g = 0; g < 3; ++g) {
    const u16* wrow = whhb + (long)(dir * 1536 + g * 512 + iglob) * 512;
#pragma unroll
    for (int kk = 0; kk < 8; ++kk)
      wfrag[g][kk] = *(const short8*)&wrow[(ks * 8 + kk) * 32 + kq * 8];
  }
  float4 bh4[3];
#pragma unroll
  for (int g = 0; g < 3; ++g) bh4[g] = *(const float4*)&bhh[g * 512 + i0];
  float4 hprev = {0.f, 0.f, 0.f, 0.f};
  float4 msum = {0.f, 0.f, 0.f, 0.f};

  float4 px[3];
  if (ks == 0) {
    int ts0 = dir ? 63 : 0;
    long xb = (long)(batch * 64 + ts0) * 3072 + dir * 1536 + i0;
#pragma unroll
    for (int g = 0; g < 3; ++g) px[g] = *(const float4*)&xg[xb + g * 512];
  }

  // stage addressing: two 16B chunks per thread, rows 2*wid and 2*wid+1
  // (granule lane&7 -> conflict-free ds_write). swizzle byte ^= (row&7)<<4.
  int so0 = wid * 2048 + lane * 16;
  int so1 = so0 + 1024;
  char* sl0 = (char*)hstage + (so0 ^ (((so0 >> 10) & 7) << 4));
  char* sl1 = (char*)hstage + (so1 ^ (((so1 >> 10) & 7) << 4));
  // fragment read base: bytes r16*1024 + ks*512 + kq*16, swz (r16&7)<<4
  int rb = r16 * 1024 + ks * 512 + kq * 16;
  int rsw = (r16 & 7) << 4;

  for (int t = 0; t < 64; ++t) {
    // 1. wait for all group blocks to have finished step t-1.
    if (t > 0) {
      if (wid == 0) {
        while (true) {
          int v;
          asm volatile("global_load_dword %0, %1, off sc0 sc1\n\ts_waitcnt vmcnt(0)"
                       : "=v"(v) : "v"(&flg[pollidx]) : "memory");
          if (__all(v >= t)) break;
          __builtin_amdgcn_s_sleep(1);
        }
      }
      asm volatile("s_barrier" ::: "memory");
    }
    int par = t & 1;
    // 2. coalesced cooperative stage: h[16][512] bf16 (16KB) -> LDS (swizzled).
    const char* hsrc = (const char*)(hbuf + (long)((par * 2 + dir) * 128 + bt * 16) * 512);
    u32x4 qa, qb;
    asm volatile(
      "global_load_dwordx4 %0, %2, off sc0 sc1\n\t"
      "global_load_dwordx4 %1, %3, off sc0 sc1"
      : "=&v"(qa), "=&v"(qb)
      : "v"(hsrc + so0), "v"(hsrc + so1)
      : "memory");
    asm volatile("s_waitcnt vmcnt(0)" ::: "memory");
    *(u32x4*)sl0 = qa;
    *(u32x4*)sl1 = qb;
    // 3. next-step xg prefetch (plain cached loads), off the stage critical path
    float4 pxn[3];
    if (ks == 0 && t < 63) {
      int ts1 = dir ? (62 - t) : (t + 1);
      long xb = (long)(batch * 64 + ts1) * 3072 + dir * 1536 + i0;
#pragma unroll
      for (int g = 0; g < 3; ++g) pxn[g] = *(const float4*)&xg[xb + g * 512];
    }
    asm volatile("s_waitcnt lgkmcnt(0)\n\ts_barrier" ::: "memory");
    // 4. fragments from LDS + MFMA  (stride kk*64: 8 k-chunks x 64B per wave)
    floatx4 acc[3];
#pragma unroll
    for (int g = 0; g < 3; ++g) acc[g] = z4;
#pragma unroll
    for (int kk = 0; kk < 8; ++kk) {
      short8 hv = *(const short8*)((const char*)hstage + ((rb + kk * 64) ^ rsw));
#pragma unroll
      for (int g = 0; g < 3; ++g)
        acc[g] = __builtin_amdgcn_mfma_f32_16x16x32_bf16(wfrag[g][kk], hv, acc[g], 0, 0, 0);
    }
    if (ks == 1) {
#pragma unroll
      for (int g = 0; g < 3; ++g) *(floatx4*)&part[par][ih][g][lane * 4] = acc[g];
    }
    // LDS-only barrier: order ks1 ds_writes before ks0 ds_reads; no vmcnt drain.
    asm volatile("s_waitcnt lgkmcnt(0)\n\ts_barrier" ::: "memory");
    if (ks == 0) {
      int tsrc = dir ? (63 - t) : t;
#pragma unroll
      for (int g = 0; g < 3; ++g) acc[g] += *(const floatx4*)&part[par][ih][g][lane * 4];
      float4 hn4;
#pragma unroll
      for (int q = 0; q < 4; ++q) {
        float rr = acc[0][q] + ((const float*)&bh4[0])[q] + ((const float*)&px[0])[q];
        float zz = acc[1][q] + ((const float*)&bh4[1])[q] + ((const float*)&px[1])[q];
        float r = 1.f / (1.f + __expf(-rr));
        float z = 1.f / (1.f + __expf(-zz));
        float n = tanhf(((const float*)&px[2])[q] + r * (acc[2][q] + ((const float*)&bh4[2])[q]));
        ((float*)&hn4)[q] = (1.f - z) * n + z * ((const float*)&hprev)[q];
      }
      hprev = hn4;
      u16* hdst = hbuf + (long)(((par ^ 1) * 2 + dir) * 128 + bt * 16) * 512;
      u64 hval = pack4(hn4.x, hn4.y, hn4.z, hn4.w);
      asm volatile("global_store_dwordx2 %0, %1, off sc0 sc1"
                   :: "v"((u64*)&hdst[r16 * 512 + i0]), "v"(hval) : "memory");
      if (t < 63) {
        // drain own stores (h store visible), then publish per-wave flag
        asm volatile("s_waitcnt vmcnt(0)" ::: "memory");
        if (lane == 0) {
          int tv = t + 1;
          asm volatile("global_store_dword %0, %1, off sc0 sc1"
                       :: "v"(&flg[pubidx]), "v"(tv) : "memory");
        }
      }
      // masked output + mean accumulation, off the critical path
      // (store drains at next step's vmcnt(0), like the old hs store)
      bool mv = tsrc < len;
      *(u64*)&maskb[(long)(batch * 64 + tsrc) * 1024 + dir * 512 + i0] = mv ? hval : 0ull;
      if (mv) {
        msum.x += hn4.x; msum.y += hn4.y; msum.z += hn4.z; msum.w += hn4.w;
      }
      px[0] = pxn[0]; px[1] = pxn[1]; px[2] = pxn[2];
    }
  }
  if (ks == 0) {
    float inv = 1.0f / (float)len;
    *(u64*)&feat[(long)batch * 5632 + dir * 512 + i0] =
        pack4(msum.x * inv, msum.y * inv, msum.z * inv, msum.w * inv);
  }
}

// ---------------- conv shift-add + relu + max over positions (z is bf16) ----------------
// 256 threads/block, each thread owns an adjacent k-pair and loads u32
// (4B/lane, G13) instead of scalar u16 (2B/lane).
__global__ __launch_bounds__(256) void k_conv_finish(
    const u16* __restrict__ z, const float* __restrict__ cb2,
    const float* __restrict__ cb3, const float* __restrict__ cb4,
    u16* __restrict__ feat)
{
  int b = blockIdx.x, wsi = blockIdx.y, k2 = threadIdx.x * 2;
  int ws = wsi + 2;
  int base = (wsi == 0) ? 0 : (wsi == 1 ? 1024 : 2560);
  const float* cb = (wsi == 0) ? cb2 : (wsi == 1 ? cb3 : cb4);
  float bias0 = cb[k2], bias1 = cb[k2 + 1];
  float m0 = 0.f, m1 = 0.f;  // relu floor
  for (int p = 0; p < 64 + ws - 1; ++p) {
    float a0 = bias0, a1 = bias1;
    for (int j = 0; j < ws; ++j) {
      int t = p - (ws - 1) + j;
      if (t >= 0 && t < 64) {
        u32 v = *(const u32*)&z[(long)(b * 64 + t) * 4608 + base + j * 512 + k2];
        a0 += bf2f((u16)v);
        a1 += bf2f((u16)(v >> 16));
      }
    }
    m0 = fmaxf(m0, a0);
    m1 = fmaxf(m1, a1);
  }
  *(u32*)&feat[(long)b * 5632 + 1024 + wsi * 512 + k2] = (u32)f2bf(m0) | ((u32)f2bf(m1) << 16);
}

// ---------------- split-K reduce + BN + row L2 normalize (8 partials) ----------------
__global__ __launch_bounds__(256) void k_l2norm(const float* __restrict__ p,
    const float* __restrict__ bns, const float* __restrict__ bnt, float* __restrict__ out)
{
  __shared__ float red[4];
  int b = blockIdx.x, tid = threadIdx.x;
  float v[8]; float s = 0.f;
#pragma unroll
  for (int j = 0; j < 8; ++j) {
    int i = j * 256 + tid;
    long o = (long)b * 2048 + i;
    float a = 0.f;
#pragma unroll
    for (int zz = 0; zz < 8; ++zz) a += p[o + (long)zz * 262144];
    a = a * bns[i] + bnt[i];
    v[j] = a; s += a * a;
  }
#pragma unroll
  for (int o = 32; o > 0; o >>= 1) s += __shfl_down(s, o);
  if ((tid & 63) == 0) red[tid >> 6] = s;
  __syncthreads();
  float rn = rsqrtf(red[0] + red[1] + red[2] + red[3]);
#pragma unroll
  for (int j = 0; j < 8; ++j)
    out[(long)b * 2048 + j * 256 + tid] = v[j] * rn;
}

// ---------------- launch ----------------
extern "C" void kernel_launch(void* const* d_in, const int* in_sizes, int n_in,
                              void* d_out, int out_size, void* d_ws, size_t ws_size,
                              hipStream_t stream)
{
  (void)in_sizes; (void)n_in; (void)out_size; (void)ws_size;
  const float* videos       = (const float*)d_in[0];
  const float* motions      = (const float*)d_in[1];
  const float* videos_origin= (const float*)d_in[2];
  const int*   lengths      = (const int*)d_in[3];
  const float* Wih_f = (const float*)d_in[4];
  const float* Whh_f = (const float*)d_in[5];
  const float* bih_f = (const float*)d_in[6];
  const float* bhh_f = (const float*)d_in[7];
  const float* Wih_b = (const float*)d_in[8];
  const float* Whh_b = (const float*)d_in[9];
  const float* bih_b = (const float*)d_in[10];
  const float* bhh_b = (const float*)d_in[11];
  const float* fc_w  = (const float*)d_in[12];
  const float* fc_b  = (const float*)d_in[13];
  const float* bn_gamma = (const float*)d_in[14];
  const float* bn_beta  = (const float*)d_in[15];
  const float* bn_mean  = (const float*)d_in[16];
  const float* bn_var   = (const float*)d_in[17];
  const float* conv_w2 = (const float*)d_in[18];
  const float* conv_b2 = (const float*)d_in[19];
  const float* conv_w3 = (const float*)d_in[20];
  const float* conv_b3 = (const float*)d_in[21];
  const float* conv_w4 = (const float*)d_in[22];
  const float* conv_b4 = (const float*)d_in[23];
  float* out = (float*)d_out;
  char* w = (char*)d_ws;

  // workspace layout (bytes). z (bf16) overlays XG; FC split-K partials overlay MASKB.
  // HS region no longer used (hs eliminated; mask+pool fused into gru_rec).
  const size_t XG    = 0;              // 8192x3072 f32 = 100,663,296
  const size_t HS    = 100663296;      // (unused)
  const size_t VID   = 134217728;      // 8192x2048 bf16 = 33,554,432
  const size_t MASKB = 167772160;      // 8192x1024 bf16 = 16,777,216 (FC partials 8MB overlay)
  const size_t WIH   = 184549376;      // 3072x2048 bf16 = 12,582,912
  const size_t WHH   = 197132288;      // 2x1536x512 bf16 = 3,145,728
  const size_t WC    = 200278016;      // 4608x1024 bf16 = 9,437,184
  const size_t FCW   = 209715200;      // 2048x5632 bf16 = 23,068,672
  const size_t FEAT  = 232783872;      // 128x5632 bf16 = 1,441,792
  const size_t BIH   = 235274240;      // 3072 f32
  const size_t BNS   = 235286528;      // 2048 f32
  const size_t BNT   = 235294720;      // 2048 f32
  const size_t HB    = 235302912;      // 2x2x128x512 bf16 = 524,288
  const size_t FLG   = HB + 524288;    // 512 flags x 64B = 32,768
  (void)HS;

  float* xg   = (float*)(w + XG);
  u16*   zb16 = (u16*)(w + XG);        // overlay
  u16* vid    = (u16*)(w + VID);
  u16* maskb  = (u16*)(w + MASKB);
  float* fcp  = (float*)(w + MASKB);   // FC split-K partials overlay (after conv GEMM)
  u16* wih    = (u16*)(w + WIH);
  u16* whh    = (u16*)(w + WHH);
  u16* wc_    = (u16*)(w + WC);
  u16* fcw    = (u16*)(w + FCW);
  u16* feat   = (u16*)(w + FEAT);
  float* bih  = (float*)(w + BIH);
  float* bns  = (float*)(w + BNS);
  float* bnt  = (float*)(w + BNT);
  u16* hb     = (u16*)(w + HB);
  int* flg    = (int*)(w + FLG);

  // zero h double-buffer (parity0 read at t=0) + flags, every launch
  hipMemsetAsync(w + HB, 0, 524288 + 32768, stream);

  k_fused_cvt<<<4096, 256, 0, stream>>>(
      videos, Wih_f, Wih_b, Whh_f, Whh_b, fc_w, conv_w2, conv_w3, conv_w4,
      videos_origin, motions, bih_f, bih_b, fc_b, bn_gamma, bn_beta, bn_mean, bn_var,
      vid, wih, whh, fcw, wc_, feat, bih, bns, bnt);

  // xg = videos @ [Wih_f;Wih_b]^T + bih  (f32 out)
  gemm_bt<<<dim3(24, 64), 256, 0, stream>>>(vid, wih, xg, nullptr, 8192, 3072, 2048, 64, nullptr, bih);

  {
    const float* xg_c = xg; const u16* whh_c = whh;
    u16* hb_c = hb; u16* mb_c = maskb; u16* ft_c = feat;
    const int* len_c = lengths; int* flg_c = flg;
    const float* bf_c = bhh_f; const float* bb_c = bhh_b;
    void* args[] = { (void*)&xg_c, (void*)&whh_c, (void*)&bf_c, (void*)&bb_c,
                     (void*)&hb_c, (void*)&mb_c, (void*)&ft_c, (void*)&len_c, (void*)&flg_c };
    hipLaunchCooperativeKernel(reinterpret_cast<void*>(gru_rec), dim3(128), dim3(512), args, 0, stream);
  }

  // z = masked @ Wc^T  (9 shifted conv col-blocks), bf16 out
  gemm_bt<<<dim3(36, 64), 256, 0, stream>>>(maskb, wc_, nullptr, zb16, 8192, 4608, 1024, 32, nullptr, nullptr);
  k_conv_finish<<<dim3(128, 3), 256, 0, stream>>>(zb16, conv_b2, conv_b3, conv_b4, feat);
  // FC split-K x8 (raw partials; BN folded into l2norm)
  gemm_bt<<<dim3(16, 1, 8), 256, 0, stream>>>(feat, fcw, fcp, nullptr, 128, 2048, 5632, 22, nullptr, nullptr);
  k_l2norm<<<128, 256, 0, stream>>>(fcp, bns, bnt, out);
}

// Round 9
// 608.710 us; speedup vs baseline: 1.3583x; 1.0541x over previous
//
#include <hip/hip_runtime.h>
#include <hip/hip_bf16.h>
#include <stdint.h>

typedef __attribute__((ext_vector_type(8))) short short8;
typedef __attribute__((ext_vector_type(4))) float floatx4;
typedef __attribute__((ext_vector_type(4))) unsigned int u32x4;
typedef unsigned short u16;
typedef unsigned int u32;
typedef unsigned long long u64;

static __device__ __forceinline__ u16 f2bf(float f) {
  union { float f; u32 u; } v; v.f = f;
  return (u16)((v.u + 0x7fffu + ((v.u >> 16) & 1u)) >> 16);
}
static __device__ __forceinline__ float bf2f(u16 h) {
  union { u32 u; float f; } v; v.u = ((u32)h) << 16; return v.f;
}
static __device__ __forceinline__ u64 pack4(float a, float b, float c, float d) {
  return (u64)f2bf(a) | ((u64)f2bf(b) << 16) | ((u64)f2bf(c) << 32) | ((u64)f2bf(d) << 48);
}

// ---------------- fused conversions + prep + vo/mo feat assembly ----------------
__global__ __launch_bounds__(256) void k_fused_cvt(
    const float* __restrict__ videos, const float* __restrict__ Wih_f,
    const float* __restrict__ Wih_b, const float* __restrict__ Whh_f,
    const float* __restrict__ Whh_b, const float* __restrict__ fc_w,
    const float* __restrict__ w2, const float* __restrict__ w3,
    const float* __restrict__ w4, const float* __restrict__ vo,
    const float* __restrict__ mo, const float* __restrict__ bih_f,
    const float* __restrict__ bih_b, const float* __restrict__ fcb,
    const float* __restrict__ gam, const float* __restrict__ bet,
    const float* __restrict__ mu, const float* __restrict__ var,
    u16* __restrict__ vid, u16* __restrict__ wih, u16* __restrict__ whh,
    u16* __restrict__ fcw, u16* __restrict__ wc, u16* __restrict__ feat,
    float* __restrict__ bihcat, float* __restrict__ bns, float* __restrict__ bnt)
{
  const int O1 = 4194304;            // vid      (16777216 elems)
  const int O2 = O1 + 786432;        // wih_f    (3145728)
  const int O3 = O2 + 786432;        // wih_b
  const int O4 = O3 + 196608;        // whh_f    (786432)
  const int O5 = O4 + 196608;        // whh_b
  const int O6 = O5 + 2883584;       // fcw      (11534336)
  const int O7 = O6 + 1179648;       // wc       (4718592, remapped)
  const int O8 = O7 + 65536;         // vo->feat (128x2048)
  const int O9 = O8 + 32768;         // mo->feat (128x1024)
  const int NQ = O9 + 1280;          // 768 bihcat quads + 512 bn quads
  for (int q = blockIdx.x * 256 + threadIdx.x; q < NQ; q += gridDim.x * 256) {
    if (q < O1) {
      float4 v = ((const float4*)videos)[q];
      ((u64*)vid)[q] = pack4(v.x, v.y, v.z, v.w);
    } else if (q < O2) {
      int r = q - O1; float4 v = ((const float4*)Wih_f)[r];
      ((u64*)wih)[r] = pack4(v.x, v.y, v.z, v.w);
    } else if (q < O3) {
      int r = q - O2; float4 v = ((const float4*)Wih_b)[r];
      ((u64*)wih)[r + 786432] = pack4(v.x, v.y, v.z, v.w);
    } else if (q < O4) {
      int r = q - O3; float4 v = ((const float4*)Whh_f)[r];
      ((u64*)whh)[r] = pack4(v.x, v.y, v.z, v.w);
    } else if (q < O5) {
      int r = q - O4; float4 v = ((const float4*)Whh_b)[r];
      ((u64*)whh)[r + 196608] = pack4(v.x, v.y, v.z, v.w);
    } else if (q < O6) {
      int r = q - O5; float4 v = ((const float4*)fc_w)[r];
      ((u64*)fcw)[r] = pack4(v.x, v.y, v.z, v.w);
    } else if (q < O7) {
      int r = q - O6;
      int e = r << 2;
      int row = e >> 10, col = e & 1023;
      const float* src;
      if (row < 1024)      { int j = row >> 9, k = row & 511;                 src = w2 + (k * 2 + j) * 1024; }
      else if (row < 2560) { int m = row - 1024; int j = m >> 9, k = m & 511; src = w3 + (k * 3 + j) * 1024; }
      else                 { int m = row - 2560; int j = m >> 9, k = m & 511; src = w4 + (k * 4 + j) * 1024; }
      float4 v = *(const float4*)(src + col);
      ((u64*)wc)[r] = pack4(v.x, v.y, v.z, v.w);
    } else if (q < O8) {
      int r = q - O7; int b = r >> 9, c = (r & 511) * 4;
      float4 v = *(const float4*)&vo[(long)b * 2048 + c];
      *(u64*)&feat[(long)b * 5632 + 2560 + c] = pack4(v.x, v.y, v.z, v.w);
    } else if (q < O9) {
      int r = q - O8; int b = r >> 8, c = (r & 255) * 4;
      float4 v = *(const float4*)&mo[(long)b * 1024 + c];
      *(u64*)&feat[(long)b * 5632 + 4608 + c] = pack4(v.x, v.y, v.z, v.w);
    } else {
      int r = q - O9;
      if (r < 768) {
        int i = r * 4;
        const float* s = (i < 1536) ? (bih_f + i) : (bih_b + (i - 1536));
        *(float4*)&bihcat[i] = *(const float4*)s;
      } else {
        int i = (r - 768) * 4;
#pragma unroll
        for (int j = 0; j < 4; ++j) {
          int idx = i + j;
          float sc = gam[idx] * rsqrtf(var[idx] + 1e-5f);
          bns[idx] = sc;
          bnt[idx] = sc * (fcb[idx] - mu[idx]) + bet[idx];
        }
      }
    }
  }
}

static __device__ __forceinline__ void gload_lds16(const u16* g, u16* l) {
  __builtin_amdgcn_global_load_lds((const __attribute__((address_space(1))) u32*)(const void*)g,
                                   (__attribute__((address_space(3))) u32*)(void*)l, 16, 0, 0);
}

// ---------------- 256x256 8-phase bf16 GEMM: C[M,N] = A[M,K]*B[N,K]^T ----------------
// 512 threads = 8 waves (2M x 4N); BK=64; per-wave output 128x64 (8x4 16x16 frags).
// LDS = 8 half-tile slots of 16KB (128 rows x 64 cols bf16), 2 K-tile parities:
//   parity P: B0 @P*65536, B1 @+16K, A0 @+32K, A1 @+48K (bytes).
// Fragment reads XOR-swizzled (byte ^= (row&7)<<4); staging writes linearly with
// pre-swizzled GLOBAL source (rule: both-sides-or-neither) -> conflict-free b128.
// Schedule (derived, invariant-checked): per tile T phases p1..p4 compute C
// quadrants (2 m-frags x 4 n-frags x K=64 each = 16 MFMA) and stage:
//   p1: A0(T+1)  p2: A1(T+1)  p3: B0(T+2)  p4: B1(T+2)  [targets are dead regions]
// vmcnt(4) once per tile at p4-end BEFORE the closing barrier: the youngest
// half-tile needed by p1(T+1) has exactly 2 half-tiles (4 loads) issued after it,
// so after the barrier ALL waves' staging of tile T+1 has landed. Never drains to 0.
// Prologue stages tiles 0,1 (+vmcnt(8)); tail wraps issue indices mod NT
// (wrapped writes target dead regions, data never read) keeping the loop uniform.
static __device__ __forceinline__ void stage_half_256(
    const u16* __restrict__ Mat, long K, int rowbase, int ktile, u16* lregion,
    int tid, int wid)
{
  int srow = tid >> 3;
  int sce = (((tid >> 3) ^ tid) & 7) * 8;   // pre-swizzled source col (elems)
  const u16* g0 = Mat + (long)(rowbase + srow) * K + ktile * 64 + sce;
  const u16* g1 = Mat + (long)(rowbase + 64 + srow) * K + ktile * 64 + sce;
  gload_lds16(g0, lregion + wid * 512);
  gload_lds16(g1, lregion + 4096 + wid * 512);
}

__global__ __launch_bounds__(512) void gemm256(
    const u16* __restrict__ A, const u16* __restrict__ Bm,
    float* __restrict__ C, u16* __restrict__ C16, int M, int N, int K, int NT,
    const float* __restrict__ shift)
{
  __shared__ u16 lds[65536];   // 128 KB
  int tid = threadIdx.x, lane = tid & 63, wid = tid >> 6;
  int r16 = lane & 15, kq = lane >> 4;
  int wr = wid >> 2, wc = wid & 3;
  // XCD-bijective swizzle (nwg % 8 == 0 for all launches here)
  int nwg = gridDim.x * gridDim.y;
  int lin = blockIdx.y * gridDim.x + blockIdx.x;
  int q8 = nwg >> 3;
  int swz = (lin & 7) * q8 + (lin >> 3);
  int m0 = (swz / gridDim.x) * 256, n0 = (swz % gridDim.x) * 256;

  int fxor = (r16 & 7) << 4;
  int c0 = (kq * 16) ^ fxor;
  int c1 = c0 ^ 64;
  int brow0 = (wc & 1) * 64;
  const char* ldsc = (const char*)lds;

  const floatx4 z4 = {0.f, 0.f, 0.f, 0.f};
  floatx4 acc[8][4];
#pragma unroll
  for (int i = 0; i < 8; ++i)
#pragma unroll
    for (int j = 0; j < 4; ++j) acc[i][j] = z4;

  // prologue: stage tiles 0 and 1
  stage_half_256(Bm, K, n0,       0, lds,                 tid, wid);
  stage_half_256(Bm, K, n0 + 128, 0, lds + 8192,          tid, wid);
  stage_half_256(A,  K, m0,       0, lds + 16384,         tid, wid);
  stage_half_256(A,  K, m0 + 128, 0, lds + 24576,         tid, wid);
  stage_half_256(Bm, K, n0,       1, lds + 32768,         tid, wid);
  stage_half_256(Bm, K, n0 + 128, 1, lds + 32768 + 8192,  tid, wid);
  stage_half_256(A,  K, m0,       1, lds + 32768 + 16384, tid, wid);
  stage_half_256(A,  K, m0 + 128, 1, lds + 32768 + 24576, tid, wid);
  asm volatile("s_waitcnt vmcnt(8)" ::: "memory");
  asm volatile("s_barrier" ::: "memory");

#define MFMA_CLUSTER(q)                                                        \
  asm volatile("s_waitcnt lgkmcnt(0)" ::: "memory");                           \
  __builtin_amdgcn_sched_barrier(0);                                           \
  __builtin_amdgcn_s_setprio(1);                                               \
  _Pragma("unroll")                                                            \
  for (int s = 0; s < 2; ++s)                                                  \
    _Pragma("unroll")                                                          \
    for (int e = 0; e < 2; ++e)                                                \
      _Pragma("unroll")                                                        \
      for (int j = 0; j < 4; ++j)                                              \
        acc[(q)*2 + e][j] = __builtin_amdgcn_mfma_f32_16x16x32_bf16(           \
            af[e][s], bf[j][s], acc[(q)*2 + e][j], 0, 0, 0);                   \
  __builtin_amdgcn_s_setprio(0);

  for (int T = 0; T < NT; ++T) {
    int P = T & 1;
    int Tn1 = (T + 1 < NT) ? T + 1 : 0;
    int Tn2 = (T + 2 < NT) ? T + 2 : T + 2 - NT;
    const char* bbase = ldsc + P * 65536 + (wc >> 1) * 16384;
    const char* abase = ldsc + P * 65536 + 32768 + wr * 16384;
    short8 bf[4][2];
    // ---- phase 1: B-frags(8) + A q0(4); stage A0(T+1) ----
    {
#pragma unroll
      for (int j = 0; j < 4; ++j) {
        bf[j][0] = *(const short8*)(bbase + (brow0 + j * 16 + r16) * 128 + c0);
        bf[j][1] = *(const short8*)(bbase + (brow0 + j * 16 + r16) * 128 + c1);
      }
      short8 af[2][2];
#pragma unroll
      for (int e = 0; e < 2; ++e) {
        af[e][0] = *(const short8*)(abase + (e * 16 + r16) * 128 + c0);
        af[e][1] = *(const short8*)(abase + (e * 16 + r16) * 128 + c1);
      }
      stage_half_256(A, K, m0, Tn1, lds + (Tn1 & 1) * 32768 + 16384, tid, wid);
      asm volatile("s_barrier" ::: "memory");
      MFMA_CLUSTER(0)
      asm volatile("s_barrier" ::: "memory");
    }
    // ---- phase 2: A q1; stage A1(T+1) ----
    {
      short8 af[2][2];
#pragma unroll
      for (int e = 0; e < 2; ++e) {
        af[e][0] = *(const short8*)(abase + ((2 + e) * 16 + r16) * 128 + c0);
        af[e][1] = *(const short8*)(abase + ((2 + e) * 16 + r16) * 128 + c1);
      }
      stage_half_256(A, K, m0 + 128, Tn1, lds + (Tn1 & 1) * 32768 + 24576, tid, wid);
      asm volatile("s_barrier" ::: "memory");
      MFMA_CLUSTER(1)
      asm volatile("s_barrier" ::: "memory");
    }
    // ---- phase 3: A q2; stage B0(T+2) ----
    {
      short8 af[2][2];
#pragma unroll
      for (int e = 0; e < 2; ++e) {
        af[e][0] = *(const short8*)(abase + ((4 + e) * 16 + r16) * 128 + c0);
        af[e][1] = *(const short8*)(abase + ((4 + e) * 16 + r16) * 128 + c1);
      }
      stage_half_256(Bm, K, n0, Tn2, lds + P * 32768, tid, wid);
      asm volatile("s_barrier" ::: "memory");
      MFMA_CLUSTER(2)
      asm volatile("s_barrier" ::: "memory");
    }
    // ---- phase 4: A q3; stage B1(T+2); vmcnt(4) before closing barrier ----
    {
      short8 af[2][2];
#pragma unroll
      for (int e = 0; e < 2; ++e) {
        af[e][0] = *(const short8*)(abase + ((6 + e) * 16 + r16) * 128 + c0);
        af[e][1] = *(const short8*)(abase + ((6 + e) * 16 + r16) * 128 + c1);
      }
      stage_half_256(Bm, K, n0 + 128, Tn2, lds + P * 32768 + 8192, tid, wid);
      asm volatile("s_barrier" ::: "memory");
      MFMA_CLUSTER(3)
      asm volatile("s_waitcnt vmcnt(4)" ::: "memory");
      asm volatile("s_barrier" ::: "memory");
    }
  }
#undef MFMA_CLUSTER

  // epilogue
#pragma unroll
  for (int mf = 0; mf < 8; ++mf)
#pragma unroll
    for (int j = 0; j < 4; ++j) {
      int col = n0 + wc * 64 + j * 16 + r16;
      int row = m0 + wr * 128 + mf * 16 + kq * 4;
      if (C16) {
#pragma unroll
        for (int qq = 0; qq < 4; ++qq)
          C16[(long)(row + qq) * N + col] = f2bf(acc[mf][j][qq]);
      } else {
        float sh = shift ? shift[col] : 0.f;
#pragma unroll
        for (int qq = 0; qq < 4; ++qq)
          C[(long)(row + qq) * N + col] = acc[mf][j][qq] + sh;
      }
    }
}

// ---------------- 128x128 MFMA GEMM (kept for the small FC GEMM) ----------------
__global__ __launch_bounds__(256) void gemm_bt(
    const u16* __restrict__ A, const u16* __restrict__ Bm,
    float* __restrict__ C, u16* __restrict__ C16, int M, int N, int K, int kn,
    const float* __restrict__ scale, const float* __restrict__ shift)
{
  __shared__ u16 As[128 * 32];
  __shared__ u16 Bs[128 * 32];
  int tid = threadIdx.x, lane = tid & 63, wid = tid >> 6;
  int nwg = gridDim.x * gridDim.y;
  int lin = blockIdx.y * gridDim.x + blockIdx.x;
  int q8 = nwg >> 3;
  int swz = (lin & 7) * q8 + (lin >> 3);
  int m0 = (swz / gridDim.x) * 128, n0 = (swz % gridDim.x) * 128;
  int kt0 = blockIdx.z * kn;
  int wr = wid >> 1, wc = wid & 1;
  int r16 = lane & 15, kq = lane >> 4;
  const floatx4 z4 = {0.f, 0.f, 0.f, 0.f};
  floatx4 acc[4][4];
#pragma unroll
  for (int i = 0; i < 4; ++i)
#pragma unroll
    for (int j = 0; j < 4; ++j) acc[i][j] = z4;
  for (int kt = kt0; kt < kt0 + kn; ++kt) {
    __syncthreads();
#pragma unroll
    for (int inst = 0; inst < 2; ++inst) {
      int g = inst * 256 + tid;
      int row = g >> 2, cb = g & 3;
      const u16* ga = A + (long)(m0 + row) * K + kt * 32 + cb * 8;
      const u16* gb = Bm + (long)(n0 + row) * K + kt * 32 + cb * 8;
      gload_lds16(ga, &As[(inst * 256 + wid * 64) * 8]);
      gload_lds16(gb, &Bs[(inst * 256 + wid * 64) * 8]);
    }
    __syncthreads();
    short8 af[4], bf[4];
#pragma unroll
    for (int mt = 0; mt < 4; ++mt) af[mt] = *(const short8*)&As[(wr * 64 + mt * 16 + r16) * 32 + kq * 8];
#pragma unroll
    for (int nt = 0; nt < 4; ++nt) bf[nt] = *(const short8*)&Bs[(wc * 64 + nt * 16 + r16) * 32 + kq * 8];
#pragma unroll
    for (int mt = 0; mt < 4; ++mt)
#pragma unroll
      for (int nt = 0; nt < 4; ++nt)
        acc[mt][nt] = __builtin_amdgcn_mfma_f32_16x16x32_bf16(af[mt], bf[nt], acc[mt][nt], 0, 0, 0);
  }
  float* Cp = C + (long)blockIdx.z * M * N;
#pragma unroll
  for (int nt = 0; nt < 4; ++nt) {
    int col = n0 + wc * 64 + nt * 16 + r16;
    float sc = scale ? scale[col] : 1.f;
    float sh = shift ? shift[col] : 0.f;
#pragma unroll
    for (int mt = 0; mt < 4; ++mt)
#pragma unroll
      for (int q = 0; q < 4; ++q) {
        int row = m0 + wr * 64 + mt * 16 + kq * 4 + q;
        float v = acc[mt][nt][q] * sc + sh;
        if (C16) C16[(long)row * N + col] = f2bf(v);
        else     Cp[(long)row * N + col] = v;
      }
  }
}

// ---------------- GRU recurrence (R2 protocol, proven; R7 fused epilogue) ----------------
__global__ __launch_bounds__(512) void gru_rec(
    const float* __restrict__ xg,     // [8192][3072]
    const u16* __restrict__ whhb,     // [2][1536][512] bf16
    const float* __restrict__ bhh_f, const float* __restrict__ bhh_b,
    u16* __restrict__ hbuf,           // [2 parity][2 dir][128][512] bf16 (zeroed each launch)
    u16* __restrict__ maskb,          // [8192][1024] bf16 masked output
    u16* __restrict__ feat,           // [128][5632] bf16 (gru mean section)
    const int* __restrict__ lengths,  // [128]
    int* __restrict__ flg)            // 512 flags x 16 ints (64B lines), zeroed each launch
{
  __shared__ float part[2][4][3][256];
  __shared__ u16 hstage[8192];        // 16KB: h[16 batches][512 i] bf16, XOR-swizzled
  int tid = threadIdx.x, lane = tid & 63, wid = tid >> 6;
  int bid = blockIdx.x;
  int dir = bid >> 6, rem = bid & 63, bt = rem >> 3, is = rem & 7;
  int ih = wid & 3, ks = wid >> 2;
  int gbase = (dir * 8 + bt) * 32;
  int r16 = lane & 15, kq = lane >> 4;
  int iglob = is * 64 + ih * 16 + r16;
  int i0 = is * 64 + ih * 16 + kq * 4;
  int batch = bt * 16 + r16;
  int pollidx = (gbase + (lane & 31)) * 16;
  int pubidx = (gbase + is * 4 + ih) * 16;
  const float* bhh = dir ? bhh_b : bhh_f;
  const floatx4 z4 = {0.f, 0.f, 0.f, 0.f};
  int len = lengths[batch];

  short8 wfrag[3][8];
#pragma unroll
  for (int g = 0; g < 3; ++g) {
    const u16* wrow = whhb + (long)(dir * 1536 + g * 512 + iglob) * 512;
#pragma unroll
    for (int kk = 0; kk < 8; ++kk)
      wfrag[g][kk] = *(const short8*)&wrow[(ks * 8 + kk) * 32 + kq * 8];
  }
  float4 bh4[3];
#pragma unroll
  for (int g = 0; g < 3; ++g) bh4[g] = *(const float4*)&bhh[g * 512 + i0];
  float4 hprev = {0.f, 0.f, 0.f, 0.f};
  float4 msum = {0.f, 0.f, 0.f, 0.f};

  float4 px[3];
  if (ks == 0) {
    int ts0 = dir ? 63 : 0;
    long xb = (long)(batch * 64 + ts0) * 3072 + dir * 1536 + i0;
#pragma unroll
    for (int g = 0; g < 3; ++g) px[g] = *(const float4*)&xg[xb + g * 512];
  }

  int so0 = wid * 2048 + lane * 16;
  int so1 = so0 + 1024;
  char* sl0 = (char*)hstage + (so0 ^ (((so0 >> 10) & 7) << 4));
  char* sl1 = (char*)hstage + (so1 ^ (((so1 >> 10) & 7) << 4));
  int rb = r16 * 1024 + ks * 512 + kq * 16;
  int rsw = (r16 & 7) << 4;

  for (int t = 0; t < 64; ++t) {
    if (t > 0) {
      if (wid == 0) {
        while (true) {
          int v;
          asm volatile("global_load_dword %0, %1, off sc0 sc1\n\ts_waitcnt vmcnt(0)"
                       : "=v"(v) : "v"(&flg[pollidx]) : "memory");
          if (__all(v >= t)) break;
          __builtin_amdgcn_s_sleep(1);
        }
      }
      asm volatile("s_barrier" ::: "memory");
    }
    int par = t & 1;
    const char* hsrc = (const char*)(hbuf + (long)((par * 2 + dir) * 128 + bt * 16) * 512);
    u32x4 qa, qb;
    asm volatile(
      "global_load_dwordx4 %0, %2, off sc0 sc1\n\t"
      "global_load_dwordx4 %1, %3, off sc0 sc1"
      : "=&v"(qa), "=&v"(qb)
      : "v"(hsrc + so0), "v"(hsrc + so1)
      : "memory");
    asm volatile("s_waitcnt vmcnt(0)" ::: "memory");
    *(u32x4*)sl0 = qa;
    *(u32x4*)sl1 = qb;
    float4 pxn[3];
    if (ks == 0 && t < 63) {
      int ts1 = dir ? (62 - t) : (t + 1);
      long xb = (long)(batch * 64 + ts1) * 3072 + dir * 1536 + i0;
#pragma unroll
      for (int g = 0; g < 3; ++g) pxn[g] = *(const float4*)&xg[xb + g * 512];
    }
    asm volatile("s_waitcnt lgkmcnt(0)\n\ts_barrier" ::: "memory");
    floatx4 acc[3];
#pragma unroll
    for (int g = 0; g < 3; ++g) acc[g] = z4;
#pragma unroll
    for (int kk = 0; kk < 8; ++kk) {
      short8 hv = *(const short8*)((const char*)hstage + ((rb + kk * 64) ^ rsw));
#pragma unroll
      for (int g = 0; g < 3; ++g)
        acc[g] = __builtin_amdgcn_mfma_f32_16x16x32_bf16(wfrag[g][kk], hv, acc[g], 0, 0, 0);
    }
    if (ks == 1) {
#pragma unroll
      for (int g = 0; g < 3; ++g) *(floatx4*)&part[par][ih][g][lane * 4] = acc[g];
    }
    asm volatile("s_waitcnt lgkmcnt(0)\n\ts_barrier" ::: "memory");
    if (ks == 0) {
      int tsrc = dir ? (63 - t) : t;
#pragma unroll
      for (int g = 0; g < 3; ++g) acc[g] += *(const floatx4*)&part[par][ih][g][lane * 4];
      float4 hn4;
#pragma unroll
      for (int q = 0; q < 4; ++q) {
        float rr = acc[0][q] + ((const float*)&bh4[0])[q] + ((const float*)&px[0])[q];
        float zz = acc[1][q] + ((const float*)&bh4[1])[q] + ((const float*)&px[1])[q];
        float r = 1.f / (1.f + __expf(-rr));
        float z = 1.f / (1.f + __expf(-zz));
        float n = tanhf(((const float*)&px[2])[q] + r * (acc[2][q] + ((const float*)&bh4[2])[q]));
        ((float*)&hn4)[q] = (1.f - z) * n + z * ((const float*)&hprev)[q];
      }
      hprev = hn4;
      u16* hdst = hbuf + (long)(((par ^ 1) * 2 + dir) * 128 + bt * 16) * 512;
      u64 hval = pack4(hn4.x, hn4.y, hn4.z, hn4.w);
      asm volatile("global_store_dwordx2 %0, %1, off sc0 sc1"
                   :: "v"((u64*)&hdst[r16 * 512 + i0]), "v"(hval) : "memory");
      if (t < 63) {
        asm volatile("s_waitcnt vmcnt(0)" ::: "memory");
        if (lane == 0) {
          int tv = t + 1;
          asm volatile("global_store_dword %0, %1, off sc0 sc1"
                       :: "v"(&flg[pubidx]), "v"(tv) : "memory");
        }
      }
      bool mv = tsrc < len;
      *(u64*)&maskb[(long)(batch * 64 + tsrc) * 1024 + dir * 512 + i0] = mv ? hval : 0ull;
      if (mv) {
        msum.x += hn4.x; msum.y += hn4.y; msum.z += hn4.z; msum.w += hn4.w;
      }
      px[0] = pxn[0]; px[1] = pxn[1]; px[2] = pxn[2];
    }
  }
  if (ks == 0) {
    float inv = 1.0f / (float)len;
    *(u64*)&feat[(long)batch * 5632 + dir * 512 + i0] =
        pack4(msum.x * inv, msum.y * inv, msum.z * inv, msum.w * inv);
  }
}

// ---------------- conv shift-add + relu + max over positions (z is bf16) ----------------
__global__ __launch_bounds__(256) void k_conv_finish(
    const u16* __restrict__ z, const float* __restrict__ cb2,
    const float* __restrict__ cb3, const float* __restrict__ cb4,
    u16* __restrict__ feat)
{
  int b = blockIdx.x, wsi = blockIdx.y, k2 = threadIdx.x * 2;
  int ws = wsi + 2;
  int base = (wsi == 0) ? 0 : (wsi == 1 ? 1024 : 2560);
  const float* cb = (wsi == 0) ? cb2 : (wsi == 1 ? cb3 : cb4);
  float bias0 = cb[k2], bias1 = cb[k2 + 1];
  float m0 = 0.f, m1 = 0.f;
  for (int p = 0; p < 64 + ws - 1; ++p) {
    float a0 = bias0, a1 = bias1;
    for (int j = 0; j < ws; ++j) {
      int t = p - (ws - 1) + j;
      if (t >= 0 && t < 64) {
        u32 v = *(const u32*)&z[(long)(b * 64 + t) * 4608 + base + j * 512 + k2];
        a0 += bf2f((u16)v);
        a1 += bf2f((u16)(v >> 16));
      }
    }
    m0 = fmaxf(m0, a0);
    m1 = fmaxf(m1, a1);
  }
  *(u32*)&feat[(long)b * 5632 + 1024 + wsi * 512 + k2] = (u32)f2bf(m0) | ((u32)f2bf(m1) << 16);
}

// ---------------- split-K reduce + BN + row L2 normalize (8 partials) ----------------
__global__ __launch_bounds__(256) void k_l2norm(const float* __restrict__ p,
    const float* __restrict__ bns, const float* __restrict__ bnt, float* __restrict__ out)
{
  __shared__ float red[4];
  int b = blockIdx.x, tid = threadIdx.x;
  float v[8]; float s = 0.f;
#pragma unroll
  for (int j = 0; j < 8; ++j) {
    int i = j * 256 + tid;
    long o = (long)b * 2048 + i;
    float a = 0.f;
#pragma unroll
    for (int zz = 0; zz < 8; ++zz) a += p[o + (long)zz * 262144];
    a = a * bns[i] + bnt[i];
    v[j] = a; s += a * a;
  }
#pragma unroll
  for (int o = 32; o > 0; o >>= 1) s += __shfl_down(s, o);
  if ((tid & 63) == 0) red[tid >> 6] = s;
  __syncthreads();
  float rn = rsqrtf(red[0] + red[1] + red[2] + red[3]);
#pragma unroll
  for (int j = 0; j < 8; ++j)
    out[(long)b * 2048 + j * 256 + tid] = v[j] * rn;
}

// ---------------- launch ----------------
extern "C" void kernel_launch(void* const* d_in, const int* in_sizes, int n_in,
                              void* d_out, int out_size, void* d_ws, size_t ws_size,
                              hipStream_t stream)
{
  (void)in_sizes; (void)n_in; (void)out_size; (void)ws_size;
  const float* videos       = (const float*)d_in[0];
  const float* motions      = (const float*)d_in[1];
  const float* videos_origin= (const float*)d_in[2];
  const int*   lengths      = (const int*)d_in[3];
  const float* Wih_f = (const float*)d_in[4];
  const float* Whh_f = (const float*)d_in[5];
  const float* bih_f = (const float*)d_in[6];
  const float* bhh_f = (const float*)d_in[7];
  const float* Wih_b = (const float*)d_in[8];
  const float* Whh_b = (const float*)d_in[9];
  const float* bih_b = (const float*)d_in[10];
  const float* bhh_b = (const float*)d_in[11];
  const float* fc_w  = (const float*)d_in[12];
  const float* fc_b  = (const float*)d_in[13];
  const float* bn_gamma = (const float*)d_in[14];
  const float* bn_beta  = (const float*)d_in[15];
  const float* bn_mean  = (const float*)d_in[16];
  const float* bn_var   = (const float*)d_in[17];
  const float* conv_w2 = (const float*)d_in[18];
  const float* conv_b2 = (const float*)d_in[19];
  const float* conv_w3 = (const float*)d_in[20];
  const float* conv_b3 = (const float*)d_in[21];
  const float* conv_w4 = (const float*)d_in[22];
  const float* conv_b4 = (const float*)d_in[23];
  float* out = (float*)d_out;
  char* w = (char*)d_ws;

  const size_t XG    = 0;              // 8192x3072 f32 = 100,663,296
  const size_t VID   = 134217728;      // 8192x2048 bf16 = 33,554,432
  const size_t MASKB = 167772160;      // 8192x1024 bf16 = 16,777,216 (FC partials 8MB overlay)
  const size_t WIH   = 184549376;      // 3072x2048 bf16 = 12,582,912
  const size_t WHH   = 197132288;      // 2x1536x512 bf16 = 3,145,728
  const size_t WC    = 200278016;      // 4608x1024 bf16 = 9,437,184
  const size_t FCW   = 209715200;      // 2048x5632 bf16 = 23,068,672
  const size_t FEAT  = 232783872;      // 128x5632 bf16 = 1,441,792
  const size_t BIH   = 235274240;      // 3072 f32
  const size_t BNS   = 235286528;      // 2048 f32
  const size_t BNT   = 235294720;      // 2048 f32
  const size_t HB    = 235302912;      // 2x2x128x512 bf16 = 524,288
  const size_t FLG   = HB + 524288;    // 512 flags x 64B = 32,768

  float* xg   = (float*)(w + XG);
  u16*   zb16 = (u16*)(w + XG);        // overlay
  u16* vid    = (u16*)(w + VID);
  u16* maskb  = (u16*)(w + MASKB);
  float* fcp  = (float*)(w + MASKB);   // FC split-K partials overlay (after conv GEMM)
  u16* wih    = (u16*)(w + WIH);
  u16* whh    = (u16*)(w + WHH);
  u16* wc_    = (u16*)(w + WC);
  u16* fcw    = (u16*)(w + FCW);
  u16* feat   = (u16*)(w + FEAT);
  float* bih  = (float*)(w + BIH);
  float* bns  = (float*)(w + BNS);
  float* bnt  = (float*)(w + BNT);
  u16* hb     = (u16*)(w + HB);
  int* flg    = (int*)(w + FLG);

  hipMemsetAsync(w + HB, 0, 524288 + 32768, stream);

  k_fused_cvt<<<4096, 256, 0, stream>>>(
      videos, Wih_f, Wih_b, Whh_f, Whh_b, fc_w, conv_w2, conv_w3, conv_w4,
      videos_origin, motions, bih_f, bih_b, fc_b, bn_gamma, bn_beta, bn_mean, bn_var,
      vid, wih, whh, fcw, wc_, feat, bih, bns, bnt);

  // xg = videos @ [Wih_f;Wih_b]^T + bih  (f32 out), 256^2 8-phase
  gemm256<<<dim3(12, 32), 512, 0, stream>>>(vid, wih, xg, nullptr, 8192, 3072, 2048, 32, bih);

  {
    const float* xg_c = xg; const u16* whh_c = whh;
    u16* hb_c = hb; u16* mb_c = maskb; u16* ft_c = feat;
    const int* len_c = lengths; int* flg_c = flg;
    const float* bf_c = bhh_f; const float* bb_c = bhh_b;
    void* args[] = { (void*)&xg_c, (void*)&whh_c, (void*)&bf_c, (void*)&bb_c,
                     (void*)&hb_c, (void*)&mb_c, (void*)&ft_c, (void*)&len_c, (void*)&flg_c };
    hipLaunchCooperativeKernel(reinterpret_cast<void*>(gru_rec), dim3(128), dim3(512), args, 0, stream);
  }

  // z = masked @ Wc^T (bf16 out), 256^2 8-phase
  gemm256<<<dim3(18, 32), 512, 0, stream>>>(maskb, wc_, nullptr, zb16, 8192, 4608, 1024, 16, nullptr);
  k_conv_finish<<<dim3(128, 3), 256, 0, stream>>>(zb16, conv_b2, conv_b3, conv_b4, feat);
  // FC split-K x8 (raw partials; BN folded into l2norm)
  gemm_bt<<<dim3(16, 1, 8), 256, 0, stream>>>(feat, fcw, fcp, nullptr, 128, 2048, 5632, 22, nullptr, nullptr);
  k_l2norm<<<128, 256, 0, stream>>>(fcp, bns, bnt, out);
}

// Round 10
// 593.953 us; speedup vs baseline: 1.3921x; 1.0248x over previous
//
#include <hip/hip_runtime.h>
#include <hip/hip_bf16.h>
#include <stdint.h>

typedef __attribute__((ext_vector_type(8))) short short8;
typedef __attribute__((ext_vector_type(4))) float floatx4;
typedef __attribute__((ext_vector_type(4))) unsigned int u32x4;
typedef unsigned short u16;
typedef unsigned int u32;
typedef unsigned long long u64;

static __device__ __forceinline__ u16 f2bf(float f) {
  union { float f; u32 u; } v; v.f = f;
  return (u16)((v.u + 0x7fffu + ((v.u >> 16) & 1u)) >> 16);
}
static __device__ __forceinline__ float bf2f(u16 h) {
  union { u32 u; float f; } v; v.u = ((u32)h) << 16; return v.f;
}
static __device__ __forceinline__ u64 pack4(float a, float b, float c, float d) {
  return (u64)f2bf(a) | ((u64)f2bf(b) << 16) | ((u64)f2bf(c) << 32) | ((u64)f2bf(d) << 48);
}

// ---------------- pre-GEMM conversions (vid/wih/whh/bias only; rest co-runs with gru) ----------------
__global__ __launch_bounds__(256) void k_pre_cvt(
    const float* __restrict__ videos, const float* __restrict__ Wih_f,
    const float* __restrict__ Wih_b, const float* __restrict__ Whh_f,
    const float* __restrict__ Whh_b, const float* __restrict__ bih_f,
    const float* __restrict__ bih_b, const float* __restrict__ fcb,
    const float* __restrict__ gam, const float* __restrict__ bet,
    const float* __restrict__ mu, const float* __restrict__ var,
    u16* __restrict__ vid, u16* __restrict__ wih, u16* __restrict__ whh,
    float* __restrict__ bihcat, float* __restrict__ bns, float* __restrict__ bnt)
{
  const int O1 = 4194304;            // vid quads
  const int O2 = O1 + 786432;        // wih_f
  const int O3 = O2 + 786432;        // wih_b
  const int O4 = O3 + 196608;        // whh_f
  const int O5 = O4 + 196608;        // whh_b
  const int NQ = O5 + 1280;          // 768 bihcat quads + 512 bn quads
  for (int q = blockIdx.x * 256 + threadIdx.x; q < NQ; q += gridDim.x * 256) {
    if (q < O1) {
      float4 v = ((const float4*)videos)[q];
      ((u64*)vid)[q] = pack4(v.x, v.y, v.z, v.w);
    } else if (q < O2) {
      int r = q - O1; float4 v = ((const float4*)Wih_f)[r];
      ((u64*)wih)[r] = pack4(v.x, v.y, v.z, v.w);
    } else if (q < O3) {
      int r = q - O2; float4 v = ((const float4*)Wih_b)[r];
      ((u64*)wih)[r + 786432] = pack4(v.x, v.y, v.z, v.w);
    } else if (q < O4) {
      int r = q - O3; float4 v = ((const float4*)Whh_f)[r];
      ((u64*)whh)[r] = pack4(v.x, v.y, v.z, v.w);
    } else if (q < O5) {
      int r = q - O4; float4 v = ((const float4*)Whh_b)[r];
      ((u64*)whh)[r + 196608] = pack4(v.x, v.y, v.z, v.w);
    } else {
      int r = q - O5;
      if (r < 768) {
        int i = r * 4;  // 1536 % 4 == 0: quad never straddles f/b boundary
        const float* s = (i < 1536) ? (bih_f + i) : (bih_b + (i - 1536));
        *(float4*)&bihcat[i] = *(const float4*)s;
      } else {
        int i = (r - 768) * 4;
#pragma unroll
        for (int j = 0; j < 4; ++j) {
          int idx = i + j;
          float sc = gam[idx] * rsqrtf(var[idx] + 1e-5f);
          bns[idx] = sc;
          bnt[idx] = sc * (fcb[idx] - mu[idx]) + bet[idx];
        }
      }
    }
  }
}

static __device__ __forceinline__ void gload_lds16(const u16* g, u16* l) {
  __builtin_amdgcn_global_load_lds((const __attribute__((address_space(1))) u32*)(const void*)g,
                                   (__attribute__((address_space(3))) u32*)(void*)l, 16, 0, 0);
}

// ---------------- 256x256 8-phase bf16 GEMM (R8, proven) ----------------
static __device__ __forceinline__ void stage_half_256(
    const u16* __restrict__ Mat, long K, int rowbase, int ktile, u16* lregion,
    int tid, int wid)
{
  int srow = tid >> 3;
  int sce = (((tid >> 3) ^ tid) & 7) * 8;   // pre-swizzled source col (elems)
  const u16* g0 = Mat + (long)(rowbase + srow) * K + ktile * 64 + sce;
  const u16* g1 = Mat + (long)(rowbase + 64 + srow) * K + ktile * 64 + sce;
  gload_lds16(g0, lregion + wid * 512);
  gload_lds16(g1, lregion + 4096 + wid * 512);
}

__global__ __launch_bounds__(512) void gemm256(
    const u16* __restrict__ A, const u16* __restrict__ Bm,
    float* __restrict__ C, u16* __restrict__ C16, int M, int N, int K, int NT,
    const float* __restrict__ shift)
{
  __shared__ u16 lds[65536];   // 128 KB
  int tid = threadIdx.x, lane = tid & 63, wid = tid >> 6;
  int r16 = lane & 15, kq = lane >> 4;
  int wr = wid >> 2, wc = wid & 3;
  int nwg = gridDim.x * gridDim.y;
  int lin = blockIdx.y * gridDim.x + blockIdx.x;
  int q8 = nwg >> 3;
  int swz = (lin & 7) * q8 + (lin >> 3);
  int m0 = (swz / gridDim.x) * 256, n0 = (swz % gridDim.x) * 256;

  int fxor = (r16 & 7) << 4;
  int c0 = (kq * 16) ^ fxor;
  int c1 = c0 ^ 64;
  int brow0 = (wc & 1) * 64;
  const char* ldsc = (const char*)lds;

  const floatx4 z4 = {0.f, 0.f, 0.f, 0.f};
  floatx4 acc[8][4];
#pragma unroll
  for (int i = 0; i < 8; ++i)
#pragma unroll
    for (int j = 0; j < 4; ++j) acc[i][j] = z4;

  stage_half_256(Bm, K, n0,       0, lds,                 tid, wid);
  stage_half_256(Bm, K, n0 + 128, 0, lds + 8192,          tid, wid);
  stage_half_256(A,  K, m0,       0, lds + 16384,         tid, wid);
  stage_half_256(A,  K, m0 + 128, 0, lds + 24576,         tid, wid);
  stage_half_256(Bm, K, n0,       1, lds + 32768,         tid, wid);
  stage_half_256(Bm, K, n0 + 128, 1, lds + 32768 + 8192,  tid, wid);
  stage_half_256(A,  K, m0,       1, lds + 32768 + 16384, tid, wid);
  stage_half_256(A,  K, m0 + 128, 1, lds + 32768 + 24576, tid, wid);
  asm volatile("s_waitcnt vmcnt(8)" ::: "memory");
  asm volatile("s_barrier" ::: "memory");

#define MFMA_CLUSTER(q)                                                        \
  asm volatile("s_waitcnt lgkmcnt(0)" ::: "memory");                           \
  __builtin_amdgcn_sched_barrier(0);                                           \
  __builtin_amdgcn_s_setprio(1);                                               \
  _Pragma("unroll")                                                            \
  for (int s = 0; s < 2; ++s)                                                  \
    _Pragma("unroll")                                                          \
    for (int e = 0; e < 2; ++e)                                                \
      _Pragma("unroll")                                                        \
      for (int j = 0; j < 4; ++j)                                              \
        acc[(q)*2 + e][j] = __builtin_amdgcn_mfma_f32_16x16x32_bf16(           \
            af[e][s], bf[j][s], acc[(q)*2 + e][j], 0, 0, 0);                   \
  __builtin_amdgcn_s_setprio(0);

  for (int T = 0; T < NT; ++T) {
    int P = T & 1;
    int Tn1 = (T + 1 < NT) ? T + 1 : 0;
    int Tn2 = (T + 2 < NT) ? T + 2 : T + 2 - NT;
    const char* bbase = ldsc + P * 65536 + (wc >> 1) * 16384;
    const char* abase = ldsc + P * 65536 + 32768 + wr * 16384;
    short8 bf[4][2];
    {
#pragma unroll
      for (int j = 0; j < 4; ++j) {
        bf[j][0] = *(const short8*)(bbase + (brow0 + j * 16 + r16) * 128 + c0);
        bf[j][1] = *(const short8*)(bbase + (brow0 + j * 16 + r16) * 128 + c1);
      }
      short8 af[2][2];
#pragma unroll
      for (int e = 0; e < 2; ++e) {
        af[e][0] = *(const short8*)(abase + (e * 16 + r16) * 128 + c0);
        af[e][1] = *(const short8*)(abase + (e * 16 + r16) * 128 + c1);
      }
      stage_half_256(A, K, m0, Tn1, lds + (Tn1 & 1) * 32768 + 16384, tid, wid);
      asm volatile("s_barrier" ::: "memory");
      MFMA_CLUSTER(0)
      asm volatile("s_barrier" ::: "memory");
    }
    {
      short8 af[2][2];
#pragma unroll
      for (int e = 0; e < 2; ++e) {
        af[e][0] = *(const short8*)(abase + ((2 + e) * 16 + r16) * 128 + c0);
        af[e][1] = *(const short8*)(abase + ((2 + e) * 16 + r16) * 128 + c1);
      }
      stage_half_256(A, K, m0 + 128, Tn1, lds + (Tn1 & 1) * 32768 + 24576, tid, wid);
      asm volatile("s_barrier" ::: "memory");
      MFMA_CLUSTER(1)
      asm volatile("s_barrier" ::: "memory");
    }
    {
      short8 af[2][2];
#pragma unroll
      for (int e = 0; e < 2; ++e) {
        af[e][0] = *(const short8*)(abase + ((4 + e) * 16 + r16) * 128 + c0);
        af[e][1] = *(const short8*)(abase + ((4 + e) * 16 + r16) * 128 + c1);
      }
      stage_half_256(Bm, K, n0, Tn2, lds + P * 32768, tid, wid);
      asm volatile("s_barrier" ::: "memory");
      MFMA_CLUSTER(2)
      asm volatile("s_barrier" ::: "memory");
    }
    {
      short8 af[2][2];
#pragma unroll
      for (int e = 0; e < 2; ++e) {
        af[e][0] = *(const short8*)(abase + ((6 + e) * 16 + r16) * 128 + c0);
        af[e][1] = *(const short8*)(abase + ((6 + e) * 16 + r16) * 128 + c1);
      }
      stage_half_256(Bm, K, n0 + 128, Tn2, lds + P * 32768 + 8192, tid, wid);
      asm volatile("s_barrier" ::: "memory");
      MFMA_CLUSTER(3)
      asm volatile("s_waitcnt vmcnt(4)" ::: "memory");
      asm volatile("s_barrier" ::: "memory");
    }
  }
#undef MFMA_CLUSTER

#pragma unroll
  for (int mf = 0; mf < 8; ++mf)
#pragma unroll
    for (int j = 0; j < 4; ++j) {
      int col = n0 + wc * 64 + j * 16 + r16;
      int row = m0 + wr * 128 + mf * 16 + kq * 4;
      if (C16) {
#pragma unroll
        for (int qq = 0; qq < 4; ++qq)
          C16[(long)(row + qq) * N + col] = f2bf(acc[mf][j][qq]);
      } else {
        float sh = shift ? shift[col] : 0.f;
#pragma unroll
        for (int qq = 0; qq < 4; ++qq)
          C[(long)(row + qq) * N + col] = acc[mf][j][qq] + sh;
      }
    }
}

// ---------------- 128x128 MFMA GEMM (kept for the small FC GEMM) ----------------
__global__ __launch_bounds__(256) void gemm_bt(
    const u16* __restrict__ A, const u16* __restrict__ Bm,
    float* __restrict__ C, u16* __restrict__ C16, int M, int N, int K, int kn,
    const float* __restrict__ scale, const float* __restrict__ shift)
{
  __shared__ u16 As[128 * 32];
  __shared__ u16 Bs[128 * 32];
  int tid = threadIdx.x, lane = tid & 63, wid = tid >> 6;
  int nwg = gridDim.x * gridDim.y;
  int lin = blockIdx.y * gridDim.x + blockIdx.x;
  int q8 = nwg >> 3;
  int swz = (lin & 7) * q8 + (lin >> 3);
  int m0 = (swz / gridDim.x) * 128, n0 = (swz % gridDim.x) * 128;
  int kt0 = blockIdx.z * kn;
  int wr = wid >> 1, wc = wid & 1;
  int r16 = lane & 15, kq = lane >> 4;
  const floatx4 z4 = {0.f, 0.f, 0.f, 0.f};
  floatx4 acc[4][4];
#pragma unroll
  for (int i = 0; i < 4; ++i)
#pragma unroll
    for (int j = 0; j < 4; ++j) acc[i][j] = z4;
  for (int kt = kt0; kt < kt0 + kn; ++kt) {
    __syncthreads();
#pragma unroll
    for (int inst = 0; inst < 2; ++inst) {
      int g = inst * 256 + tid;
      int row = g >> 2, cb = g & 3;
      const u16* ga = A + (long)(m0 + row) * K + kt * 32 + cb * 8;
      const u16* gb = Bm + (long)(n0 + row) * K + kt * 32 + cb * 8;
      gload_lds16(ga, &As[(inst * 256 + wid * 64) * 8]);
      gload_lds16(gb, &Bs[(inst * 256 + wid * 64) * 8]);
    }
    __syncthreads();
    short8 af[4], bf[4];
#pragma unroll
    for (int mt = 0; mt < 4; ++mt) af[mt] = *(const short8*)&As[(wr * 64 + mt * 16 + r16) * 32 + kq * 8];
#pragma unroll
    for (int nt = 0; nt < 4; ++nt) bf[nt] = *(const short8*)&Bs[(wc * 64 + nt * 16 + r16) * 32 + kq * 8];
#pragma unroll
    for (int mt = 0; mt < 4; ++mt)
#pragma unroll
      for (int nt = 0; nt < 4; ++nt)
        acc[mt][nt] = __builtin_amdgcn_mfma_f32_16x16x32_bf16(af[mt], bf[nt], acc[mt][nt], 0, 0, 0);
  }
  float* Cp = C + (long)blockIdx.z * M * N;
#pragma unroll
  for (int nt = 0; nt < 4; ++nt) {
    int col = n0 + wc * 64 + nt * 16 + r16;
    float sc = scale ? scale[col] : 1.f;
    float sh = shift ? shift[col] : 0.f;
#pragma unroll
    for (int mt = 0; mt < 4; ++mt)
#pragma unroll
      for (int q = 0; q < 4; ++q) {
        int row = m0 + wr * 64 + mt * 16 + kq * 4 + q;
        float v = acc[mt][nt][q] * sc + sh;
        if (C16) C16[(long)row * N + col] = f2bf(v);
        else     Cp[(long)row * N + col] = v;
      }
  }
}

// ---------------- GRU recurrence (R2 protocol, proven; R7 fused epilogue) ----------------
// R9: (a) grid 256 blocks — blocks 128-255 are CONVERTER blocks that run the
// fcw/wc/vo/mo conversions (no dependency before the conv/FC stage) on the
// otherwise-idle half of the chip under gru's latency shadow, then exit.
// No sync interaction with the recurrence blocks.
// (b) flags compacted 64B -> 4B stride: the poller wave's 32 flag loads now
// hit 2 cache lines (2 coalesced L3 txns/poll instead of 32) — publishes are
// still distinct dwords, protocol unchanged.
__global__ __launch_bounds__(512) void gru_rec(
    const float* __restrict__ xg,     // [8192][3072]
    const u16* __restrict__ whhb,     // [2][1536][512] bf16
    const float* __restrict__ bhh_f, const float* __restrict__ bhh_b,
    u16* __restrict__ hbuf,           // [2 parity][2 dir][128][512] bf16 (zeroed each launch)
    u16* __restrict__ maskb,          // [8192][1024] bf16 masked output
    u16* __restrict__ feat,           // [128][5632] bf16 (gru mean + vo/mo sections)
    const int* __restrict__ lengths,  // [128]
    int* __restrict__ flg,            // 512 flags x 4B (compact), zeroed each launch
    const float* __restrict__ fc_w, const float* __restrict__ w2,
    const float* __restrict__ w3, const float* __restrict__ w4,
    const float* __restrict__ vo, const float* __restrict__ mo,
    u16* __restrict__ fcw, u16* __restrict__ wc)
{
  __shared__ float part[2][4][3][256];
  __shared__ u16 hstage[8192];        // 16KB: h[16 batches][512 i] bf16, XOR-swizzled
  int tid = threadIdx.x, lane = tid & 63, wid = tid >> 6;
  int bid = blockIdx.x;

  if (bid >= 128) {
    // -------- converter blocks: fcw, wc remap, vo/mo feat sections --------
    int cid = bid - 128;
    const int C1 = 2883584;           // fcw quads
    const int C2 = C1 + 1179648;      // wc quads
    const int C3 = C2 + 65536;        // vo
    const int NQ = C3 + 32768;        // mo
    for (int q = cid * 512 + tid; q < NQ; q += 128 * 512) {
      if (q < C1) {
        float4 v = ((const float4*)fc_w)[q];
        ((u64*)fcw)[q] = pack4(v.x, v.y, v.z, v.w);
      } else if (q < C2) {
        int r = q - C1;
        int e = r << 2;
        int row = e >> 10, col = e & 1023;
        const float* src;
        if (row < 1024)      { int j = row >> 9, k = row & 511;                 src = w2 + (k * 2 + j) * 1024; }
        else if (row < 2560) { int m = row - 1024; int j = m >> 9, k = m & 511; src = w3 + (k * 3 + j) * 1024; }
        else                 { int m = row - 2560; int j = m >> 9, k = m & 511; src = w4 + (k * 4 + j) * 1024; }
        float4 v = *(const float4*)(src + col);
        ((u64*)wc)[r] = pack4(v.x, v.y, v.z, v.w);
      } else if (q < C3) {
        int r = q - C2; int b = r >> 9, c = (r & 511) * 4;
        float4 v = *(const float4*)&vo[(long)b * 2048 + c];
        *(u64*)&feat[(long)b * 5632 + 2560 + c] = pack4(v.x, v.y, v.z, v.w);
      } else {
        int r = q - C3; int b = r >> 8, c = (r & 255) * 4;
        float4 v = *(const float4*)&mo[(long)b * 1024 + c];
        *(u64*)&feat[(long)b * 5632 + 4608 + c] = pack4(v.x, v.y, v.z, v.w);
      }
    }
    return;
  }

  // -------- recurrence blocks (R2 protocol, byte-identical except flag stride) --------
  int dir = bid >> 6, rem = bid & 63, bt = rem >> 3, is = rem & 7;
  int ih = wid & 3, ks = wid >> 2;
  int gbase = (dir * 8 + bt) * 32;
  int r16 = lane & 15, kq = lane >> 4;
  int iglob = is * 64 + ih * 16 + r16;
  int i0 = is * 64 + ih * 16 + kq * 4;
  int batch = bt * 16 + r16;
  int pollidx = gbase + (lane & 31);
  int pubidx = gbase + is * 4 + ih;
  const float* bhh = dir ? bhh_b : bhh_f;
  const floatx4 z4 = {0.f, 0.f, 0.f, 0.f};
  int len = lengths[batch];

  short8 wfrag[3][8];
#pragma unroll
  for (int g = 0; g < 3; ++g) {
    const u16* wrow = whhb + (long)(dir * 1536 + g * 512 + iglob) * 512;
#pragma unroll
    for (int kk = 0; kk < 8; ++kk)
      wfrag[g][kk] = *(const short8*)&wrow[(ks * 8 + kk) * 32 + kq * 8];
  }
  float4 bh4[3];
#pragma unroll
  for (int g = 0; g < 3; ++g) bh4[g] = *(const float4*)&bhh[g * 512 + i0];
  float4 hprev = {0.f, 0.f, 0.f, 0.f};
  float4 msum = {0.f, 0.f, 0.f, 0.f};

  float4 px[3];
  if (ks == 0) {
    int ts0 = dir ? 63 : 0;
    long xb = (long)(batch * 64 + ts0) * 3072 + dir * 1536 + i0;
#pragma unroll
    for (int g = 0; g < 3; ++g) px[g] = *(const float4*)&xg[xb + g * 512];
  }

  int so0 = wid * 2048 + lane * 16;
  int so1 = so0 + 1024;
  char* sl0 = (char*)hstage + (so0 ^ (((so0 >> 10) & 7) << 4));
  char* sl1 = (char*)hstage + (so1 ^ (((so1 >> 10) & 7) << 4));
  int rb = r16 * 1024 + ks * 512 + kq * 16;
  int rsw = (r16 & 7) << 4;

  for (int t = 0; t < 64; ++t) {
    if (t > 0) {
      if (wid == 0) {
        while (true) {
          int v;
          asm volatile("global_load_dword %0, %1, off sc0 sc1\n\ts_waitcnt vmcnt(0)"
                       : "=v"(v) : "v"(&flg[pollidx]) : "memory");
          if (__all(v >= t)) break;
          __builtin_amdgcn_s_sleep(1);
        }
      }
      asm volatile("s_barrier" ::: "memory");
    }
    int par = t & 1;
    const char* hsrc = (const char*)(hbuf + (long)((par * 2 + dir) * 128 + bt * 16) * 512);
    u32x4 qa, qb;
    asm volatile(
      "global_load_dwordx4 %0, %2, off sc0 sc1\n\t"
      "global_load_dwordx4 %1, %3, off sc0 sc1"
      : "=&v"(qa), "=&v"(qb)
      : "v"(hsrc + so0), "v"(hsrc + so1)
      : "memory");
    asm volatile("s_waitcnt vmcnt(0)" ::: "memory");
    *(u32x4*)sl0 = qa;
    *(u32x4*)sl1 = qb;
    float4 pxn[3];
    if (ks == 0 && t < 63) {
      int ts1 = dir ? (62 - t) : (t + 1);
      long xb = (long)(batch * 64 + ts1) * 3072 + dir * 1536 + i0;
#pragma unroll
      for (int g = 0; g < 3; ++g) pxn[g] = *(const float4*)&xg[xb + g * 512];
    }
    asm volatile("s_waitcnt lgkmcnt(0)\n\ts_barrier" ::: "memory");
    floatx4 acc[3];
#pragma unroll
    for (int g = 0; g < 3; ++g) acc[g] = z4;
#pragma unroll
    for (int kk = 0; kk < 8; ++kk) {
      short8 hv = *(const short8*)((const char*)hstage + ((rb + kk * 64) ^ rsw));
#pragma unroll
      for (int g = 0; g < 3; ++g)
        acc[g] = __builtin_amdgcn_mfma_f32_16x16x32_bf16(wfrag[g][kk], hv, acc[g], 0, 0, 0);
    }
    if (ks == 1) {
#pragma unroll
      for (int g = 0; g < 3; ++g) *(floatx4*)&part[par][ih][g][lane * 4] = acc[g];
    }
    asm volatile("s_waitcnt lgkmcnt(0)\n\ts_barrier" ::: "memory");
    if (ks == 0) {
      int tsrc = dir ? (63 - t) : t;
#pragma unroll
      for (int g = 0; g < 3; ++g) acc[g] += *(const floatx4*)&part[par][ih][g][lane * 4];
      float4 hn4;
#pragma unroll
      for (int q = 0; q < 4; ++q) {
        float rr = acc[0][q] + ((const float*)&bh4[0])[q] + ((const float*)&px[0])[q];
        float zz = acc[1][q] + ((const float*)&bh4[1])[q] + ((const float*)&px[1])[q];
        float r = 1.f / (1.f + __expf(-rr));
        float z = 1.f / (1.f + __expf(-zz));
        float n = tanhf(((const float*)&px[2])[q] + r * (acc[2][q] + ((const float*)&bh4[2])[q]));
        ((float*)&hn4)[q] = (1.f - z) * n + z * ((const float*)&hprev)[q];
      }
      hprev = hn4;
      u16* hdst = hbuf + (long)(((par ^ 1) * 2 + dir) * 128 + bt * 16) * 512;
      u64 hval = pack4(hn4.x, hn4.y, hn4.z, hn4.w);
      asm volatile("global_store_dwordx2 %0, %1, off sc0 sc1"
                   :: "v"((u64*)&hdst[r16 * 512 + i0]), "v"(hval) : "memory");
      if (t < 63) {
        asm volatile("s_waitcnt vmcnt(0)" ::: "memory");
        if (lane == 0) {
          int tv = t + 1;
          asm volatile("global_store_dword %0, %1, off sc0 sc1"
                       :: "v"(&flg[pubidx]), "v"(tv) : "memory");
        }
      }
      bool mv = tsrc < len;
      *(u64*)&maskb[(long)(batch * 64 + tsrc) * 1024 + dir * 512 + i0] = mv ? hval : 0ull;
      if (mv) {
        msum.x += hn4.x; msum.y += hn4.y; msum.z += hn4.z; msum.w += hn4.w;
      }
      px[0] = pxn[0]; px[1] = pxn[1]; px[2] = pxn[2];
    }
  }
  if (ks == 0) {
    float inv = 1.0f / (float)len;
    *(u64*)&feat[(long)batch * 5632 + dir * 512 + i0] =
        pack4(msum.x * inv, msum.y * inv, msum.z * inv, msum.w * inv);
  }
}

// ---------------- conv shift-add + relu + max over positions (z is bf16) ----------------
__global__ __launch_bounds__(256) void k_conv_finish(
    const u16* __restrict__ z, const float* __restrict__ cb2,
    const float* __restrict__ cb3, const float* __restrict__ cb4,
    u16* __restrict__ feat)
{
  int b = blockIdx.x, wsi = blockIdx.y, k2 = threadIdx.x * 2;
  int ws = wsi + 2;
  int base = (wsi == 0) ? 0 : (wsi == 1 ? 1024 : 2560);
  const float* cb = (wsi == 0) ? cb2 : (wsi == 1 ? cb3 : cb4);
  float bias0 = cb[k2], bias1 = cb[k2 + 1];
  float m0 = 0.f, m1 = 0.f;
  for (int p = 0; p < 64 + ws - 1; ++p) {
    float a0 = bias0, a1 = bias1;
    for (int j = 0; j < ws; ++j) {
      int t = p - (ws - 1) + j;
      if (t >= 0 && t < 64) {
        u32 v = *(const u32*)&z[(long)(b * 64 + t) * 4608 + base + j * 512 + k2];
        a0 += bf2f((u16)v);
        a1 += bf2f((u16)(v >> 16));
      }
    }
    m0 = fmaxf(m0, a0);
    m1 = fmaxf(m1, a1);
  }
  *(u32*)&feat[(long)b * 5632 + 1024 + wsi * 512 + k2] = (u32)f2bf(m0) | ((u32)f2bf(m1) << 16);
}

// ---------------- split-K reduce + BN + row L2 normalize (8 partials) ----------------
__global__ __launch_bounds__(256) void k_l2norm(const float* __restrict__ p,
    const float* __restrict__ bns, const float* __restrict__ bnt, float* __restrict__ out)
{
  __shared__ float red[4];
  int b = blockIdx.x, tid = threadIdx.x;
  float v[8]; float s = 0.f;
#pragma unroll
  for (int j = 0; j < 8; ++j) {
    int i = j * 256 + tid;
    long o = (long)b * 2048 + i;
    float a = 0.f;
#pragma unroll
    for (int zz = 0; zz < 8; ++zz) a += p[o + (long)zz * 262144];
    a = a * bns[i] + bnt[i];
    v[j] = a; s += a * a;
  }
#pragma unroll
  for (int o = 32; o > 0; o >>= 1) s += __shfl_down(s, o);
  if ((tid & 63) == 0) red[tid >> 6] = s;
  __syncthreads();
  float rn = rsqrtf(red[0] + red[1] + red[2] + red[3]);
#pragma unroll
  for (int j = 0; j < 8; ++j)
    out[(long)b * 2048 + j * 256 + tid] = v[j] * rn;
}

// ---------------- launch ----------------
extern "C" void kernel_launch(void* const* d_in, const int* in_sizes, int n_in,
                              void* d_out, int out_size, void* d_ws, size_t ws_size,
                              hipStream_t stream)
{
  (void)in_sizes; (void)n_in; (void)out_size; (void)ws_size;
  const float* videos       = (const float*)d_in[0];
  const float* motions      = (const float*)d_in[1];
  const float* videos_origin= (const float*)d_in[2];
  const int*   lengths      = (const int*)d_in[3];
  const float* Wih_f = (const float*)d_in[4];
  const float* Whh_f = (const float*)d_in[5];
  const float* bih_f = (const float*)d_in[6];
  const float* bhh_f = (const float*)d_in[7];
  const float* Wih_b = (const float*)d_in[8];
  const float* Whh_b = (const float*)d_in[9];
  const float* bih_b = (const float*)d_in[10];
  const float* bhh_b = (const float*)d_in[11];
  const float* fc_w  = (const float*)d_in[12];
  const float* fc_b  = (const float*)d_in[13];
  const float* bn_gamma = (const float*)d_in[14];
  const float* bn_beta  = (const float*)d_in[15];
  const float* bn_mean  = (const float*)d_in[16];
  const float* bn_var   = (const float*)d_in[17];
  const float* conv_w2 = (const float*)d_in[18];
  const float* conv_b2 = (const float*)d_in[19];
  const float* conv_w3 = (const float*)d_in[20];
  const float* conv_b3 = (const float*)d_in[21];
  const float* conv_w4 = (const float*)d_in[22];
  const float* conv_b4 = (const float*)d_in[23];
  float* out = (float*)d_out;
  char* w = (char*)d_ws;

  const size_t XG    = 0;              // 8192x3072 f32 = 100,663,296
  const size_t VID   = 134217728;      // 8192x2048 bf16 = 33,554,432
  const size_t MASKB = 167772160;      // 8192x1024 bf16 = 16,777,216 (FC partials 8MB overlay)
  const size_t WIH   = 184549376;      // 3072x2048 bf16 = 12,582,912
  const size_t WHH   = 197132288;      // 2x1536x512 bf16 = 3,145,728
  const size_t WC    = 200278016;      // 4608x1024 bf16 = 9,437,184
  const size_t FCW   = 209715200;      // 2048x5632 bf16 = 23,068,672
  const size_t FEAT  = 232783872;      // 128x5632 bf16 = 1,441,792
  const size_t BIH   = 235274240;      // 3072 f32
  const size_t BNS   = 235286528;      // 2048 f32
  const size_t BNT   = 235294720;      // 2048 f32
  const size_t HB    = 235302912;      // 2x2x128x512 bf16 = 524,288
  const size_t FLG   = HB + 524288;    // 512 flags x 4B = 2,048

  float* xg   = (float*)(w + XG);
  u16*   zb16 = (u16*)(w + XG);        // overlay
  u16* vid    = (u16*)(w + VID);
  u16* maskb  = (u16*)(w + MASKB);
  float* fcp  = (float*)(w + MASKB);   // FC split-K partials overlay (after conv GEMM)
  u16* wih    = (u16*)(w + WIH);
  u16* whh    = (u16*)(w + WHH);
  u16* wc_    = (u16*)(w + WC);
  u16* fcw    = (u16*)(w + FCW);
  u16* feat   = (u16*)(w + FEAT);
  float* bih  = (float*)(w + BIH);
  float* bns  = (float*)(w + BNS);
  float* bnt  = (float*)(w + BNT);
  u16* hb     = (u16*)(w + HB);
  int* flg    = (int*)(w + FLG);

  // zero h double-buffer (parity0 read at t=0) + compact flags, every launch
  hipMemsetAsync(w + HB, 0, 524288 + 2048, stream);

  k_pre_cvt<<<4096, 256, 0, stream>>>(
      videos, Wih_f, Wih_b, Whh_f, Whh_b, bih_f, bih_b,
      fc_b, bn_gamma, bn_beta, bn_mean, bn_var,
      vid, wih, whh, bih, bns, bnt);

  // xg = videos @ [Wih_f;Wih_b]^T + bih  (f32 out), 256^2 8-phase
  gemm256<<<dim3(12, 32), 512, 0, stream>>>(vid, wih, xg, nullptr, 8192, 3072, 2048, 32, bih);

  {
    const float* xg_c = xg; const u16* whh_c = whh;
    u16* hb_c = hb; u16* mb_c = maskb; u16* ft_c = feat;
    const int* len_c = lengths; int* flg_c = flg;
    const float* bf_c = bhh_f; const float* bb_c = bhh_b;
    const float* fw_c = fc_w; const float* w2_c = conv_w2;
    const float* w3_c = conv_w3; const float* w4_c = conv_w4;
    const float* vo_c = videos_origin; const float* mo_c = motions;
    u16* fcw_c = fcw; u16* wc_c = wc_;
    void* args[] = { (void*)&xg_c, (void*)&whh_c, (void*)&bf_c, (void*)&bb_c,
                     (void*)&hb_c, (void*)&mb_c, (void*)&ft_c, (void*)&len_c, (void*)&flg_c,
                     (void*)&fw_c, (void*)&w2_c, (void*)&w3_c, (void*)&w4_c,
                     (void*)&vo_c, (void*)&mo_c, (void*)&fcw_c, (void*)&wc_c };
    hipLaunchCooperativeKernel(reinterpret_cast<void*>(gru_rec), dim3(256), dim3(512), args, 0, stream);
  }

  // z = masked @ Wc^T (bf16 out), 256^2 8-phase
  gemm256<<<dim3(18, 32), 512, 0, stream>>>(maskb, wc_, nullptr, zb16, 8192, 4608, 1024, 16, nullptr);
  k_conv_finish<<<dim3(128, 3), 256, 0, stream>>>(zb16, conv_b2, conv_b3, conv_b4, feat);
  // FC split-K x8 (raw partials; BN folded into l2norm)
  gemm_bt<<<dim3(16, 1, 8), 256, 0, stream>>>(feat, fcw, fcp, nullptr, 128, 2048, 5632, 22, nullptr, nullptr);
  k_l2norm<<<128, 256, 0, stream>>>(fcp, bns, bnt, out);
}

// Round 11
// 592.705 us; speedup vs baseline: 1.3950x; 1.0021x over previous
//
#include <hip/hip_runtime.h>
#include <hip/hip_bf16.h>
#include <stdint.h>

typedef __attribute__((ext_vector_type(8))) short short8;
typedef __attribute__((ext_vector_type(4))) float floatx4;
typedef __attribute__((ext_vector_type(4))) unsigned int u32x4;
typedef unsigned short u16;
typedef unsigned int u32;
typedef unsigned long long u64;

static __device__ __forceinline__ u16 f2bf(float f) {
  union { float f; u32 u; } v; v.f = f;
  return (u16)((v.u + 0x7fffu + ((v.u >> 16) & 1u)) >> 16);
}
static __device__ __forceinline__ float bf2f(u16 h) {
  union { u32 u; float f; } v; v.u = ((u32)h) << 16; return v.f;
}
static __device__ __forceinline__ u64 pack4(float a, float b, float c, float d) {
  return (u64)f2bf(a) | ((u64)f2bf(b) << 16) | ((u64)f2bf(c) << 32) | ((u64)f2bf(d) << 48);
}

// ---------------- pre-GEMM conversions (vid/wih/whh/bias only; rest co-runs with gru) ----------------
__global__ __launch_bounds__(256) void k_pre_cvt(
    const float* __restrict__ videos, const float* __restrict__ Wih_f,
    const float* __restrict__ Wih_b, const float* __restrict__ Whh_f,
    const float* __restrict__ Whh_b, const float* __restrict__ bih_f,
    const float* __restrict__ bih_b, const float* __restrict__ fcb,
    const float* __restrict__ gam, const float* __restrict__ bet,
    const float* __restrict__ mu, const float* __restrict__ var,
    u16* __restrict__ vid, u16* __restrict__ wih, u16* __restrict__ whh,
    float* __restrict__ bihcat, float* __restrict__ bns, float* __restrict__ bnt)
{
  const int O1 = 4194304;            // vid quads
  const int O2 = O1 + 786432;        // wih_f
  const int O3 = O2 + 786432;        // wih_b
  const int O4 = O3 + 196608;        // whh_f
  const int O5 = O4 + 196608;        // whh_b
  const int NQ = O5 + 1280;          // 768 bihcat quads + 512 bn quads
  for (int q = blockIdx.x * 256 + threadIdx.x; q < NQ; q += gridDim.x * 256) {
    if (q < O1) {
      float4 v = ((const float4*)videos)[q];
      ((u64*)vid)[q] = pack4(v.x, v.y, v.z, v.w);
    } else if (q < O2) {
      int r = q - O1; float4 v = ((const float4*)Wih_f)[r];
      ((u64*)wih)[r] = pack4(v.x, v.y, v.z, v.w);
    } else if (q < O3) {
      int r = q - O2; float4 v = ((const float4*)Wih_b)[r];
      ((u64*)wih)[r + 786432] = pack4(v.x, v.y, v.z, v.w);
    } else if (q < O4) {
      int r = q - O3; float4 v = ((const float4*)Whh_f)[r];
      ((u64*)whh)[r] = pack4(v.x, v.y, v.z, v.w);
    } else if (q < O5) {
      int r = q - O4; float4 v = ((const float4*)Whh_b)[r];
      ((u64*)whh)[r + 196608] = pack4(v.x, v.y, v.z, v.w);
    } else {
      int r = q - O5;
      if (r < 768) {
        int i = r * 4;  // 1536 % 4 == 0: quad never straddles f/b boundary
        const float* s = (i < 1536) ? (bih_f + i) : (bih_b + (i - 1536));
        *(float4*)&bihcat[i] = *(const float4*)s;
      } else {
        int i = (r - 768) * 4;
#pragma unroll
        for (int j = 0; j < 4; ++j) {
          int idx = i + j;
          float sc = gam[idx] * rsqrtf(var[idx] + 1e-5f);
          bns[idx] = sc;
          bnt[idx] = sc * (fcb[idx] - mu[idx]) + bet[idx];
        }
      }
    }
  }
}

static __device__ __forceinline__ void gload_lds16(const u16* g, u16* l) {
  __builtin_amdgcn_global_load_lds((const __attribute__((address_space(1))) u32*)(const void*)g,
                                   (__attribute__((address_space(3))) u32*)(void*)l, 16, 0, 0);
}

// ---------------- 256x256 8-phase bf16 GEMM (R8, proven) ----------------
static __device__ __forceinline__ void stage_half_256(
    const u16* __restrict__ Mat, long K, int rowbase, int ktile, u16* lregion,
    int tid, int wid)
{
  int srow = tid >> 3;
  int sce = (((tid >> 3) ^ tid) & 7) * 8;   // pre-swizzled source col (elems)
  const u16* g0 = Mat + (long)(rowbase + srow) * K + ktile * 64 + sce;
  const u16* g1 = Mat + (long)(rowbase + 64 + srow) * K + ktile * 64 + sce;
  gload_lds16(g0, lregion + wid * 512);
  gload_lds16(g1, lregion + 4096 + wid * 512);
}

__global__ __launch_bounds__(512) void gemm256(
    const u16* __restrict__ A, const u16* __restrict__ Bm,
    float* __restrict__ C, u16* __restrict__ C16, int M, int N, int K, int NT,
    const float* __restrict__ shift)
{
  __shared__ u16 lds[65536];   // 128 KB
  int tid = threadIdx.x, lane = tid & 63, wid = tid >> 6;
  int r16 = lane & 15, kq = lane >> 4;
  int wr = wid >> 2, wc = wid & 3;
  int nwg = gridDim.x * gridDim.y;
  int lin = blockIdx.y * gridDim.x + blockIdx.x;
  int q8 = nwg >> 3;
  int swz = (lin & 7) * q8 + (lin >> 3);
  int m0 = (swz / gridDim.x) * 256, n0 = (swz % gridDim.x) * 256;

  int fxor = (r16 & 7) << 4;
  int c0 = (kq * 16) ^ fxor;
  int c1 = c0 ^ 64;
  int brow0 = (wc & 1) * 64;
  const char* ldsc = (const char*)lds;

  const floatx4 z4 = {0.f, 0.f, 0.f, 0.f};
  floatx4 acc[8][4];
#pragma unroll
  for (int i = 0; i < 8; ++i)
#pragma unroll
    for (int j = 0; j < 4; ++j) acc[i][j] = z4;

  stage_half_256(Bm, K, n0,       0, lds,                 tid, wid);
  stage_half_256(Bm, K, n0 + 128, 0, lds + 8192,          tid, wid);
  stage_half_256(A,  K, m0,       0, lds + 16384,         tid, wid);
  stage_half_256(A,  K, m0 + 128, 0, lds + 24576,         tid, wid);
  stage_half_256(Bm, K, n0,       1, lds + 32768,         tid, wid);
  stage_half_256(Bm, K, n0 + 128, 1, lds + 32768 + 8192,  tid, wid);
  stage_half_256(A,  K, m0,       1, lds + 32768 + 16384, tid, wid);
  stage_half_256(A,  K, m0 + 128, 1, lds + 32768 + 24576, tid, wid);
  asm volatile("s_waitcnt vmcnt(8)" ::: "memory");
  asm volatile("s_barrier" ::: "memory");

#define MFMA_CLUSTER(q)                                                        \
  asm volatile("s_waitcnt lgkmcnt(0)" ::: "memory");                           \
  __builtin_amdgcn_sched_barrier(0);                                           \
  __builtin_amdgcn_s_setprio(1);                                               \
  _Pragma("unroll")                                                            \
  for (int s = 0; s < 2; ++s)                                                  \
    _Pragma("unroll")                                                          \
    for (int e = 0; e < 2; ++e)                                                \
      _Pragma("unroll")                                                        \
      for (int j = 0; j < 4; ++j)                                              \
        acc[(q)*2 + e][j] = __builtin_amdgcn_mfma_f32_16x16x32_bf16(           \
            af[e][s], bf[j][s], acc[(q)*2 + e][j], 0, 0, 0);                   \
  __builtin_amdgcn_s_setprio(0);

  for (int T = 0; T < NT; ++T) {
    int P = T & 1;
    int Tn1 = (T + 1 < NT) ? T + 1 : 0;
    int Tn2 = (T + 2 < NT) ? T + 2 : T + 2 - NT;
    const char* bbase = ldsc + P * 65536 + (wc >> 1) * 16384;
    const char* abase = ldsc + P * 65536 + 32768 + wr * 16384;
    short8 bf[4][2];
    {
#pragma unroll
      for (int j = 0; j < 4; ++j) {
        bf[j][0] = *(const short8*)(bbase + (brow0 + j * 16 + r16) * 128 + c0);
        bf[j][1] = *(const short8*)(bbase + (brow0 + j * 16 + r16) * 128 + c1);
      }
      short8 af[2][2];
#pragma unroll
      for (int e = 0; e < 2; ++e) {
        af[e][0] = *(const short8*)(abase + (e * 16 + r16) * 128 + c0);
        af[e][1] = *(const short8*)(abase + (e * 16 + r16) * 128 + c1);
      }
      stage_half_256(A, K, m0, Tn1, lds + (Tn1 & 1) * 32768 + 16384, tid, wid);
      asm volatile("s_barrier" ::: "memory");
      MFMA_CLUSTER(0)
      asm volatile("s_barrier" ::: "memory");
    }
    {
      short8 af[2][2];
#pragma unroll
      for (int e = 0; e < 2; ++e) {
        af[e][0] = *(const short8*)(abase + ((2 + e) * 16 + r16) * 128 + c0);
        af[e][1] = *(const short8*)(abase + ((2 + e) * 16 + r16) * 128 + c1);
      }
      stage_half_256(A, K, m0 + 128, Tn1, lds + (Tn1 & 1) * 32768 + 24576, tid, wid);
      asm volatile("s_barrier" ::: "memory");
      MFMA_CLUSTER(1)
      asm volatile("s_barrier" ::: "memory");
    }
    {
      short8 af[2][2];
#pragma unroll
      for (int e = 0; e < 2; ++e) {
        af[e][0] = *(const short8*)(abase + ((4 + e) * 16 + r16) * 128 + c0);
        af[e][1] = *(const short8*)(abase + ((4 + e) * 16 + r16) * 128 + c1);
      }
      stage_half_256(Bm, K, n0, Tn2, lds + P * 32768, tid, wid);
      asm volatile("s_barrier" ::: "memory");
      MFMA_CLUSTER(2)
      asm volatile("s_barrier" ::: "memory");
    }
    {
      short8 af[2][2];
#pragma unroll
      for (int e = 0; e < 2; ++e) {
        af[e][0] = *(const short8*)(abase + ((6 + e) * 16 + r16) * 128 + c0);
        af[e][1] = *(const short8*)(abase + ((6 + e) * 16 + r16) * 128 + c1);
      }
      stage_half_256(Bm, K, n0 + 128, Tn2, lds + P * 32768 + 8192, tid, wid);
      asm volatile("s_barrier" ::: "memory");
      MFMA_CLUSTER(3)
      asm volatile("s_waitcnt vmcnt(4)" ::: "memory");
      asm volatile("s_barrier" ::: "memory");
    }
  }
#undef MFMA_CLUSTER

#pragma unroll
  for (int mf = 0; mf < 8; ++mf)
#pragma unroll
    for (int j = 0; j < 4; ++j) {
      int col = n0 + wc * 64 + j * 16 + r16;
      int row = m0 + wr * 128 + mf * 16 + kq * 4;
      if (C16) {
#pragma unroll
        for (int qq = 0; qq < 4; ++qq)
          C16[(long)(row + qq) * N + col] = f2bf(acc[mf][j][qq]);
      } else {
        float sh = shift ? shift[col] : 0.f;
#pragma unroll
        for (int qq = 0; qq < 4; ++qq)
          C[(long)(row + qq) * N + col] = acc[mf][j][qq] + sh;
      }
    }
}

// ---------------- 128x128 MFMA GEMM (kept for the small FC GEMM) ----------------
__global__ __launch_bounds__(256) void gemm_bt(
    const u16* __restrict__ A, const u16* __restrict__ Bm,
    float* __restrict__ C, u16* __restrict__ C16, int M, int N, int K, int kn,
    const float* __restrict__ scale, const float* __restrict__ shift)
{
  __shared__ u16 As[128 * 32];
  __shared__ u16 Bs[128 * 32];
  int tid = threadIdx.x, lane = tid & 63, wid = tid >> 6;
  int nwg = gridDim.x * gridDim.y;
  int lin = blockIdx.y * gridDim.x + blockIdx.x;
  int q8 = nwg >> 3;
  int swz = (lin & 7) * q8 + (lin >> 3);
  int m0 = (swz / gridDim.x) * 128, n0 = (swz % gridDim.x) * 128;
  int kt0 = blockIdx.z * kn;
  int wr = wid >> 1, wc = wid & 1;
  int r16 = lane & 15, kq = lane >> 4;
  const floatx4 z4 = {0.f, 0.f, 0.f, 0.f};
  floatx4 acc[4][4];
#pragma unroll
  for (int i = 0; i < 4; ++i)
#pragma unroll
    for (int j = 0; j < 4; ++j) acc[i][j] = z4;
  for (int kt = kt0; kt < kt0 + kn; ++kt) {
    __syncthreads();
#pragma unroll
    for (int inst = 0; inst < 2; ++inst) {
      int g = inst * 256 + tid;
      int row = g >> 2, cb = g & 3;
      const u16* ga = A + (long)(m0 + row) * K + kt * 32 + cb * 8;
      const u16* gb = Bm + (long)(n0 + row) * K + kt * 32 + cb * 8;
      gload_lds16(ga, &As[(inst * 256 + wid * 64) * 8]);
      gload_lds16(gb, &Bs[(inst * 256 + wid * 64) * 8]);
    }
    __syncthreads();
    short8 af[4], bf[4];
#pragma unroll
    for (int mt = 0; mt < 4; ++mt) af[mt] = *(const short8*)&As[(wr * 64 + mt * 16 + r16) * 32 + kq * 8];
#pragma unroll
    for (int nt = 0; nt < 4; ++nt) bf[nt] = *(const short8*)&Bs[(wc * 64 + nt * 16 + r16) * 32 + kq * 8];
#pragma unroll
    for (int mt = 0; mt < 4; ++mt)
#pragma unroll
      for (int nt = 0; nt < 4; ++nt)
        acc[mt][nt] = __builtin_amdgcn_mfma_f32_16x16x32_bf16(af[mt], bf[nt], acc[mt][nt], 0, 0, 0);
  }
  float* Cp = C + (long)blockIdx.z * M * N;
#pragma unroll
  for (int nt = 0; nt < 4; ++nt) {
    int col = n0 + wc * 64 + nt * 16 + r16;
    float sc = scale ? scale[col] : 1.f;
    float sh = shift ? shift[col] : 0.f;
#pragma unroll
    for (int mt = 0; mt < 4; ++mt)
#pragma unroll
      for (int q = 0; q < 4; ++q) {
        int row = m0 + wr * 64 + mt * 16 + kq * 4 + q;
        float v = acc[mt][nt][q] * sc + sh;
        if (C16) C16[(long)row * N + col] = f2bf(v);
        else     Cp[(long)row * N + col] = v;
      }
  }
}

// ---------------- GRU recurrence (R2 protocol; R9 co-run; R10 atomic publish) ----------------
// R10: hbuf/flag publishes now use global_atomic_swap(_x2) sc1 instead of plain
// sc0sc1 stores. Evidence: WRITE_SIZE has included hbuf's full traffic every
// round -> plain sc0sc1 stores write THROUGH to HBM, so the vmcnt(0) ack and
// the consumer's poll/stage miss L3 and pay ~1000cy DRAM hops. Atomics execute
// at the LLC coherence point: the line stays in L3, every handshake hop drops
// to ~500cy. Swap-without-return is semantically a device-scope store; the
// proven ordering (h publish -> vmcnt(0) ack -> flag publish; poll; s_barrier)
// is unchanged.
__global__ __launch_bounds__(512) void gru_rec(
    const float* __restrict__ xg,     // [8192][3072]
    const u16* __restrict__ whhb,     // [2][1536][512] bf16
    const float* __restrict__ bhh_f, const float* __restrict__ bhh_b,
    u16* __restrict__ hbuf,           // [2 parity][2 dir][128][512] bf16 (zeroed each launch)
    u16* __restrict__ maskb,          // [8192][1024] bf16 masked output
    u16* __restrict__ feat,           // [128][5632] bf16 (gru mean + vo/mo sections)
    const int* __restrict__ lengths,  // [128]
    int* __restrict__ flg,            // 512 flags x 4B (compact), zeroed each launch
    const float* __restrict__ fc_w, const float* __restrict__ w2,
    const float* __restrict__ w3, const float* __restrict__ w4,
    const float* __restrict__ vo, const float* __restrict__ mo,
    u16* __restrict__ fcw, u16* __restrict__ wc)
{
  __shared__ float part[2][4][3][256];
  __shared__ u16 hstage[8192];        // 16KB: h[16 batches][512 i] bf16, XOR-swizzled
  int tid = threadIdx.x, lane = tid & 63, wid = tid >> 6;
  int bid = blockIdx.x;

  if (bid >= 128) {
    // -------- converter blocks: fcw, wc remap, vo/mo feat sections --------
    int cid = bid - 128;
    const int C1 = 2883584;           // fcw quads
    const int C2 = C1 + 1179648;      // wc quads
    const int C3 = C2 + 65536;        // vo
    const int NQ = C3 + 32768;        // mo
    for (int q = cid * 512 + tid; q < NQ; q += 128 * 512) {
      if (q < C1) {
        float4 v = ((const float4*)fc_w)[q];
        ((u64*)fcw)[q] = pack4(v.x, v.y, v.z, v.w);
      } else if (q < C2) {
        int r = q - C1;
        int e = r << 2;
        int row = e >> 10, col = e & 1023;
        const float* src;
        if (row < 1024)      { int j = row >> 9, k = row & 511;                 src = w2 + (k * 2 + j) * 1024; }
        else if (row < 2560) { int m = row - 1024; int j = m >> 9, k = m & 511; src = w3 + (k * 3 + j) * 1024; }
        else                 { int m = row - 2560; int j = m >> 9, k = m & 511; src = w4 + (k * 4 + j) * 1024; }
        float4 v = *(const float4*)(src + col);
        ((u64*)wc)[r] = pack4(v.x, v.y, v.z, v.w);
      } else if (q < C3) {
        int r = q - C2; int b = r >> 9, c = (r & 511) * 4;
        float4 v = *(const float4*)&vo[(long)b * 2048 + c];
        *(u64*)&feat[(long)b * 5632 + 2560 + c] = pack4(v.x, v.y, v.z, v.w);
      } else {
        int r = q - C3; int b = r >> 8, c = (r & 255) * 4;
        float4 v = *(const float4*)&mo[(long)b * 1024 + c];
        *(u64*)&feat[(long)b * 5632 + 4608 + c] = pack4(v.x, v.y, v.z, v.w);
      }
    }
    return;
  }

  // -------- recurrence blocks --------
  int dir = bid >> 6, rem = bid & 63, bt = rem >> 3, is = rem & 7;
  int ih = wid & 3, ks = wid >> 2;
  int gbase = (dir * 8 + bt) * 32;
  int r16 = lane & 15, kq = lane >> 4;
  int iglob = is * 64 + ih * 16 + r16;
  int i0 = is * 64 + ih * 16 + kq * 4;
  int batch = bt * 16 + r16;
  int pollidx = gbase + (lane & 31);
  int pubidx = gbase + is * 4 + ih;
  const float* bhh = dir ? bhh_b : bhh_f;
  const floatx4 z4 = {0.f, 0.f, 0.f, 0.f};
  int len = lengths[batch];

  short8 wfrag[3][8];
#pragma unroll
  for (int g = 0; g < 3; ++g) {
    const u16* wrow = whhb + (long)(dir * 1536 + g * 512 + iglob) * 512;
#pragma unroll
    for (int kk = 0; kk < 8; ++kk)
      wfrag[g][kk] = *(const short8*)&wrow[(ks * 8 + kk) * 32 + kq * 8];
  }
  float4 bh4[3];
#pragma unroll
  for (int g = 0; g < 3; ++g) bh4[g] = *(const float4*)&bhh[g * 512 + i0];
  float4 hprev = {0.f, 0.f, 0.f, 0.f};
  float4 msum = {0.f, 0.f, 0.f, 0.f};

  float4 px[3];
  if (ks == 0) {
    int ts0 = dir ? 63 : 0;
    long xb = (long)(batch * 64 + ts0) * 3072 + dir * 1536 + i0;
#pragma unroll
    for (int g = 0; g < 3; ++g) px[g] = *(const float4*)&xg[xb + g * 512];
  }

  int so0 = wid * 2048 + lane * 16;
  int so1 = so0 + 1024;
  char* sl0 = (char*)hstage + (so0 ^ (((so0 >> 10) & 7) << 4));
  char* sl1 = (char*)hstage + (so1 ^ (((so1 >> 10) & 7) << 4));
  int rb = r16 * 1024 + ks * 512 + kq * 16;
  int rsw = (r16 & 7) << 4;

  for (int t = 0; t < 64; ++t) {
    if (t > 0) {
      if (wid == 0) {
        while (true) {
          int v;
          asm volatile("global_load_dword %0, %1, off sc0 sc1\n\ts_waitcnt vmcnt(0)"
                       : "=v"(v) : "v"(&flg[pollidx]) : "memory");
          if (__all(v >= t)) break;
          __builtin_amdgcn_s_sleep(1);
        }
      }
      asm volatile("s_barrier" ::: "memory");
    }
    int par = t & 1;
    const char* hsrc = (const char*)(hbuf + (long)((par * 2 + dir) * 128 + bt * 16) * 512);
    u32x4 qa, qb;
    asm volatile(
      "global_load_dwordx4 %0, %2, off sc0 sc1\n\t"
      "global_load_dwordx4 %1, %3, off sc0 sc1"
      : "=&v"(qa), "=&v"(qb)
      : "v"(hsrc + so0), "v"(hsrc + so1)
      : "memory");
    asm volatile("s_waitcnt vmcnt(0)" ::: "memory");
    *(u32x4*)sl0 = qa;
    *(u32x4*)sl1 = qb;
    float4 pxn[3];
    if (ks == 0 && t < 63) {
      int ts1 = dir ? (62 - t) : (t + 1);
      long xb = (long)(batch * 64 + ts1) * 3072 + dir * 1536 + i0;
#pragma unroll
      for (int g = 0; g < 3; ++g) pxn[g] = *(const float4*)&xg[xb + g * 512];
    }
    asm volatile("s_waitcnt lgkmcnt(0)\n\ts_barrier" ::: "memory");
    floatx4 acc[3];
#pragma unroll
    for (int g = 0; g < 3; ++g) acc[g] = z4;
#pragma unroll
    for (int kk = 0; kk < 8; ++kk) {
      short8 hv = *(const short8*)((const char*)hstage + ((rb + kk * 64) ^ rsw));
#pragma unroll
      for (int g = 0; g < 3; ++g)
        acc[g] = __builtin_amdgcn_mfma_f32_16x16x32_bf16(wfrag[g][kk], hv, acc[g], 0, 0, 0);
    }
    if (ks == 1) {
#pragma unroll
      for (int g = 0; g < 3; ++g) *(floatx4*)&part[par][ih][g][lane * 4] = acc[g];
    }
    asm volatile("s_waitcnt lgkmcnt(0)\n\ts_barrier" ::: "memory");
    if (ks == 0) {
      int tsrc = dir ? (63 - t) : t;
#pragma unroll
      for (int g = 0; g < 3; ++g) acc[g] += *(const floatx4*)&part[par][ih][g][lane * 4];
      float4 hn4;
#pragma unroll
      for (int q = 0; q < 4; ++q) {
        float rr = acc[0][q] + ((const float*)&bh4[0])[q] + ((const float*)&px[0])[q];
        float zz = acc[1][q] + ((const float*)&bh4[1])[q] + ((const float*)&px[1])[q];
        float r = 1.f / (1.f + __expf(-rr));
        float z = 1.f / (1.f + __expf(-zz));
        float n = tanhf(((const float*)&px[2])[q] + r * (acc[2][q] + ((const float*)&bh4[2])[q]));
        ((float*)&hn4)[q] = (1.f - z) * n + z * ((const float*)&hprev)[q];
      }
      hprev = hn4;
      u16* hdst = hbuf + (long)(((par ^ 1) * 2 + dir) * 128 + bt * 16) * 512;
      u64 hval = pack4(hn4.x, hn4.y, hn4.z, hn4.w);
      // R10: publish h via atomic swap (executes at LLC; line stays in L3)
      asm volatile("global_atomic_swap_x2 %0, %1, off sc1"
                   :: "v"((u64*)&hdst[r16 * 512 + i0]), "v"(hval) : "memory");
      if (t < 63) {
        asm volatile("s_waitcnt vmcnt(0)" ::: "memory");
        if (lane == 0) {
          int tv = t + 1;
          asm volatile("global_atomic_swap %0, %1, off sc1"
                       :: "v"(&flg[pubidx]), "v"(tv) : "memory");
        }
      }
      bool mv = tsrc < len;
      *(u64*)&maskb[(long)(batch * 64 + tsrc) * 1024 + dir * 512 + i0] = mv ? hval : 0ull;
      if (mv) {
        msum.x += hn4.x; msum.y += hn4.y; msum.z += hn4.z; msum.w += hn4.w;
      }
      px[0] = pxn[0]; px[1] = pxn[1]; px[2] = pxn[2];
    }
  }
  if (ks == 0) {
    float inv = 1.0f / (float)len;
    *(u64*)&feat[(long)batch * 5632 + dir * 512 + i0] =
        pack4(msum.x * inv, msum.y * inv, msum.z * inv, msum.w * inv);
  }
}

// ---------------- conv shift-add + relu + max over positions (z is bf16) ----------------
__global__ __launch_bounds__(256) void k_conv_finish(
    const u16* __restrict__ z, const float* __restrict__ cb2,
    const float* __restrict__ cb3, const float* __restrict__ cb4,
    u16* __restrict__ feat)
{
  int b = blockIdx.x, wsi = blockIdx.y, k2 = threadIdx.x * 2;
  int ws = wsi + 2;
  int base = (wsi == 0) ? 0 : (wsi == 1 ? 1024 : 2560);
  const float* cb = (wsi == 0) ? cb2 : (wsi == 1 ? cb3 : cb4);
  float bias0 = cb[k2], bias1 = cb[k2 + 1];
  float m0 = 0.f, m1 = 0.f;
  for (int p = 0; p < 64 + ws - 1; ++p) {
    float a0 = bias0, a1 = bias1;
    for (int j = 0; j < ws; ++j) {
      int t = p - (ws - 1) + j;
      if (t >= 0 && t < 64) {
        u32 v = *(const u32*)&z[(long)(b * 64 + t) * 4608 + base + j * 512 + k2];
        a0 += bf2f((u16)v);
        a1 += bf2f((u16)(v >> 16));
      }
    }
    m0 = fmaxf(m0, a0);
    m1 = fmaxf(m1, a1);
  }
  *(u32*)&feat[(long)b * 5632 + 1024 + wsi * 512 + k2] = (u32)f2bf(m0) | ((u32)f2bf(m1) << 16);
}

// ---------------- split-K reduce + BN + row L2 normalize (8 partials) ----------------
__global__ __launch_bounds__(256) void k_l2norm(const float* __restrict__ p,
    const float* __restrict__ bns, const float* __restrict__ bnt, float* __restrict__ out)
{
  __shared__ float red[4];
  int b = blockIdx.x, tid = threadIdx.x;
  float v[8]; float s = 0.f;
#pragma unroll
  for (int j = 0; j < 8; ++j) {
    int i = j * 256 + tid;
    long o = (long)b * 2048 + i;
    float a = 0.f;
#pragma unroll
    for (int zz = 0; zz < 8; ++zz) a += p[o + (long)zz * 262144];
    a = a * bns[i] + bnt[i];
    v[j] = a; s += a * a;
  }
#pragma unroll
  for (int o = 32; o > 0; o >>= 1) s += __shfl_down(s, o);
  if ((tid & 63) == 0) red[tid >> 6] = s;
  __syncthreads();
  float rn = rsqrtf(red[0] + red[1] + red[2] + red[3]);
#pragma unroll
  for (int j = 0; j < 8; ++j)
    out[(long)b * 2048 + j * 256 + tid] = v[j] * rn;
}

// ---------------- launch ----------------
extern "C" void kernel_launch(void* const* d_in, const int* in_sizes, int n_in,
                              void* d_out, int out_size, void* d_ws, size_t ws_size,
                              hipStream_t stream)
{
  (void)in_sizes; (void)n_in; (void)out_size; (void)ws_size;
  const float* videos       = (const float*)d_in[0];
  const float* motions      = (const float*)d_in[1];
  const float* videos_origin= (const float*)d_in[2];
  const int*   lengths      = (const int*)d_in[3];
  const float* Wih_f = (const float*)d_in[4];
  const float* Whh_f = (const float*)d_in[5];
  const float* bih_f = (const float*)d_in[6];
  const float* bhh_f = (const float*)d_in[7];
  const float* Wih_b = (const float*)d_in[8];
  const float* Whh_b = (const float*)d_in[9];
  const float* bih_b = (const float*)d_in[10];
  const float* bhh_b = (const float*)d_in[11];
  const float* fc_w  = (const float*)d_in[12];
  const float* fc_b  = (const float*)d_in[13];
  const float* bn_gamma = (const float*)d_in[14];
  const float* bn_beta  = (const float*)d_in[15];
  const float* bn_mean  = (const float*)d_in[16];
  const float* bn_var   = (const float*)d_in[17];
  const float* conv_w2 = (const float*)d_in[18];
  const float* conv_b2 = (const float*)d_in[19];
  const float* conv_w3 = (const float*)d_in[20];
  const float* conv_b3 = (const float*)d_in[21];
  const float* conv_w4 = (const float*)d_in[22];
  const float* conv_b4 = (const float*)d_in[23];
  float* out = (float*)d_out;
  char* w = (char*)d_ws;

  const size_t XG    = 0;              // 8192x3072 f32 = 100,663,296
  const size_t VID   = 134217728;      // 8192x2048 bf16 = 33,554,432
  const size_t MASKB = 167772160;      // 8192x1024 bf16 = 16,777,216 (FC partials 8MB overlay)
  const size_t WIH   = 184549376;      // 3072x2048 bf16 = 12,582,912
  const size_t WHH   = 197132288;      // 2x1536x512 bf16 = 3,145,728
  const size_t WC    = 200278016;      // 4608x1024 bf16 = 9,437,184
  const size_t FCW   = 209715200;      // 2048x5632 bf16 = 23,068,672
  const size_t FEAT  = 232783872;      // 128x5632 bf16 = 1,441,792
  const size_t BIH   = 235274240;      // 3072 f32
  const size_t BNS   = 235286528;      // 2048 f32
  const size_t BNT   = 235294720;      // 2048 f32
  const size_t HB    = 235302912;      // 2x2x128x512 bf16 = 524,288
  const size_t FLG   = HB + 524288;    // 512 flags x 4B = 2,048

  float* xg   = (float*)(w + XG);
  u16*   zb16 = (u16*)(w + XG);        // overlay
  u16* vid    = (u16*)(w + VID);
  u16* maskb  = (u16*)(w + MASKB);
  float* fcp  = (float*)(w + MASKB);   // FC split-K partials overlay (after conv GEMM)
  u16* wih    = (u16*)(w + WIH);
  u16* whh    = (u16*)(w + WHH);
  u16* wc_    = (u16*)(w + WC);
  u16* fcw    = (u16*)(w + FCW);
  u16* feat   = (u16*)(w + FEAT);
  float* bih  = (float*)(w + BIH);
  float* bns  = (float*)(w + BNS);
  float* bnt  = (float*)(w + BNT);
  u16* hb     = (u16*)(w + HB);
  int* flg    = (int*)(w + FLG);

  // zero h double-buffer (parity0 read at t=0) + compact flags, every launch
  hipMemsetAsync(w + HB, 0, 524288 + 2048, stream);

  k_pre_cvt<<<4096, 256, 0, stream>>>(
      videos, Wih_f, Wih_b, Whh_f, Whh_b, bih_f, bih_b,
      fc_b, bn_gamma, bn_beta, bn_mean, bn_var,
      vid, wih, whh, bih, bns, bnt);

  // xg = videos @ [Wih_f;Wih_b]^T + bih  (f32 out), 256^2 8-phase
  gemm256<<<dim3(12, 32), 512, 0, stream>>>(vid, wih, xg, nullptr, 8192, 3072, 2048, 32, bih);

  {
    const float* xg_c = xg; const u16* whh_c = whh;
    u16* hb_c = hb; u16* mb_c = maskb; u16* ft_c = feat;
    const int* len_c = lengths; int* flg_c = flg;
    const float* bf_c = bhh_f; const float* bb_c = bhh_b;
    const float* fw_c = fc_w; const float* w2_c = conv_w2;
    const float* w3_c = conv_w3; const float* w4_c = conv_w4;
    const float* vo_c = videos_origin; const float* mo_c = motions;
    u16* fcw_c = fcw; u16* wc_c = wc_;
    void* args[] = { (void*)&xg_c, (void*)&whh_c, (void*)&bf_c, (void*)&bb_c,
                     (void*)&hb_c, (void*)&mb_c, (void*)&ft_c, (void*)&len_c, (void*)&flg_c,
                     (void*)&fw_c, (void*)&w2_c, (void*)&w3_c, (void*)&w4_c,
                     (void*)&vo_c, (void*)&mo_c, (void*)&fcw_c, (void*)&wc_c };
    hipLaunchCooperativeKernel(reinterpret_cast<void*>(gru_rec), dim3(256), dim3(512), args, 0, stream);
  }

  // z = masked @ Wc^T (bf16 out), 256^2 8-phase
  gemm256<<<dim3(18, 32), 512, 0, stream>>>(maskb, wc_, nullptr, zb16, 8192, 4608, 1024, 16, nullptr);
  k_conv_finish<<<dim3(128, 3), 256, 0, stream>>>(zb16, conv_b2, conv_b3, conv_b4, feat);
  // FC split-K x8 (raw partials; BN folded into l2norm)
  gemm_bt<<<dim3(16, 1, 8), 256, 0, stream>>>(feat, fcw, fcp, nullptr, 128, 2048, 5632, 22, nullptr, nullptr);
  k_l2norm<<<128, 256, 0, stream>>>(fcp, bns, bnt, out);
}

// Round 12
// 560.550 us; speedup vs baseline: 1.4750x; 1.0574x over previous
//
#include <hip/hip_runtime.h>
#include <hip/hip_bf16.h>
#include <stdint.h>

typedef __attribute__((ext_vector_type(8))) short short8;
typedef __attribute__((ext_vector_type(4))) float floatx4;
typedef __attribute__((ext_vector_type(4))) unsigned int u32x4;
typedef unsigned short u16;
typedef unsigned int u32;
typedef unsigned long long u64;

static __device__ __forceinline__ u16 f2bf(float f) {
  union { float f; u32 u; } v; v.f = f;
  return (u16)((v.u + 0x7fffu + ((v.u >> 16) & 1u)) >> 16);
}
static __device__ __forceinline__ float bf2f(u16 h) {
  union { u32 u; float f; } v; v.u = ((u32)h) << 16; return v.f;
}
static __device__ __forceinline__ u64 pack4(float a, float b, float c, float d) {
  return (u64)f2bf(a) | ((u64)f2bf(b) << 16) | ((u64)f2bf(c) << 32) | ((u64)f2bf(d) << 48);
}

// ---------------- pre-GEMM conversions (vid/wih/whh/bias only; rest co-runs with gru) ----------------
__global__ __launch_bounds__(256) void k_pre_cvt(
    const float* __restrict__ videos, const float* __restrict__ Wih_f,
    const float* __restrict__ Wih_b, const float* __restrict__ Whh_f,
    const float* __restrict__ Whh_b, const float* __restrict__ bih_f,
    const float* __restrict__ bih_b, const float* __restrict__ fcb,
    const float* __restrict__ gam, const float* __restrict__ bet,
    const float* __restrict__ mu, const float* __restrict__ var,
    u16* __restrict__ vid, u16* __restrict__ wih, u16* __restrict__ whh,
    float* __restrict__ bihcat, float* __restrict__ bns, float* __restrict__ bnt)
{
  const int O1 = 4194304;            // vid quads
  const int O2 = O1 + 786432;        // wih_f
  const int O3 = O2 + 786432;        // wih_b
  const int O4 = O3 + 196608;        // whh_f
  const int O5 = O4 + 196608;        // whh_b
  const int NQ = O5 + 1280;          // 768 bihcat quads + 512 bn quads
  for (int q = blockIdx.x * 256 + threadIdx.x; q < NQ; q += gridDim.x * 256) {
    if (q < O1) {
      float4 v = ((const float4*)videos)[q];
      ((u64*)vid)[q] = pack4(v.x, v.y, v.z, v.w);
    } else if (q < O2) {
      int r = q - O1; float4 v = ((const float4*)Wih_f)[r];
      ((u64*)wih)[r] = pack4(v.x, v.y, v.z, v.w);
    } else if (q < O3) {
      int r = q - O2; float4 v = ((const float4*)Wih_b)[r];
      ((u64*)wih)[r + 786432] = pack4(v.x, v.y, v.z, v.w);
    } else if (q < O4) {
      int r = q - O3; float4 v = ((const float4*)Whh_f)[r];
      ((u64*)whh)[r] = pack4(v.x, v.y, v.z, v.w);
    } else if (q < O5) {
      int r = q - O4; float4 v = ((const float4*)Whh_b)[r];
      ((u64*)whh)[r + 196608] = pack4(v.x, v.y, v.z, v.w);
    } else {
      int r = q - O5;
      if (r < 768) {
        int i = r * 4;  // 1536 % 4 == 0: quad never straddles f/b boundary
        const float* s = (i < 1536) ? (bih_f + i) : (bih_b + (i - 1536));
        *(float4*)&bihcat[i] = *(const float4*)s;
      } else {
        int i = (r - 768) * 4;
#pragma unroll
        for (int j = 0; j < 4; ++j) {
          int idx = i + j;
          float sc = gam[idx] * rsqrtf(var[idx] + 1e-5f);
          bns[idx] = sc;
          bnt[idx] = sc * (fcb[idx] - mu[idx]) + bet[idx];
        }
      }
    }
  }
}

static __device__ __forceinline__ void gload_lds16(const u16* g, u16* l) {
  __builtin_amdgcn_global_load_lds((const __attribute__((address_space(1))) u32*)(const void*)g,
                                   (__attribute__((address_space(3))) u32*)(void*)l, 16, 0, 0);
}

// ---------------- 256x256 8-phase bf16 GEMM (R8, proven) ----------------
static __device__ __forceinline__ void stage_half_256(
    const u16* __restrict__ Mat, long K, int rowbase, int ktile, u16* lregion,
    int tid, int wid)
{
  int srow = tid >> 3;
  int sce = (((tid >> 3) ^ tid) & 7) * 8;   // pre-swizzled source col (elems)
  const u16* g0 = Mat + (long)(rowbase + srow) * K + ktile * 64 + sce;
  const u16* g1 = Mat + (long)(rowbase + 64 + srow) * K + ktile * 64 + sce;
  gload_lds16(g0, lregion + wid * 512);
  gload_lds16(g1, lregion + 4096 + wid * 512);
}

__global__ __launch_bounds__(512) void gemm256(
    const u16* __restrict__ A, const u16* __restrict__ Bm,
    float* __restrict__ C, u16* __restrict__ C16, int M, int N, int K, int NT,
    const float* __restrict__ shift)
{
  __shared__ u16 lds[65536];   // 128 KB
  int tid = threadIdx.x, lane = tid & 63, wid = tid >> 6;
  int r16 = lane & 15, kq = lane >> 4;
  int wr = wid >> 2, wc = wid & 3;
  int nwg = gridDim.x * gridDim.y;
  int lin = blockIdx.y * gridDim.x + blockIdx.x;
  int q8 = nwg >> 3;
  int swz = (lin & 7) * q8 + (lin >> 3);
  int m0 = (swz / gridDim.x) * 256, n0 = (swz % gridDim.x) * 256;

  int fxor = (r16 & 7) << 4;
  int c0 = (kq * 16) ^ fxor;
  int c1 = c0 ^ 64;
  int brow0 = (wc & 1) * 64;
  const char* ldsc = (const char*)lds;

  const floatx4 z4 = {0.f, 0.f, 0.f, 0.f};
  floatx4 acc[8][4];
#pragma unroll
  for (int i = 0; i < 8; ++i)
#pragma unroll
    for (int j = 0; j < 4; ++j) acc[i][j] = z4;

  stage_half_256(Bm, K, n0,       0, lds,                 tid, wid);
  stage_half_256(Bm, K, n0 + 128, 0, lds + 8192,          tid, wid);
  stage_half_256(A,  K, m0,       0, lds + 16384,         tid, wid);
  stage_half_256(A,  K, m0 + 128, 0, lds + 24576,         tid, wid);
  stage_half_256(Bm, K, n0,       1, lds + 32768,         tid, wid);
  stage_half_256(Bm, K, n0 + 128, 1, lds + 32768 + 8192,  tid, wid);
  stage_half_256(A,  K, m0,       1, lds + 32768 + 16384, tid, wid);
  stage_half_256(A,  K, m0 + 128, 1, lds + 32768 + 24576, tid, wid);
  asm volatile("s_waitcnt vmcnt(8)" ::: "memory");
  asm volatile("s_barrier" ::: "memory");

#define MFMA_CLUSTER(q)                                                        \
  asm volatile("s_waitcnt lgkmcnt(0)" ::: "memory");                           \
  __builtin_amdgcn_sched_barrier(0);                                           \
  __builtin_amdgcn_s_setprio(1);                                               \
  _Pragma("unroll")                                                            \
  for (int s = 0; s < 2; ++s)                                                  \
    _Pragma("unroll")                                                          \
    for (int e = 0; e < 2; ++e)                                                \
      _Pragma("unroll")                                                        \
      for (int j = 0; j < 4; ++j)                                              \
        acc[(q)*2 + e][j] = __builtin_amdgcn_mfma_f32_16x16x32_bf16(           \
            af[e][s], bf[j][s], acc[(q)*2 + e][j], 0, 0, 0);                   \
  __builtin_amdgcn_s_setprio(0);

  for (int T = 0; T < NT; ++T) {
    int P = T & 1;
    int Tn1 = (T + 1 < NT) ? T + 1 : 0;
    int Tn2 = (T + 2 < NT) ? T + 2 : T + 2 - NT;
    const char* bbase = ldsc + P * 65536 + (wc >> 1) * 16384;
    const char* abase = ldsc + P * 65536 + 32768 + wr * 16384;
    short8 bf[4][2];
    {
#pragma unroll
      for (int j = 0; j < 4; ++j) {
        bf[j][0] = *(const short8*)(bbase + (brow0 + j * 16 + r16) * 128 + c0);
        bf[j][1] = *(const short8*)(bbase + (brow0 + j * 16 + r16) * 128 + c1);
      }
      short8 af[2][2];
#pragma unroll
      for (int e = 0; e < 2; ++e) {
        af[e][0] = *(const short8*)(abase + (e * 16 + r16) * 128 + c0);
        af[e][1] = *(const short8*)(abase + (e * 16 + r16) * 128 + c1);
      }
      stage_half_256(A, K, m0, Tn1, lds + (Tn1 & 1) * 32768 + 16384, tid, wid);
      asm volatile("s_barrier" ::: "memory");
      MFMA_CLUSTER(0)
      asm volatile("s_barrier" ::: "memory");
    }
    {
      short8 af[2][2];
#pragma unroll
      for (int e = 0; e < 2; ++e) {
        af[e][0] = *(const short8*)(abase + ((2 + e) * 16 + r16) * 128 + c0);
        af[e][1] = *(const short8*)(abase + ((2 + e) * 16 + r16) * 128 + c1);
      }
      stage_half_256(A, K, m0 + 128, Tn1, lds + (Tn1 & 1) * 32768 + 24576, tid, wid);
      asm volatile("s_barrier" ::: "memory");
      MFMA_CLUSTER(1)
      asm volatile("s_barrier" ::: "memory");
    }
    {
      short8 af[2][2];
#pragma unroll
      for (int e = 0; e < 2; ++e) {
        af[e][0] = *(const short8*)(abase + ((4 + e) * 16 + r16) * 128 + c0);
        af[e][1] = *(const short8*)(abase + ((4 + e) * 16 + r16) * 128 + c1);
      }
      stage_half_256(Bm, K, n0, Tn2, lds + P * 32768, tid, wid);
      asm volatile("s_barrier" ::: "memory");
      MFMA_CLUSTER(2)
      asm volatile("s_barrier" ::: "memory");
    }
    {
      short8 af[2][2];
#pragma unroll
      for (int e = 0; e < 2; ++e) {
        af[e][0] = *(const short8*)(abase + ((6 + e) * 16 + r16) * 128 + c0);
        af[e][1] = *(const short8*)(abase + ((6 + e) * 16 + r16) * 128 + c1);
      }
      stage_half_256(Bm, K, n0 + 128, Tn2, lds + P * 32768 + 8192, tid, wid);
      asm volatile("s_barrier" ::: "memory");
      MFMA_CLUSTER(3)
      asm volatile("s_waitcnt vmcnt(4)" ::: "memory");
      asm volatile("s_barrier" ::: "memory");
    }
  }
#undef MFMA_CLUSTER

#pragma unroll
  for (int mf = 0; mf < 8; ++mf)
#pragma unroll
    for (int j = 0; j < 4; ++j) {
      int col = n0 + wc * 64 + j * 16 + r16;
      int row = m0 + wr * 128 + mf * 16 + kq * 4;
      if (C16) {
#pragma unroll
        for (int qq = 0; qq < 4; ++qq)
          C16[(long)(row + qq) * N + col] = f2bf(acc[mf][j][qq]);
      } else {
        float sh = shift ? shift[col] : 0.f;
#pragma unroll
        for (int qq = 0; qq < 4; ++qq)
          C[(long)(row + qq) * N + col] = acc[mf][j][qq] + sh;
      }
    }
}

// ---------------- 128x128 MFMA GEMM (kept for the small FC GEMM) ----------------
__global__ __launch_bounds__(256) void gemm_bt(
    const u16* __restrict__ A, const u16* __restrict__ Bm,
    float* __restrict__ C, u16* __restrict__ C16, int M, int N, int K, int kn,
    const float* __restrict__ scale, const float* __restrict__ shift)
{
  __shared__ u16 As[128 * 32];
  __shared__ u16 Bs[128 * 32];
  int tid = threadIdx.x, lane = tid & 63, wid = tid >> 6;
  int nwg = gridDim.x * gridDim.y;
  int lin = blockIdx.y * gridDim.x + blockIdx.x;
  int q8 = nwg >> 3;
  int swz = (lin & 7) * q8 + (lin >> 3);
  int m0 = (swz / gridDim.x) * 128, n0 = (swz % gridDim.x) * 128;
  int kt0 = blockIdx.z * kn;
  int wr = wid >> 1, wc = wid & 1;
  int r16 = lane & 15, kq = lane >> 4;
  const floatx4 z4 = {0.f, 0.f, 0.f, 0.f};
  floatx4 acc[4][4];
#pragma unroll
  for (int i = 0; i < 4; ++i)
#pragma unroll
    for (int j = 0; j < 4; ++j) acc[i][j] = z4;
  for (int kt = kt0; kt < kt0 + kn; ++kt) {
    __syncthreads();
#pragma unroll
    for (int inst = 0; inst < 2; ++inst) {
      int g = inst * 256 + tid;
      int row = g >> 2, cb = g & 3;
      const u16* ga = A + (long)(m0 + row) * K + kt * 32 + cb * 8;
      const u16* gb = Bm + (long)(n0 + row) * K + kt * 32 + cb * 8;
      gload_lds16(ga, &As[(inst * 256 + wid * 64) * 8]);
      gload_lds16(gb, &Bs[(inst * 256 + wid * 64) * 8]);
    }
    __syncthreads();
    short8 af[4], bf[4];
#pragma unroll
    for (int mt = 0; mt < 4; ++mt) af[mt] = *(const short8*)&As[(wr * 64 + mt * 16 + r16) * 32 + kq * 8];
#pragma unroll
    for (int nt = 0; nt < 4; ++nt) bf[nt] = *(const short8*)&Bs[(wc * 64 + nt * 16 + r16) * 32 + kq * 8];
#pragma unroll
    for (int mt = 0; mt < 4; ++mt)
#pragma unroll
      for (int nt = 0; nt < 4; ++nt)
        acc[mt][nt] = __builtin_amdgcn_mfma_f32_16x16x32_bf16(af[mt], bf[nt], acc[mt][nt], 0, 0, 0);
  }
  float* Cp = C + (long)blockIdx.z * M * N;
#pragma unroll
  for (int nt = 0; nt < 4; ++nt) {
    int col = n0 + wc * 64 + nt * 16 + r16;
    float sc = scale ? scale[col] : 1.f;
    float sh = shift ? shift[col] : 0.f;
#pragma unroll
    for (int mt = 0; mt < 4; ++mt)
#pragma unroll
      for (int q = 0; q < 4; ++q) {
        int row = m0 + wr * 64 + mt * 16 + kq * 4 + q;
        float v = acc[mt][nt][q] * sc + sh;
        if (C16) C16[(long)row * N + col] = f2bf(v);
        else     Cp[(long)row * N + col] = v;
      }
  }
}

// ---------------- GRU recurrence (R11: single-hop tagged exchange) ----------------
// Exchange redesign: h published as 8-byte pairs {2xbf16 data, u32 tag} via
// global_atomic_swap_x2 (architecturally ATOMIC 8B write at the coherence
// point — cannot tear, unlike R3's 16B plain-store scheme). Consumers load
// pairs (sc0 sc1) and retry until tags match; the data load IS the poll.
// Removes per step: producer vmcnt(0) ack drain, flag store, separate poll
// phase — 3 serialized hops -> 1. Double-buffer safety: producer overwrites
// slot S at t+2 only after verifying all blocks' t+1 tags, which transitively
// proves all step-t reads of S are done (publish follows consumption).
// Tagged buffer [2 par][2 dir][8 bt] x 32KB (4096 pairs), zeroed each launch
// (tag 0 = t=0 expectation, data 0 = h0). Consumer: 4 interleaved dwordx4
// loads (wave-coalesced 1KB/instr), per-thread tag check + s_sleep backoff,
// 4x ds_write_b64 into the same XOR-swizzled hstage layout.
// R9 co-run (converter blocks 128-255) unchanged.
__global__ __launch_bounds__(512) void gru_rec(
    const float* __restrict__ xg,     // [8192][3072]
    const u16* __restrict__ whhb,     // [2][1536][512] bf16
    const float* __restrict__ bhh_f, const float* __restrict__ bhh_b,
    char* __restrict__ hb3,           // tagged exchange, 1MB, zeroed each launch
    u16* __restrict__ maskb,          // [8192][1024] bf16 masked output
    u16* __restrict__ feat,           // [128][5632] bf16 (gru mean + vo/mo sections)
    const int* __restrict__ lengths,  // [128]
    const float* __restrict__ fc_w, const float* __restrict__ w2,
    const float* __restrict__ w3, const float* __restrict__ w4,
    const float* __restrict__ vo, const float* __restrict__ mo,
    u16* __restrict__ fcw, u16* __restrict__ wc)
{
  __shared__ float part[2][4][3][256];
  __shared__ u16 hstage[8192];        // 16KB: h[16 batches][512 i] bf16, XOR-swizzled
  int tid = threadIdx.x, lane = tid & 63, wid = tid >> 6;
  int bid = blockIdx.x;

  if (bid >= 128) {
    // -------- converter blocks: fcw, wc remap, vo/mo feat sections --------
    int cid = bid - 128;
    const int C1 = 2883584;           // fcw quads
    const int C2 = C1 + 1179648;      // wc quads
    const int C3 = C2 + 65536;        // vo
    const int NQ = C3 + 32768;        // mo
    for (int q = cid * 512 + tid; q < NQ; q += 128 * 512) {
      if (q < C1) {
        float4 v = ((const float4*)fc_w)[q];
        ((u64*)fcw)[q] = pack4(v.x, v.y, v.z, v.w);
      } else if (q < C2) {
        int r = q - C1;
        int e = r << 2;
        int row = e >> 10, col = e & 1023;
        const float* src;
        if (row < 1024)      { int j = row >> 9, k = row & 511;                 src = w2 + (k * 2 + j) * 1024; }
        else if (row < 2560) { int m = row - 1024; int j = m >> 9, k = m & 511; src = w3 + (k * 3 + j) * 1024; }
        else                 { int m = row - 2560; int j = m >> 9, k = m & 511; src = w4 + (k * 4 + j) * 1024; }
        float4 v = *(const float4*)(src + col);
        ((u64*)wc)[r] = pack4(v.x, v.y, v.z, v.w);
      } else if (q < C3) {
        int r = q - C2; int b = r >> 9, c = (r & 511) * 4;
        float4 v = *(const float4*)&vo[(long)b * 2048 + c];
        *(u64*)&feat[(long)b * 5632 + 2560 + c] = pack4(v.x, v.y, v.z, v.w);
      } else {
        int r = q - C3; int b = r >> 8, c = (r & 255) * 4;
        float4 v = *(const float4*)&mo[(long)b * 1024 + c];
        *(u64*)&feat[(long)b * 5632 + 4608 + c] = pack4(v.x, v.y, v.z, v.w);
      }
    }
    return;
  }

  // -------- recurrence blocks --------
  int dir = bid >> 6, rem = bid & 63, bt = rem >> 3, is = rem & 7;
  int ih = wid & 3, ks = wid >> 2;
  int r16 = lane & 15, kq = lane >> 4;
  int iglob = is * 64 + ih * 16 + r16;
  int i0 = is * 64 + ih * 16 + kq * 4;
  int batch = bt * 16 + r16;
  const float* bhh = dir ? bhh_b : bhh_f;
  const floatx4 z4 = {0.f, 0.f, 0.f, 0.f};
  int len = lengths[batch];

  short8 wfrag[3][8];
#pragma unroll
  for (int g = 0; g < 3; ++g) {
    const u16* wrow = whhb + (long)(dir * 1536 + g * 512 + iglob) * 512;
#pragma unroll
    for (int kk = 0; kk < 8; ++kk)
      wfrag[g][kk] = *(const short8*)&wrow[(ks * 8 + kk) * 32 + kq * 8];
  }
  float4 bh4[3];
#pragma unroll
  for (int g = 0; g < 3; ++g) bh4[g] = *(const float4*)&bhh[g * 512 + i0];
  float4 hprev = {0.f, 0.f, 0.f, 0.f};
  float4 msum = {0.f, 0.f, 0.f, 0.f};

  float4 px[3];
  if (ks == 0) {
    int ts0 = dir ? 63 : 0;
    long xb = (long)(batch * 64 + ts0) * 3072 + dir * 1536 + i0;
#pragma unroll
    for (int g = 0; g < 3; ++g) px[g] = *(const float4*)&xg[xb + g * 512];
  }

  // tagged-exchange addressing
  char* slot[2];
  slot[0] = hb3 + (long)((0 * 2 + dir) * 8 + bt) * 32768;
  slot[1] = hb3 + (long)((1 * 2 + dir) * 8 + bt) * 32768;
  // consumer LDS dests: load k covers pairs p = k*1024 + tid*2 + {0,1}
  //   -> batch row = 4k + (tid>>7), i0 = (tid&127)*4, 8B data per k
  char* sdst[4];
#pragma unroll
  for (int k = 0; k < 4; ++k) {
    int row = 4 * k + (tid >> 7);
    int colb = (tid & 127) * 8;
    sdst[k] = (char*)hstage + row * 1024 + (colb ^ ((row & 7) << 4));
  }
  int ld_off = tid * 16;
  // producer pair index (ks0 lanes): p0 = batch_local*256 + i0/2
  int p0 = r16 * 256 + is * 32 + ih * 8 + kq * 2;
  // fragment read base (unchanged layout)
  int rb = r16 * 1024 + ks * 512 + kq * 16;
  int rsw = (r16 & 7) << 4;

  for (int t = 0; t < 64; ++t) {
    int par = t & 1;
    u32 tg = (u32)t;
    // ---- stage with tag-verify: the data load IS the poll ----
    const char* sb = slot[par];
    u32x4 L0, L1, L2, L3;
    while (true) {
      asm volatile(
        "global_load_dwordx4 %0, %4, off sc0 sc1\n\t"
        "global_load_dwordx4 %1, %5, off sc0 sc1\n\t"
        "global_load_dwordx4 %2, %6, off sc0 sc1\n\t"
        "global_load_dwordx4 %3, %7, off sc0 sc1\n\t"
        "s_waitcnt vmcnt(0)"
        : "=&v"(L0), "=&v"(L1), "=&v"(L2), "=&v"(L3)
        : "v"(sb + ld_off), "v"(sb + 8192 + ld_off),
          "v"(sb + 16384 + ld_off), "v"(sb + 24576 + ld_off)
        : "memory");
      bool ok = (L0.y == tg) & (L0.w == tg) & (L1.y == tg) & (L1.w == tg) &
                (L2.y == tg) & (L2.w == tg) & (L3.y == tg) & (L3.w == tg);
      if (ok) break;
      __builtin_amdgcn_s_sleep(1);
    }
    *(u64*)sdst[0] = (u64)L0.x | ((u64)L0.z << 32);
    *(u64*)sdst[1] = (u64)L1.x | ((u64)L1.z << 32);
    *(u64*)sdst[2] = (u64)L2.x | ((u64)L2.z << 32);
    *(u64*)sdst[3] = (u64)L3.x | ((u64)L3.z << 32);
    // ---- next-step xg prefetch (off critical path) ----
    float4 pxn[3];
    if (ks == 0 && t < 63) {
      int ts1 = dir ? (62 - t) : (t + 1);
      long xb = (long)(batch * 64 + ts1) * 3072 + dir * 1536 + i0;
#pragma unroll
      for (int g = 0; g < 3; ++g) pxn[g] = *(const float4*)&xg[xb + g * 512];
    }
    asm volatile("s_waitcnt lgkmcnt(0)\n\ts_barrier" ::: "memory");
    // ---- fragments from LDS + MFMA ----
    floatx4 acc[3];
#pragma unroll
    for (int g = 0; g < 3; ++g) acc[g] = z4;
#pragma unroll
    for (int kk = 0; kk < 8; ++kk) {
      short8 hv = *(const short8*)((const char*)hstage + ((rb + kk * 64) ^ rsw));
#pragma unroll
      for (int g = 0; g < 3; ++g)
        acc[g] = __builtin_amdgcn_mfma_f32_16x16x32_bf16(wfrag[g][kk], hv, acc[g], 0, 0, 0);
    }
    if (ks == 1) {
#pragma unroll
      for (int g = 0; g < 3; ++g) *(floatx4*)&part[par][ih][g][lane * 4] = acc[g];
    }
    asm volatile("s_waitcnt lgkmcnt(0)\n\ts_barrier" ::: "memory");
    if (ks == 0) {
      int tsrc = dir ? (63 - t) : t;
#pragma unroll
      for (int g = 0; g < 3; ++g) acc[g] += *(const floatx4*)&part[par][ih][g][lane * 4];
      float4 hn4;
#pragma unroll
      for (int q = 0; q < 4; ++q) {
        float rr = acc[0][q] + ((const float*)&bh4[0])[q] + ((const float*)&px[0])[q];
        float zz = acc[1][q] + ((const float*)&bh4[1])[q] + ((const float*)&px[1])[q];
        float r = 1.f / (1.f + __expf(-rr));
        float z = 1.f / (1.f + __expf(-zz));
        float n = tanhf(((const float*)&px[2])[q] + r * (acc[2][q] + ((const float*)&bh4[2])[q]));
        ((float*)&hn4)[q] = (1.f - z) * n + z * ((const float*)&hprev)[q];
      }
      hprev = hn4;
      u64 hval = pack4(hn4.x, hn4.y, hn4.z, hn4.w);
      if (t < 63) {
        // publish: two ATOMIC 8B pairs {data32, tag} — fire-and-forget, no ack
        u32 tg1 = (u32)(t + 1);
        char* pb = slot[(t + 1) & 1] + p0 * 8;
        u64 v0 = (u64)(u32)hval | ((u64)tg1 << 32);
        u64 v1 = (u64)(u32)(hval >> 32) | ((u64)tg1 << 32);
        asm volatile("global_atomic_swap_x2 %0, %1, off sc1"
                     :: "v"(pb), "v"(v0) : "memory");
        asm volatile("global_atomic_swap_x2 %0, %1, off sc1"
                     :: "v"(pb + 8), "v"(v1) : "memory");
      }
      bool mv = tsrc < len;
      *(u64*)&maskb[(long)(batch * 64 + tsrc) * 1024 + dir * 512 + i0] = mv ? hval : 0ull;
      if (mv) {
        msum.x += hn4.x; msum.y += hn4.y; msum.z += hn4.z; msum.w += hn4.w;
      }
      px[0] = pxn[0]; px[1] = pxn[1]; px[2] = pxn[2];
    }
  }
  if (ks == 0) {
    float inv = 1.0f / (float)len;
    *(u64*)&feat[(long)batch * 5632 + dir * 512 + i0] =
        pack4(msum.x * inv, msum.y * inv, msum.z * inv, msum.w * inv);
  }
}

// ---------------- conv shift-add + relu + max over positions (z is bf16) ----------------
__global__ __launch_bounds__(256) void k_conv_finish(
    const u16* __restrict__ z, const float* __restrict__ cb2,
    const float* __restrict__ cb3, const float* __restrict__ cb4,
    u16* __restrict__ feat)
{
  int b = blockIdx.x, wsi = blockIdx.y, k2 = threadIdx.x * 2;
  int ws = wsi + 2;
  int base = (wsi == 0) ? 0 : (wsi == 1 ? 1024 : 2560);
  const float* cb = (wsi == 0) ? cb2 : (wsi == 1 ? cb3 : cb4);
  float bias0 = cb[k2], bias1 = cb[k2 + 1];
  float m0 = 0.f, m1 = 0.f;
  for (int p = 0; p < 64 + ws - 1; ++p) {
    float a0 = bias0, a1 = bias1;
    for (int j = 0; j < ws; ++j) {
      int t = p - (ws - 1) + j;
      if (t >= 0 && t < 64) {
        u32 v = *(const u32*)&z[(long)(b * 64 + t) * 4608 + base + j * 512 + k2];
        a0 += bf2f((u16)v);
        a1 += bf2f((u16)(v >> 16));
      }
    }
    m0 = fmaxf(m0, a0);
    m1 = fmaxf(m1, a1);
  }
  *(u32*)&feat[(long)b * 5632 + 1024 + wsi * 512 + k2] = (u32)f2bf(m0) | ((u32)f2bf(m1) << 16);
}

// ---------------- split-K reduce + BN + row L2 normalize (8 partials) ----------------
__global__ __launch_bounds__(256) void k_l2norm(const float* __restrict__ p,
    const float* __restrict__ bns, const float* __restrict__ bnt, float* __restrict__ out)
{
  __shared__ float red[4];
  int b = blockIdx.x, tid = threadIdx.x;
  float v[8]; float s = 0.f;
#pragma unroll
  for (int j = 0; j < 8; ++j) {
    int i = j * 256 + tid;
    long o = (long)b * 2048 + i;
    float a = 0.f;
#pragma unroll
    for (int zz = 0; zz < 8; ++zz) a += p[o + (long)zz * 262144];
    a = a * bns[i] + bnt[i];
    v[j] = a; s += a * a;
  }
#pragma unroll
  for (int o = 32; o > 0; o >>= 1) s += __shfl_down(s, o);
  if ((tid & 63) == 0) red[tid >> 6] = s;
  __syncthreads();
  float rn = rsqrtf(red[0] + red[1] + red[2] + red[3]);
#pragma unroll
  for (int j = 0; j < 8; ++j)
    out[(long)b * 2048 + j * 256 + tid] = v[j] * rn;
}

// ---------------- launch ----------------
extern "C" void kernel_launch(void* const* d_in, const int* in_sizes, int n_in,
                              void* d_out, int out_size, void* d_ws, size_t ws_size,
                              hipStream_t stream)
{
  (void)in_sizes; (void)n_in; (void)out_size; (void)ws_size;
  const float* videos       = (const float*)d_in[0];
  const float* motions      = (const float*)d_in[1];
  const float* videos_origin= (const float*)d_in[2];
  const int*   lengths      = (const int*)d_in[3];
  const float* Wih_f = (const float*)d_in[4];
  const float* Whh_f = (const float*)d_in[5];
  const float* bih_f = (const float*)d_in[6];
  const float* bhh_f = (const float*)d_in[7];
  const float* Wih_b = (const float*)d_in[8];
  const float* Whh_b = (const float*)d_in[9];
  const float* bih_b = (const float*)d_in[10];
  const float* bhh_b = (const float*)d_in[11];
  const float* fc_w  = (const float*)d_in[12];
  const float* fc_b  = (const float*)d_in[13];
  const float* bn_gamma = (const float*)d_in[14];
  const float* bn_beta  = (const float*)d_in[15];
  const float* bn_mean  = (const float*)d_in[16];
  const float* bn_var   = (const float*)d_in[17];
  const float* conv_w2 = (const float*)d_in[18];
  const float* conv_b2 = (const float*)d_in[19];
  const float* conv_w3 = (const float*)d_in[20];
  const float* conv_b3 = (const float*)d_in[21];
  const float* conv_w4 = (const float*)d_in[22];
  const float* conv_b4 = (const float*)d_in[23];
  float* out = (float*)d_out;
  char* w = (char*)d_ws;

  const size_t XG    = 0;              // 8192x3072 f32 = 100,663,296
  const size_t HS    = 100663296;      // dead region: tagged h exchange (1MB)
  const size_t VID   = 134217728;      // 8192x2048 bf16 = 33,554,432
  const size_t MASKB = 167772160;      // 8192x1024 bf16 = 16,777,216 (FC partials 8MB overlay)
  const size_t WIH   = 184549376;      // 3072x2048 bf16 = 12,582,912
  const size_t WHH   = 197132288;      // 2x1536x512 bf16 = 3,145,728
  const size_t WC    = 200278016;      // 4608x1024 bf16 = 9,437,184
  const size_t FCW   = 209715200;      // 2048x5632 bf16 = 23,068,672
  const size_t FEAT  = 232783872;      // 128x5632 bf16 = 1,441,792
  const size_t BIH   = 235274240;      // 3072 f32
  const size_t BNS   = 235286528;      // 2048 f32
  const size_t BNT   = 235294720;      // 2048 f32

  float* xg   = (float*)(w + XG);
  u16*   zb16 = (u16*)(w + XG);        // overlay
  char* hb3   = (char*)(w + HS);       // tagged exchange (1MB)
  u16* vid    = (u16*)(w + VID);
  u16* maskb  = (u16*)(w + MASKB);
  float* fcp  = (float*)(w + MASKB);   // FC split-K partials overlay (after conv GEMM)
  u16* wih    = (u16*)(w + WIH);
  u16* whh    = (u16*)(w + WHH);
  u16* wc_    = (u16*)(w + WC);
  u16* fcw    = (u16*)(w + FCW);
  u16* feat   = (u16*)(w + FEAT);
  float* bih  = (float*)(w + BIH);
  float* bns  = (float*)(w + BNS);
  float* bnt  = (float*)(w + BNT);

  // zero tagged exchange (tags 0 expected at t=0; data 0 = h0), every launch
  hipMemsetAsync(hb3, 0, 1048576, stream);

  k_pre_cvt<<<4096, 256, 0, stream>>>(
      videos, Wih_f, Wih_b, Whh_f, Whh_b, bih_f, bih_b,
      fc_b, bn_gamma, bn_beta, bn_mean, bn_var,
      vid, wih, whh, bih, bns, bnt);

  // xg = videos @ [Wih_f;Wih_b]^T + bih  (f32 out), 256^2 8-phase
  gemm256<<<dim3(12, 32), 512, 0, stream>>>(vid, wih, xg, nullptr, 8192, 3072, 2048, 32, bih);

  {
    const float* xg_c = xg; const u16* whh_c = whh;
    char* hb_c = hb3; u16* mb_c = maskb; u16* ft_c = feat;
    const int* len_c = lengths;
    const float* bf_c = bhh_f; const float* bb_c = bhh_b;
    const float* fw_c = fc_w; const float* w2_c = conv_w2;
    const float* w3_c = conv_w3; const float* w4_c = conv_w4;
    const float* vo_c = videos_origin; const float* mo_c = motions;
    u16* fcw_c = fcw; u16* wc_c = wc_;
    void* args[] = { (void*)&xg_c, (void*)&whh_c, (void*)&bf_c, (void*)&bb_c,
                     (void*)&hb_c, (void*)&mb_c, (void*)&ft_c, (void*)&len_c,
                     (void*)&fw_c, (void*)&w2_c, (void*)&w3_c, (void*)&w4_c,
                     (void*)&vo_c, (void*)&mo_c, (void*)&fcw_c, (void*)&wc_c };
    hipLaunchCooperativeKernel(reinterpret_cast<void*>(gru_rec), dim3(256), dim3(512), args, 0, stream);
  }

  // z = masked @ Wc^T (bf16 out), 256^2 8-phase
  gemm256<<<dim3(18, 32), 512, 0, stream>>>(maskb, wc_, nullptr, zb16, 8192, 4608, 1024, 16, nullptr);
  k_conv_finish<<<dim3(128, 3), 256, 0, stream>>>(zb16, conv_b2, conv_b3, conv_b4, feat);
  // FC split-K x8 (raw partials; BN folded into l2norm)
  gemm_bt<<<dim3(16, 1, 8), 256, 0, stream>>>(feat, fcw, fcp, nullptr, 128, 2048, 5632, 22, nullptr, nullptr);
  k_l2norm<<<128, 256, 0, stream>>>(fcp, bns, bnt, out);
}

// Round 13
// 517.548 us; speedup vs baseline: 1.5976x; 1.0831x over previous
//
#include <hip/hip_runtime.h>
#include <hip/hip_bf16.h>
#include <stdint.h>

typedef __attribute__((ext_vector_type(8))) short short8;
typedef __attribute__((ext_vector_type(4))) float floatx4;
typedef __attribute__((ext_vector_type(4))) unsigned int u32x4;
typedef unsigned short u16;
typedef unsigned int u32;
typedef unsigned long long u64;

static __device__ __forceinline__ u16 f2bf(float f) {
  union { float f; u32 u; } v; v.f = f;
  return (u16)((v.u + 0x7fffu + ((v.u >> 16) & 1u)) >> 16);
}
static __device__ __forceinline__ float bf2f(u16 h) {
  union { u32 u; float f; } v; v.u = ((u32)h) << 16; return v.f;
}
static __device__ __forceinline__ u64 pack4(float a, float b, float c, float d) {
  return (u64)f2bf(a) | ((u64)f2bf(b) << 16) | ((u64)f2bf(c) << 32) | ((u64)f2bf(d) << 48);
}

// ---------------- pre-GEMM conversions (vid/wih/whh/bias only; rest co-runs with gru) ----------------
__global__ __launch_bounds__(256) void k_pre_cvt(
    const float* __restrict__ videos, const float* __restrict__ Wih_f,
    const float* __restrict__ Wih_b, const float* __restrict__ Whh_f,
    const float* __restrict__ Whh_b, const float* __restrict__ bih_f,
    const float* __restrict__ bih_b, const float* __restrict__ fcb,
    const float* __restrict__ gam, const float* __restrict__ bet,
    const float* __restrict__ mu, const float* __restrict__ var,
    u16* __restrict__ vid, u16* __restrict__ wih, u16* __restrict__ whh,
    float* __restrict__ bihcat, float* __restrict__ bns, float* __restrict__ bnt)
{
  const int O1 = 4194304;            // vid quads
  const int O2 = O1 + 786432;        // wih_f
  const int O3 = O2 + 786432;        // wih_b
  const int O4 = O3 + 196608;        // whh_f
  const int O5 = O4 + 196608;        // whh_b
  const int NQ = O5 + 1280;          // 768 bihcat quads + 512 bn quads
  for (int q = blockIdx.x * 256 + threadIdx.x; q < NQ; q += gridDim.x * 256) {
    if (q < O1) {
      float4 v = ((const float4*)videos)[q];
      ((u64*)vid)[q] = pack4(v.x, v.y, v.z, v.w);
    } else if (q < O2) {
      int r = q - O1; float4 v = ((const float4*)Wih_f)[r];
      ((u64*)wih)[r] = pack4(v.x, v.y, v.z, v.w);
    } else if (q < O3) {
      int r = q - O2; float4 v = ((const float4*)Wih_b)[r];
      ((u64*)wih)[r + 786432] = pack4(v.x, v.y, v.z, v.w);
    } else if (q < O4) {
      int r = q - O3; float4 v = ((const float4*)Whh_f)[r];
      ((u64*)whh)[r] = pack4(v.x, v.y, v.z, v.w);
    } else if (q < O5) {
      int r = q - O4; float4 v = ((const float4*)Whh_b)[r];
      ((u64*)whh)[r + 196608] = pack4(v.x, v.y, v.z, v.w);
    } else {
      int r = q - O5;
      if (r < 768) {
        int i = r * 4;  // 1536 % 4 == 0: quad never straddles f/b boundary
        const float* s = (i < 1536) ? (bih_f + i) : (bih_b + (i - 1536));
        *(float4*)&bihcat[i] = *(const float4*)s;
      } else {
        int i = (r - 768) * 4;
#pragma unroll
        for (int j = 0; j < 4; ++j) {
          int idx = i + j;
          float sc = gam[idx] * rsqrtf(var[idx] + 1e-5f);
          bns[idx] = sc;
          bnt[idx] = sc * (fcb[idx] - mu[idx]) + bet[idx];
        }
      }
    }
  }
}

static __device__ __forceinline__ void gload_lds16(const u16* g, u16* l) {
  __builtin_amdgcn_global_load_lds((const __attribute__((address_space(1))) u32*)(const void*)g,
                                   (__attribute__((address_space(3))) u32*)(void*)l, 16, 0, 0);
}

// ---------------- 256x256 8-phase bf16 GEMM (R8, proven) ----------------
static __device__ __forceinline__ void stage_half_256(
    const u16* __restrict__ Mat, long K, int rowbase, int ktile, u16* lregion,
    int tid, int wid)
{
  int srow = tid >> 3;
  int sce = (((tid >> 3) ^ tid) & 7) * 8;   // pre-swizzled source col (elems)
  const u16* g0 = Mat + (long)(rowbase + srow) * K + ktile * 64 + sce;
  const u16* g1 = Mat + (long)(rowbase + 64 + srow) * K + ktile * 64 + sce;
  gload_lds16(g0, lregion + wid * 512);
  gload_lds16(g1, lregion + 4096 + wid * 512);
}

#define GEMM256_BODY(A, Bm, K, NT)                                             \
  __shared__ u16 lds[65536];                                                   \
  int tid = threadIdx.x, lane = tid & 63, wid = tid >> 6;                      \
  int r16 = lane & 15, kq = lane >> 4;                                         \
  int wr = wid >> 2, wc = wid & 3;                                             \
  int nwg = gridDim.x * gridDim.y;                                             \
  int lin = blockIdx.y * gridDim.x + blockIdx.x;                               \
  int q8 = nwg >> 3;                                                           \
  int swz = (lin & 7) * q8 + (lin >> 3);                                       \
  int m0 = (swz / gridDim.x) * 256, n0 = (swz % gridDim.x) * 256;              \
  int fxor = (r16 & 7) << 4;                                                   \
  int c0 = (kq * 16) ^ fxor;                                                   \
  int c1 = c0 ^ 64;                                                            \
  int brow0 = (wc & 1) * 64;                                                   \
  const char* ldsc = (const char*)lds;                                         \
  const floatx4 z4 = {0.f, 0.f, 0.f, 0.f};                                     \
  floatx4 acc[8][4];                                                           \
  _Pragma("unroll")                                                            \
  for (int i = 0; i < 8; ++i)                                                  \
    _Pragma("unroll")                                                          \
    for (int j = 0; j < 4; ++j) acc[i][j] = z4;                                \
  stage_half_256(Bm, K, n0,       0, lds,                 tid, wid);           \
  stage_half_256(Bm, K, n0 + 128, 0, lds + 8192,          tid, wid);           \
  stage_half_256(A,  K, m0,       0, lds + 16384,         tid, wid);           \
  stage_half_256(A,  K, m0 + 128, 0, lds + 24576,         tid, wid);           \
  stage_half_256(Bm, K, n0,       1, lds + 32768,         tid, wid);           \
  stage_half_256(Bm, K, n0 + 128, 1, lds + 32768 + 8192,  tid, wid);           \
  stage_half_256(A,  K, m0,       1, lds + 32768 + 16384, tid, wid);           \
  stage_half_256(A,  K, m0 + 128, 1, lds + 32768 + 24576, tid, wid);           \
  asm volatile("s_waitcnt vmcnt(8)" ::: "memory");                             \
  asm volatile("s_barrier" ::: "memory");                                      \
  for (int T = 0; T < NT; ++T) {                                               \
    int P = T & 1;                                                             \
    int Tn1 = (T + 1 < NT) ? T + 1 : 0;                                        \
    int Tn2 = (T + 2 < NT) ? T + 2 : T + 2 - NT;                               \
    const char* bbase = ldsc + P * 65536 + (wc >> 1) * 16384;                  \
    const char* abase = ldsc + P * 65536 + 32768 + wr * 16384;                 \
    short8 bf[4][2];                                                           \
    {                                                                          \
      _Pragma("unroll")                                                        \
      for (int j = 0; j < 4; ++j) {                                            \
        bf[j][0] = *(const short8*)(bbase + (brow0 + j * 16 + r16) * 128 + c0);\
        bf[j][1] = *(const short8*)(bbase + (brow0 + j * 16 + r16) * 128 + c1);\
      }                                                                        \
      short8 af[2][2];                                                         \
      _Pragma("unroll")                                                        \
      for (int e = 0; e < 2; ++e) {                                            \
        af[e][0] = *(const short8*)(abase + (e * 16 + r16) * 128 + c0);        \
        af[e][1] = *(const short8*)(abase + (e * 16 + r16) * 128 + c1);        \
      }                                                                        \
      stage_half_256(A, K, m0, Tn1, lds + (Tn1 & 1) * 32768 + 16384, tid, wid);\
      asm volatile("s_barrier" ::: "memory");                                  \
      MFMA_CLUSTER(0)                                                          \
      asm volatile("s_barrier" ::: "memory");                                  \
    }                                                                          \
    {                                                                          \
      short8 af[2][2];                                                         \
      _Pragma("unroll")                                                        \
      for (int e = 0; e < 2; ++e) {                                            \
        af[e][0] = *(const short8*)(abase + ((2 + e) * 16 + r16) * 128 + c0);  \
        af[e][1] = *(const short8*)(abase + ((2 + e) * 16 + r16) * 128 + c1);  \
      }                                                                        \
      stage_half_256(A, K, m0 + 128, Tn1, lds + (Tn1 & 1) * 32768 + 24576, tid, wid); \
      asm volatile("s_barrier" ::: "memory");                                  \
      MFMA_CLUSTER(1)                                                          \
      asm volatile("s_barrier" ::: "memory");                                  \
    }                                                                          \
    {                                                                          \
      short8 af[2][2];                                                         \
      _Pragma("unroll")                                                        \
      for (int e = 0; e < 2; ++e) {                                            \
        af[e][0] = *(const short8*)(abase + ((4 + e) * 16 + r16) * 128 + c0);  \
        af[e][1] = *(const short8*)(abase + ((4 + e) * 16 + r16) * 128 + c1);  \
      }                                                                        \
      stage_half_256(Bm, K, n0, Tn2, lds + P * 32768, tid, wid);               \
      asm volatile("s_barrier" ::: "memory");                                  \
      MFMA_CLUSTER(2)                                                          \
      asm volatile("s_barrier" ::: "memory");                                  \
    }                                                                          \
    {                                                                          \
      short8 af[2][2];                                                         \
      _Pragma("unroll")                                                        \
      for (int e = 0; e < 2; ++e) {                                            \
        af[e][0] = *(const short8*)(abase + ((6 + e) * 16 + r16) * 128 + c0);  \
        af[e][1] = *(const short8*)(abase + ((6 + e) * 16 + r16) * 128 + c1);  \
      }                                                                        \
      stage_half_256(Bm, K, n0 + 128, Tn2, lds + P * 32768 + 8192, tid, wid);  \
      asm volatile("s_barrier" ::: "memory");                                  \
      MFMA_CLUSTER(3)                                                          \
      asm volatile("s_waitcnt vmcnt(4)" ::: "memory");                         \
      asm volatile("s_barrier" ::: "memory");                                  \
    }                                                                          \
  }

#define MFMA_CLUSTER(q)                                                        \
  asm volatile("s_waitcnt lgkmcnt(0)" ::: "memory");                           \
  __builtin_amdgcn_sched_barrier(0);                                           \
  __builtin_amdgcn_s_setprio(1);                                               \
  _Pragma("unroll")                                                            \
  for (int s = 0; s < 2; ++s)                                                  \
    _Pragma("unroll")                                                          \
    for (int e = 0; e < 2; ++e)                                                \
      _Pragma("unroll")                                                        \
      for (int j = 0; j < 4; ++j)                                              \
        acc[(q)*2 + e][j] = __builtin_amdgcn_mfma_f32_16x16x32_bf16(           \
            af[e][s], bf[j][s], acc[(q)*2 + e][j], 0, 0, 0);                   \
  __builtin_amdgcn_s_setprio(0);

// xg GEMM: f32 C out + shift (proven R8 epilogue)
__global__ __launch_bounds__(512) void gemm256(
    const u16* __restrict__ A, const u16* __restrict__ Bm,
    float* __restrict__ C, int N, int K, int NT,
    const float* __restrict__ shift)
{
  GEMM256_BODY(A, Bm, K, NT)
#pragma unroll
  for (int mf = 0; mf < 8; ++mf)
#pragma unroll
    for (int j = 0; j < 4; ++j) {
      int col = n0 + wc * 64 + j * 16 + r16;
      int row = m0 + wr * 128 + mf * 16 + kq * 4;
      float sh = shift ? shift[col] : 0.f;
#pragma unroll
      for (int qq = 0; qq < 4; ++qq)
        C[(long)(row + qq) * N + col] = acc[mf][j][qq] + sh;
    }
}

// conv GEMM with fused conv-finish (R12).
// Wc layout is k-interleaved: section ws2 rows [0,1024) = k*2+j; ws3 rows
// [1024,3072) = 1024 + k*4 + j (j=3 zero-padded); ws4 rows [3072,5120) =
// 3072 + k*4 + j. Tiles never straddle sections (0/1024/3072 all %256==0),
// so each 256-col N-tile holds ALL j columns for its k-range, and each
// 256-row M-tile holds ALL 64 timesteps of its 4 batches -> the shift-add +
// relu + max reduction closes entirely inside the block: acc -> LDS z-tile
// (256x256 bf16 = 128KB, exact staging-LDS reuse after vmcnt(0) drain) ->
// per-thread reduce -> feat. Same f2bf/bf2f rounding as the old z path.
__global__ __launch_bounds__(512) void gemm256c(
    const u16* __restrict__ A, const u16* __restrict__ Bm,
    u16* __restrict__ feat, const float* __restrict__ cb2,
    const float* __restrict__ cb3, const float* __restrict__ cb4,
    int K, int NT)
{
  GEMM256_BODY(A, Bm, K, NT)
  // drain staging DMAs before overwriting LDS with the z-tile
  asm volatile("s_waitcnt vmcnt(0)" ::: "memory");
  asm volatile("s_barrier" ::: "memory");
  u16* zt = lds;  // [256 rows][256 cols] bf16
#pragma unroll
  for (int mf = 0; mf < 8; ++mf)
#pragma unroll
    for (int j = 0; j < 4; ++j) {
      int col = wc * 64 + j * 16 + r16;
      int row = wr * 128 + mf * 16 + kq * 4;
#pragma unroll
      for (int qq = 0; qq < 4; ++qq)
        zt[(row + qq) * 256 + col] = f2bf(acc[mf][j][qq]);
    }
  __syncthreads();
  int S, k0, fo, ws;
  const float* cb;
  if (n0 < 1024)      { S = 2; k0 = n0 >> 1;          cb = cb2; fo = 1024; ws = 2; }
  else if (n0 < 3072) { S = 4; k0 = (n0 - 1024) >> 2; cb = cb3; fo = 1536; ws = 3; }
  else                { S = 4; k0 = (n0 - 3072) >> 2; cb = cb4; fo = 2048; ws = 4; }
  int KT = 256 / S;
  if (tid < 4 * KT) {
    int b = tid / KT, kk = tid % KT;
    float bias = cb[k0 + kk];
    float m = 0.f;  // relu floor
    for (int p = 0; p < 64 + ws - 1; ++p) {
      float a = bias;
      for (int j = 0; j < ws; ++j) {
        int t = p - (ws - 1) + j;
        if (t >= 0 && t < 64)
          a += bf2f(zt[(b * 64 + t) * 256 + kk * S + j]);
      }
      m = fmaxf(m, a);
    }
    int gb = (m0 >> 6) + b;
    feat[(long)gb * 5632 + fo + k0 + kk] = f2bf(m);
  }
}
#undef MFMA_CLUSTER
#undef GEMM256_BODY

// ---------------- 128x128 MFMA GEMM (kept for the small FC GEMM) ----------------
__global__ __launch_bounds__(256) void gemm_bt(
    const u16* __restrict__ A, const u16* __restrict__ Bm,
    float* __restrict__ C, int M, int N, int K, int kn)
{
  __shared__ u16 As[128 * 32];
  __shared__ u16 Bs[128 * 32];
  int tid = threadIdx.x, lane = tid & 63, wid = tid >> 6;
  int nwg = gridDim.x * gridDim.y;
  int lin = blockIdx.y * gridDim.x + blockIdx.x;
  int q8 = nwg >> 3;
  int swz = (lin & 7) * q8 + (lin >> 3);
  int m0 = (swz / gridDim.x) * 128, n0 = (swz % gridDim.x) * 128;
  int kt0 = blockIdx.z * kn;
  int wr = wid >> 1, wc = wid & 1;
  int r16 = lane & 15, kq = lane >> 4;
  const floatx4 z4 = {0.f, 0.f, 0.f, 0.f};
  floatx4 acc[4][4];
#pragma unroll
  for (int i = 0; i < 4; ++i)
#pragma unroll
    for (int j = 0; j < 4; ++j) acc[i][j] = z4;
  for (int kt = kt0; kt < kt0 + kn; ++kt) {
    __syncthreads();
#pragma unroll
    for (int inst = 0; inst < 2; ++inst) {
      int g = inst * 256 + tid;
      int row = g >> 2, cb = g & 3;
      const u16* ga = A + (long)(m0 + row) * K + kt * 32 + cb * 8;
      const u16* gb = Bm + (long)(n0 + row) * K + kt * 32 + cb * 8;
      gload_lds16(ga, &As[(inst * 256 + wid * 64) * 8]);
      gload_lds16(gb, &Bs[(inst * 256 + wid * 64) * 8]);
    }
    __syncthreads();
    short8 af[4], bf[4];
#pragma unroll
    for (int mt = 0; mt < 4; ++mt) af[mt] = *(const short8*)&As[(wr * 64 + mt * 16 + r16) * 32 + kq * 8];
#pragma unroll
    for (int nt = 0; nt < 4; ++nt) bf[nt] = *(const short8*)&Bs[(wc * 64 + nt * 16 + r16) * 32 + kq * 8];
#pragma unroll
    for (int mt = 0; mt < 4; ++mt)
#pragma unroll
      for (int nt = 0; nt < 4; ++nt)
        acc[mt][nt] = __builtin_amdgcn_mfma_f32_16x16x32_bf16(af[mt], bf[nt], acc[mt][nt], 0, 0, 0);
  }
  float* Cp = C + (long)blockIdx.z * M * N;
#pragma unroll
  for (int nt = 0; nt < 4; ++nt) {
    int col = n0 + wc * 64 + nt * 16 + r16;
#pragma unroll
    for (int mt = 0; mt < 4; ++mt)
#pragma unroll
      for (int q = 0; q < 4; ++q) {
        int row = m0 + wr * 64 + mt * 16 + kq * 4 + q;
        Cp[(long)row * N + col] = acc[mt][nt][q];
      }
  }
}

// ---------------- GRU recurrence (R11 single-hop tagged exchange; proven) ----------------
__global__ __launch_bounds__(512) void gru_rec(
    const float* __restrict__ xg,     // [8192][3072]
    const u16* __restrict__ whhb,     // [2][1536][512] bf16
    const float* __restrict__ bhh_f, const float* __restrict__ bhh_b,
    char* __restrict__ hb3,           // tagged exchange, 1MB, zeroed each launch
    u16* __restrict__ maskb,          // [8192][1024] bf16 masked output
    u16* __restrict__ feat,           // [128][5632] bf16 (gru mean + vo/mo sections)
    const int* __restrict__ lengths,  // [128]
    const float* __restrict__ fc_w, const float* __restrict__ w2,
    const float* __restrict__ w3, const float* __restrict__ w4,
    const float* __restrict__ vo, const float* __restrict__ mo,
    u16* __restrict__ fcw, u16* __restrict__ wc)
{
  __shared__ float part[2][4][3][256];
  __shared__ u16 hstage[8192];        // 16KB: h[16 batches][512 i] bf16, XOR-swizzled
  int tid = threadIdx.x, lane = tid & 63, wid = tid >> 6;
  int bid = blockIdx.x;

  if (bid >= 128) {
    // -------- converter blocks: fcw, wc remap (R12 k-interleaved), vo/mo --------
    int cid = bid - 128;
    const int C1 = 2883584;           // fcw quads
    const int C2 = C1 + 1310720;      // wc quads (5120x1024/4)
    const int C3 = C2 + 65536;        // vo
    const int NQ = C3 + 32768;        // mo
    for (int q = cid * 512 + tid; q < NQ; q += 128 * 512) {
      if (q < C1) {
        float4 v = ((const float4*)fc_w)[q];
        ((u64*)fcw)[q] = pack4(v.x, v.y, v.z, v.w);
      } else if (q < C2) {
        int r = q - C1;
        int e = r << 2;
        int row = e >> 10, col = e & 1023;
        float4 v = {0.f, 0.f, 0.f, 0.f};
        if (row < 1024)      { int k = row >> 1, j = row & 1;
                               v = *(const float4*)(w2 + (k * 2 + j) * 1024 + col); }
        else if (row < 3072) { int m = row - 1024; int k = m >> 2, j = m & 3;
                               if (j < 3) v = *(const float4*)(w3 + (k * 3 + j) * 1024 + col); }
        else                 { int m = row - 3072; int k = m >> 2, j = m & 3;
                               v = *(const float4*)(w4 + (k * 4 + j) * 1024 + col); }
        ((u64*)wc)[r] = pack4(v.x, v.y, v.z, v.w);
      } else if (q < C3) {
        int r = q - C2; int b = r >> 9, c = (r & 511) * 4;
        float4 v = *(const float4*)&vo[(long)b * 2048 + c];
        *(u64*)&feat[(long)b * 5632 + 2560 + c] = pack4(v.x, v.y, v.z, v.w);
      } else {
        int r = q - C3; int b = r >> 8, c = (r & 255) * 4;
        float4 v = *(const float4*)&mo[(long)b * 1024 + c];
        *(u64*)&feat[(long)b * 5632 + 4608 + c] = pack4(v.x, v.y, v.z, v.w);
      }
    }
    return;
  }

  // -------- recurrence blocks --------
  int dir = bid >> 6, rem = bid & 63, bt = rem >> 3, is = rem & 7;
  int ih = wid & 3, ks = wid >> 2;
  int r16 = lane & 15, kq = lane >> 4;
  int iglob = is * 64 + ih * 16 + r16;
  int i0 = is * 64 + ih * 16 + kq * 4;
  int batch = bt * 16 + r16;
  const float* bhh = dir ? bhh_b : bhh_f;
  const floatx4 z4 = {0.f, 0.f, 0.f, 0.f};
  int len = lengths[batch];

  short8 wfrag[3][8];
#pragma unroll
  for (int g = 0; g < 3; ++g) {
    const u16* wrow = whhb + (long)(dir * 1536 + g * 512 + iglob) * 512;
#pragma unroll
    for (int kk = 0; kk < 8; ++kk)
      wfrag[g][kk] = *(const short8*)&wrow[(ks * 8 + kk) * 32 + kq * 8];
  }
  float4 bh4[3];
#pragma unroll
  for (int g = 0; g < 3; ++g) bh4[g] = *(const float4*)&bhh[g * 512 + i0];
  float4 hprev = {0.f, 0.f, 0.f, 0.f};
  float4 msum = {0.f, 0.f, 0.f, 0.f};

  float4 px[3];
  if (ks == 0) {
    int ts0 = dir ? 63 : 0;
    long xb = (long)(batch * 64 + ts0) * 3072 + dir * 1536 + i0;
#pragma unroll
    for (int g = 0; g < 3; ++g) px[g] = *(const float4*)&xg[xb + g * 512];
  }

  char* slot[2];
  slot[0] = hb3 + (long)((0 * 2 + dir) * 8 + bt) * 32768;
  slot[1] = hb3 + (long)((1 * 2 + dir) * 8 + bt) * 32768;
  char* sdst[4];
#pragma unroll
  for (int k = 0; k < 4; ++k) {
    int row = 4 * k + (tid >> 7);
    int colb = (tid & 127) * 8;
    sdst[k] = (char*)hstage + row * 1024 + (colb ^ ((row & 7) << 4));
  }
  int ld_off = tid * 16;
  int p0 = r16 * 256 + is * 32 + ih * 8 + kq * 2;
  int rb = r16 * 1024 + ks * 512 + kq * 16;
  int rsw = (r16 & 7) << 4;

  for (int t = 0; t < 64; ++t) {
    int par = t & 1;
    u32 tg = (u32)t;
    const char* sb = slot[par];
    u32x4 L0, L1, L2, L3;
    while (true) {
      asm volatile(
        "global_load_dwordx4 %0, %4, off sc0 sc1\n\t"
        "global_load_dwordx4 %1, %5, off sc0 sc1\n\t"
        "global_load_dwordx4 %2, %6, off sc0 sc1\n\t"
        "global_load_dwordx4 %3, %7, off sc0 sc1\n\t"
        "s_waitcnt vmcnt(0)"
        : "=&v"(L0), "=&v"(L1), "=&v"(L2), "=&v"(L3)
        : "v"(sb + ld_off), "v"(sb + 8192 + ld_off),
          "v"(sb + 16384 + ld_off), "v"(sb + 24576 + ld_off)
        : "memory");
      bool ok = (L0.y == tg) & (L0.w == tg) & (L1.y == tg) & (L1.w == tg) &
                (L2.y == tg) & (L2.w == tg) & (L3.y == tg) & (L3.w == tg);
      if (ok) break;
      __builtin_amdgcn_s_sleep(1);
    }
    *(u64*)sdst[0] = (u64)L0.x | ((u64)L0.z << 32);
    *(u64*)sdst[1] = (u64)L1.x | ((u64)L1.z << 32);
    *(u64*)sdst[2] = (u64)L2.x | ((u64)L2.z << 32);
    *(u64*)sdst[3] = (u64)L3.x | ((u64)L3.z << 32);
    float4 pxn[3];
    if (ks == 0 && t < 63) {
      int ts1 = dir ? (62 - t) : (t + 1);
      long xb = (long)(batch * 64 + ts1) * 3072 + dir * 1536 + i0;
#pragma unroll
      for (int g = 0; g < 3; ++g) pxn[g] = *(const float4*)&xg[xb + g * 512];
    }
    asm volatile("s_waitcnt lgkmcnt(0)\n\ts_barrier" ::: "memory");
    floatx4 acc[3];
#pragma unroll
    for (int g = 0; g < 3; ++g) acc[g] = z4;
#pragma unroll
    for (int kk = 0; kk < 8; ++kk) {
      short8 hv = *(const short8*)((const char*)hstage + ((rb + kk * 64) ^ rsw));
#pragma unroll
      for (int g = 0; g < 3; ++g)
        acc[g] = __builtin_amdgcn_mfma_f32_16x16x32_bf16(wfrag[g][kk], hv, acc[g], 0, 0, 0);
    }
    if (ks == 1) {
#pragma unroll
      for (int g = 0; g < 3; ++g) *(floatx4*)&part[par][ih][g][lane * 4] = acc[g];
    }
    asm volatile("s_waitcnt lgkmcnt(0)\n\ts_barrier" ::: "memory");
    if (ks == 0) {
      int tsrc = dir ? (63 - t) : t;
#pragma unroll
      for (int g = 0; g < 3; ++g) acc[g] += *(const floatx4*)&part[par][ih][g][lane * 4];
      float4 hn4;
#pragma unroll
      for (int q = 0; q < 4; ++q) {
        float rr = acc[0][q] + ((const float*)&bh4[0])[q] + ((const float*)&px[0])[q];
        float zz = acc[1][q] + ((const float*)&bh4[1])[q] + ((const float*)&px[1])[q];
        float r = 1.f / (1.f + __expf(-rr));
        float z = 1.f / (1.f + __expf(-zz));
        float n = tanhf(((const float*)&px[2])[q] + r * (acc[2][q] + ((const float*)&bh4[2])[q]));
        ((float*)&hn4)[q] = (1.f - z) * n + z * ((const float*)&hprev)[q];
      }
      hprev = hn4;
      u64 hval = pack4(hn4.x, hn4.y, hn4.z, hn4.w);
      if (t < 63) {
        u32 tg1 = (u32)(t + 1);
        char* pb = slot[(t + 1) & 1] + p0 * 8;
        u64 v0 = (u64)(u32)hval | ((u64)tg1 << 32);
        u64 v1 = (u64)(u32)(hval >> 32) | ((u64)tg1 << 32);
        asm volatile("global_atomic_swap_x2 %0, %1, off sc1"
                     :: "v"(pb), "v"(v0) : "memory");
        asm volatile("global_atomic_swap_x2 %0, %1, off sc1"
                     :: "v"(pb + 8), "v"(v1) : "memory");
      }
      bool mv = tsrc < len;
      *(u64*)&maskb[(long)(batch * 64 + tsrc) * 1024 + dir * 512 + i0] = mv ? hval : 0ull;
      if (mv) {
        msum.x += hn4.x; msum.y += hn4.y; msum.z += hn4.z; msum.w += hn4.w;
      }
      px[0] = pxn[0]; px[1] = pxn[1]; px[2] = pxn[2];
    }
  }
  if (ks == 0) {
    float inv = 1.0f / (float)len;
    *(u64*)&feat[(long)batch * 5632 + dir * 512 + i0] =
        pack4(msum.x * inv, msum.y * inv, msum.z * inv, msum.w * inv);
  }
}

// ---------------- split-K reduce + BN + row L2 normalize (8 partials) ----------------
__global__ __launch_bounds__(256) void k_l2norm(const float* __restrict__ p,
    const float* __restrict__ bns, const float* __restrict__ bnt, float* __restrict__ out)
{
  __shared__ float red[4];
  int b = blockIdx.x, tid = threadIdx.x;
  float v[8]; float s = 0.f;
#pragma unroll
  for (int j = 0; j < 8; ++j) {
    int i = j * 256 + tid;
    long o = (long)b * 2048 + i;
    float a = 0.f;
#pragma unroll
    for (int zz = 0; zz < 8; ++zz) a += p[o + (long)zz * 262144];
    a = a * bns[i] + bnt[i];
    v[j] = a; s += a * a;
  }
#pragma unroll
  for (int o = 32; o > 0; o >>= 1) s += __shfl_down(s, o);
  if ((tid & 63) == 0) red[tid >> 6] = s;
  __syncthreads();
  float rn = rsqrtf(red[0] + red[1] + red[2] + red[3]);
#pragma unroll
  for (int j = 0; j < 8; ++j)
    out[(long)b * 2048 + j * 256 + tid] = v[j] * rn;
}

// ---------------- launch ----------------
extern "C" void kernel_launch(void* const* d_in, const int* in_sizes, int n_in,
                              void* d_out, int out_size, void* d_ws, size_t ws_size,
                              hipStream_t stream)
{
  (void)in_sizes; (void)n_in; (void)out_size; (void)ws_size;
  const float* videos       = (const float*)d_in[0];
  const float* motions      = (const float*)d_in[1];
  const float* videos_origin= (const float*)d_in[2];
  const int*   lengths      = (const int*)d_in[3];
  const float* Wih_f = (const float*)d_in[4];
  const float* Whh_f = (const float*)d_in[5];
  const float* bih_f = (const float*)d_in[6];
  const float* bhh_f = (const float*)d_in[7];
  const float* Wih_b = (const float*)d_in[8];
  const float* Whh_b = (const float*)d_in[9];
  const float* bih_b = (const float*)d_in[10];
  const float* bhh_b = (const float*)d_in[11];
  const float* fc_w  = (const float*)d_in[12];
  const float* fc_b  = (const float*)d_in[13];
  const float* bn_gamma = (const float*)d_in[14];
  const float* bn_beta  = (const float*)d_in[15];
  const float* bn_mean  = (const float*)d_in[16];
  const float* bn_var   = (const float*)d_in[17];
  const float* conv_w2 = (const float*)d_in[18];
  const float* conv_b2 = (const float*)d_in[19];
  const float* conv_w3 = (const float*)d_in[20];
  const float* conv_b3 = (const float*)d_in[21];
  const float* conv_w4 = (const float*)d_in[22];
  const float* conv_b4 = (const float*)d_in[23];
  float* out = (float*)d_out;
  char* w = (char*)d_ws;

  const size_t XG    = 0;              // 8192x3072 f32 = 100,663,296
  const size_t HS    = 100663296;      // dead region: tagged h exchange (1MB) + Wc (10.5MB)
  const size_t VID   = 134217728;      // 8192x2048 bf16 = 33,554,432
  const size_t MASKB = 167772160;      // 8192x1024 bf16 = 16,777,216 (FC partials 8MB overlay)
  const size_t WIH   = 184549376;      // 3072x2048 bf16 = 12,582,912
  const size_t WHH   = 197132288;      // 2x1536x512 bf16 = 3,145,728
  const size_t FCW   = 209715200;      // 2048x5632 bf16 = 23,068,672
  const size_t FEAT  = 232783872;      // 128x5632 bf16 = 1,441,792
  const size_t BIH   = 235274240;      // 3072 f32
  const size_t BNS   = 235286528;      // 2048 f32
  const size_t BNT   = 235294720;      // 2048 f32

  float* xg   = (float*)(w + XG);
  char* hb3   = (char*)(w + HS);               // tagged exchange (1MB)
  u16* wc_    = (u16*)(w + HS + 1048576);      // Wc [5120][1024] bf16 (10.5MB, HS region)
  u16* vid    = (u16*)(w + VID);
  u16* maskb  = (u16*)(w + MASKB);
  float* fcp  = (float*)(w + MASKB);   // FC split-K partials overlay (after conv GEMM)
  u16* wih    = (u16*)(w + WIH);
  u16* whh    = (u16*)(w + WHH);
  u16* fcw    = (u16*)(w + FCW);
  u16* feat   = (u16*)(w + FEAT);
  float* bih  = (float*)(w + BIH);
  float* bns  = (float*)(w + BNS);
  float* bnt  = (float*)(w + BNT);

  // zero tagged exchange (tags 0 expected at t=0; data 0 = h0), every launch
  hipMemsetAsync(hb3, 0, 1048576, stream);

  k_pre_cvt<<<4096, 256, 0, stream>>>(
      videos, Wih_f, Wih_b, Whh_f, Whh_b, bih_f, bih_b,
      fc_b, bn_gamma, bn_beta, bn_mean, bn_var,
      vid, wih, whh, bih, bns, bnt);

  // xg = videos @ [Wih_f;Wih_b]^T + bih  (f32 out), 256^2 8-phase
  gemm256<<<dim3(12, 32), 512, 0, stream>>>(vid, wih, xg, 3072, 2048, 32, bih);

  {
    const float* xg_c = xg; const u16* whh_c = whh;
    char* hb_c = hb3; u16* mb_c = maskb; u16* ft_c = feat;
    const int* len_c = lengths;
    const float* bf_c = bhh_f; const float* bb_c = bhh_b;
    const float* fw_c = fc_w; const float* w2_c = conv_w2;
    const float* w3_c = conv_w3; const float* w4_c = conv_w4;
    const float* vo_c = videos_origin; const float* mo_c = motions;
    u16* fcw_c = fcw; u16* wc_c = wc_;
    void* args[] = { (void*)&xg_c, (void*)&whh_c, (void*)&bf_c, (void*)&bb_c,
                     (void*)&hb_c, (void*)&mb_c, (void*)&ft_c, (void*)&len_c,
                     (void*)&fw_c, (void*)&w2_c, (void*)&w3_c, (void*)&w4_c,
                     (void*)&vo_c, (void*)&mo_c, (void*)&fcw_c, (void*)&wc_c };
    hipLaunchCooperativeKernel(reinterpret_cast<void*>(gru_rec), dim3(256), dim3(512), args, 0, stream);
  }

  // conv GEMM with fused conv-finish (k-interleaved Wc, N=5120), writes feat directly
  gemm256c<<<dim3(20, 32), 512, 0, stream>>>(maskb, wc_, feat, conv_b2, conv_b3, conv_b4, 1024, 16);
  // FC split-K x8 (raw partials; BN folded into l2norm)
  gemm_bt<<<dim3(16, 1, 8), 256, 0, stream>>>(feat, fcw, fcp, 128, 2048, 5632, 22);
  k_l2norm<<<128, 256, 0, stream>>>(fcp, bns, bnt, out);
}